// Round 7
// baseline (638.036 us; speedup 1.0000x reference)
//
#include <hip/hip_runtime.h>
#include <cmath>

#define S_ 1024
#define B_ 8
#define H_ 512
#define S2_ 1022
#define M_ (B_*S2_)     // 8176
#define PAD_ 8192
#define VTS_ ((size_t)8*8*64*1024)   // VT per-branch stride (4194304 shorts)

typedef __attribute__((ext_vector_type(8))) short bf16x8;
typedef __attribute__((ext_vector_type(4))) float f32x4;
typedef __attribute__((ext_vector_type(4))) unsigned int u32x4;
typedef __attribute__((ext_vector_type(2))) unsigned int u32x2;

__device__ __forceinline__ unsigned short f2bf(float f){
  unsigned int u = __float_as_uint(f);
  return (unsigned short)((u + 0x7fffu + ((u>>16)&1u)) >> 16);
}
__device__ __forceinline__ float bf2f(unsigned short u){
  return __uint_as_float((unsigned int)u << 16);
}
// tanh-approx gelu: x*sigmoid(2*(c1 x + c2 x^3)); |err vs erf-gelu| < ~3e-4
__device__ __forceinline__ float fgelu(float x){
  float u = x * (0.7978845608f + 0.0356774081f * x * x);
  return x / (1.f + __expf(-2.f * u));
}
// raw 2^x (v_exp_f32 is natively base-2)
__device__ __forceinline__ float fexp2(float x){
  float r; asm("v_exp_f32 %0, %1" : "=v"(r) : "v"(x)); return r;
}
// hardware packed f32->bf16 (RNE), lo -> bits[15:0], hi -> bits[31:16]
__device__ __forceinline__ unsigned int cvtpk(float lo, float hi){
  unsigned int r; asm("v_cvt_pk_bf16_f32 %0, %1, %2" : "=v"(r) : "v"(lo), "v"(hi)); return r;
}

__device__ __forceinline__ void glds16(const void* g, void* l){
  __builtin_amdgcn_global_load_lds((const __attribute__((address_space(1))) unsigned int*)g,
                                   (__attribute__((address_space(3))) unsigned int*)l, 16, 0, 0);
}
#define SB() __builtin_amdgcn_sched_barrier(0)

// ---------------------------------------------------------------- prep: X = [f[:-2], bk[2:]] bf16 (M_ x 1024)
__global__ __launch_bounds__(256) void lma_prep_x(const float* __restrict__ hidden,
                                                  unsigned short* __restrict__ Xb){
  int m = blockIdx.x; int dq = threadIdx.x * 4;
  int b = m / S2_, s = m - b * S2_;
  int srow = (dq < 512) ? s : (s + 2);
  const float* src = hidden + ((size_t)srow * B_ + b) * 1024 + dq;
  f32x4 v = *(const f32x4*)src;
  union { u32x2 u; unsigned short s4[4]; } pk;
  #pragma unroll
  for (int j = 0; j < 4; j++) pk.s4[j] = f2bf(v[j]);
  *(u32x2*)&Xb[(size_t)m * 1024 + dq] = pk.u;
}

// ---------------------------------------------------------------- batched weight transpose+cast
struct TPack {
  const float* src[14];
  unsigned short* dst[14];
  int K[14];
  int N[14];
};
__global__ __launch_bounds__(256) void lma_transpose_all(TPack p){
  int idx = blockIdx.z;
  int K = p.K[idx], N = p.N[idx];
  int kb = blockIdx.x * 32, nb = blockIdx.y * 32;
  if (kb >= K || nb >= N) return;
  const float* W = p.src[idx];
  unsigned short* WT = p.dst[idx];
  __shared__ float t[32][33];
  int tx = threadIdx.x & 31, ty = threadIdx.x >> 5;
  #pragma unroll
  for (int i = ty; i < 32; i += 8) t[i][tx] = W[(size_t)(kb + i) * N + nb + tx];
  __syncthreads();
  #pragma unroll
  for (int i = ty; i < 32; i += 8) WT[(size_t)(nb + i) * K + kb + tx] = f2bf(t[tx][i]);
}

// ---------------------------------------------------------------- concat K/V biases
__global__ __launch_bounds__(256) void lma_biascat(const float* __restrict__ fk, const float* __restrict__ fv,
                                                   const float* __restrict__ bk, const float* __restrict__ bv,
                                                   float* __restrict__ out){
  int i = blockIdx.x * 256 + threadIdx.x;     // 0..2047
  int fb = i >> 10, col = i & 1023;
  const float* s = (col < 512) ? (fb ? bk : fk) : (fb ? bv : fv);
  out[i] = s[col & 511];
}

// ---------------------------------------------------------------- V (in KV2, cols 512..1023) -> VT2[fb][b][h][d][s pad 1024]
// Pad cols s in [S2_,1024) ZEROED (aliased buffer may hold bf16-NaN bit patterns).
__global__ __launch_bounds__(256) void lma_vt2(const unsigned short* __restrict__ KV2,
                                               unsigned short* __restrict__ VT2){
  __shared__ unsigned short t[32][34];
  int s0 = blockIdx.x * 32, c0 = blockIdx.y * 32;
  int z = blockIdx.z, fb = z >> 3, b = z & 7;
  const unsigned short* V = KV2 + (size_t)fb * PAD_ * 1024 + 512;
  unsigned short* VT = VT2 + (size_t)fb * VTS_;
  int tx = threadIdx.x & 31, ty = threadIdx.x >> 5;
  #pragma unroll
  for (int i = ty; i < 32; i += 8){
    int s = s0 + i; if (s > S2_-1) s = S2_-1;
    t[i][tx] = V[((size_t)b * S2_ + s) * 1024 + c0 + tx];
  }
  __syncthreads();
  int s = s0 + tx;
  #pragma unroll
  for (int i = ty; i < 32; i += 8){
    int c = c0 + i, h = c >> 6, d = c & 63;
    VT[(((size_t)b * 8 + h) * 64 + d) * 1024 + s] = (s < S2_) ? t[tx][i] : (unsigned short)0;
  }
}

// ---------------------------------------------------------------- 128^2 2-phase GEMM (kept for small-grid shapes)
__global__ __launch_bounds__(256) void lma_gemm2(
    const unsigned short* __restrict__ A, int lda,
    const unsigned short* __restrict__ Bt0, const unsigned short* __restrict__ Bt1,
    const float* __restrict__ bias0, const float* __restrict__ bias1,
    void* __restrict__ Cout, int ldc,
    int M, int N, int K, int mode, int amap, int nmt)
{
  __shared__ unsigned short Al[128*32];
  __shared__ unsigned short Bl[128*32];
  const int tid = threadIdx.x;
  const int w = tid >> 6, lane = tid & 63, quad = lane >> 4, l16 = lane & 15;
  const int mt = blockIdx.x % nmt, nt = blockIdx.x / nmt;
  const int m0 = mt * 128, n0 = nt * 128;
  const int brch = m0 >> 13;
  const unsigned short* Bt = brch ? Bt1 : Bt0;
  const float* bias = brch ? bias1 : bias0;
  const int coloff = (amap == 2 && brch) ? 512 : 0;
  const int wm = (w >> 1) * 64, wn = (w & 1) * 64;

  f32x4 acc[4][4];
  #pragma unroll
  for (int i = 0; i < 4; i++)
    #pragma unroll
    for (int f = 0; f < 4; f++) acc[i][f] = f32x4{0.f,0.f,0.f,0.f};

  const int srow = lane >> 2;
  const int spc  = (((lane & 3) ^ ((lane >> 2) & 3))) * 8;   // pre-swizzled source block
  const int rswz = (l16 & 3);                                 // read-side row XOR

  for (int k0 = 0; k0 < K; k0 += 32) {
    #pragma unroll
    for (int c = 0; c < 2; c++) {
      int ra = w*32 + c*16 + srow;
      int ga = m0 + ra;
      int ar;
      if (amap == 0) { ar = (ga > M-1) ? (M-1) : ga; }
      else { ar = ga & (PAD_-1); if (ar > M_-1) ar = M_-1; }
      glds16(A + (size_t)ar * lda + coloff + k0 + spc, &Al[(w*32 + c*16) * 32]);
      int gb = n0 + ra; if (gb > N-1) gb = N-1;
      glds16(Bt + (size_t)gb * K + k0 + spc, &Bl[(w*32 + c*16) * 32]);
    }
    __syncthreads();
    bf16x8 af[4], bfr[4];
    #pragma unroll
    for (int i = 0; i < 4; i++) af[i]  = *(const bf16x8*)&Al[(wm + i*16 + l16)*32 + ((quad ^ rswz) * 8)];
    #pragma unroll
    for (int f = 0; f < 4; f++) bfr[f] = *(const bf16x8*)&Bl[(wn + f*16 + l16)*32 + ((quad ^ rswz) * 8)];
    #pragma unroll
    for (int i = 0; i < 4; i++)
      #pragma unroll
      for (int f = 0; f < 4; f++)
        acc[i][f] = __builtin_amdgcn_mfma_f32_16x16x32_bf16(af[i], bfr[f], acc[i][f], 0, 0, 0);
    __syncthreads();
  }

  #pragma unroll
  for (int f = 0; f < 4; f++) {
    int col = n0 + wn + f*16 + l16;
    float bv = bias ? bias[col] : 0.f;
    #pragma unroll
    for (int i = 0; i < 4; i++) {
      #pragma unroll
      for (int r = 0; r < 4; r++) {
        int row = m0 + wm + i*16 + quad*4 + r;
        if (row < M) {
          float v = acc[i][f][r] + bv;
          if (mode == 2) v = fgelu(v);
          else if (mode == 1) v *= 0.18033688011112042f;   // 0.125 * log2(e)
          if (mode <= 2) ((unsigned short*)Cout)[(size_t)row * ldc + col] = f2bf(v);
          else if (mode == 3) ((float*)Cout)[(size_t)row * ldc + col] = v;
          else {
            int sr = row % S2_, bb2 = row / S2_;
            ((float*)Cout)[((size_t)sr * B_ + bb2) * ldc + col] = v;
          }
        }
      }
    }
  }
}

// ---------------------------------------------------------------- 256^2 8-phase GEMM v2 (T2+T3+T4+T5)
// Round-7 changes vs v1 (which spilled ~32MB scratch: VGPR demand = acc128 +
// af32 + bf0/bf1 32 + addressing > cap):
// (1) quadrant order 00,01,11,10 -> ONE B-frag set live at a time (-16 VGPR),
//     cost: 2 extra LDB8/iter (ph4, ph8 re-read nq0).
// (2) stage addressing is K-invariant -> precompute 8 per-thread global ptrs
//     once; in-loop stage = glds16(ptr + kt*64, uniform_dst). Removes the
//     clamp/select/mul chains from every phase.
// (3) re-derived stage map for the new read order (region liveness):
//     reads  : ph1 A0,B0 | ph2 B1 | ph3 A1 | ph4 B0 | (buf1 same ph5-8)
//     stages : ph1 {b.B0,b.B1,b.A1}  ph2 a+2.A0  ph3 a+2.B1  ph4 a+2.A1
//              ph5 a+2.B0  ph6 b+2.A0  (ph7,ph8 none)
//     every stage lands >=1 barrier after its region's last read.
//     vmcnt(6) @ph4 end: drains prev-ph6 + ph1x3 (covers ph5-8 reads),
//       leaves ph2,3,4 stages (3x2 ops) in flight.
//     vmcnt(2) @ph8 end: drains through ph5 (covers next ph1-4 reads),
//       leaves ph6 stage. Never drains to 0 in the loop.
//     Tail: clamped ta2/tb2 re-stage byte-identical data -> benign.
__global__ __launch_bounds__(512, 2) void lma_gemm8(
    const unsigned short* __restrict__ A, int lda,
    const unsigned short* __restrict__ Bt0, const unsigned short* __restrict__ Bt1,
    const float* __restrict__ bias0, const float* __restrict__ bias1,
    unsigned short* __restrict__ Cout, int ldc,
    int M, int N, int K, int mode, int amap, int nmt)
{
  __shared__ unsigned short Ls[2][2][256*64];   // [buf][0=A,1=B][row*64+k]
  const int tid = threadIdx.x;
  const int w = tid >> 6, lane = tid & 63, quad = lane >> 4, l16 = lane & 15;
  const int mt = blockIdx.x % nmt, nt = blockIdx.x / nmt;
  const int m0 = mt * 256, n0 = nt * 256;
  const int brch = m0 >> 13;
  const unsigned short* Bt = brch ? Bt1 : Bt0;
  const float* bias = brch ? bias1 : bias0;
  const int coloff = (amap == 2 && brch) ? 512 : 0;
  const int wm = (w >> 2) * 128, wn = (w & 3) * 64;

  f32x4 acc[8][4];
  #pragma unroll
  for (int i = 0; i < 8; i++)
    #pragma unroll
    for (int f = 0; f < 4; f++) acc[i][f] = f32x4{0.f,0.f,0.f,0.f};

  const int lrow8 = lane >> 3;     // 0..7
  const int lkb   = lane & 7;      // kblk 0..7 (16B units within 128B row)
  const int NT = K >> 6;           // K-tiles (even for K in {512,1024})

  // K-invariant per-thread stage pointers + uniform LDS dest offsets
  const unsigned short* aP[2][2]; const unsigned short* bP[2][2];
  int aD[2][2], bD[2][2];
  #pragma unroll
  for (int hf = 0; hf < 2; hf++)
    #pragma unroll
    for (int c = 0; c < 2; c++) {
      int rtA = (w>>2)*128 + hf*64 + ((w&3)*2 + c)*8 + lrow8;
      int kbA = lkb ^ (((rtA>>2)&3)<<1);
      int ga = m0 + rtA;
      int ar;
      if (amap == 0) { ar = (ga > M-1) ? (M-1) : ga; }
      else { ar = ga & (PAD_-1); if (ar > M_-1) ar = M_-1; }
      aP[hf][c] = A + (size_t)ar * lda + coloff + kbA*8;
      aD[hf][c] = ((w>>2)*128 + hf*64 + ((w&3)*2 + c)*8) * 64;
      int rtB = (w>>1)*64 + hf*32 + ((w&1)*2 + c)*8 + lrow8;
      int kbB = lkb ^ (((rtB>>2)&3)<<1);
      int gb = n0 + rtB; if (gb > N-1) gb = N-1;
      bP[hf][c] = Bt + (size_t)gb * K + kbB*8;
      bD[hf][c] = ((w>>1)*64 + hf*32 + ((w&1)*2 + c)*8) * 64;
    }

  bf16x8 af[4][2], bf[2][2];

  #define STA(buf, hf, kt) { _Pragma("unroll") for (int c = 0; c < 2; c++) \
      glds16(aP[hf][c] + (size_t)(kt)*64, &Ls[buf][0][aD[hf][c]]); }
  #define STB(buf, hf, kt) { _Pragma("unroll") for (int c = 0; c < 2; c++) \
      glds16(bP[hf][c] + (size_t)(kt)*64, &Ls[buf][1][bD[hf][c]]); }
  #define LDA8(buf, mq) { _Pragma("unroll") for (int j = 0; j < 4; j++){ \
      int rt = wm + (mq)*64 + j*16 + l16; \
      const unsigned short* base = &Ls[buf][0][rt*64]; \
      int f_ = ((rt>>2)&3)<<1; \
      af[j][0] = *(const bf16x8*)(base + ((    quad) ^ f_)*8); \
      af[j][1] = *(const bf16x8*)(base + ((4 + quad) ^ f_)*8); } }
  #define LDB8(buf, nq) { _Pragma("unroll") for (int j = 0; j < 2; j++){ \
      int rt = wn + (nq)*32 + j*16 + l16; \
      const unsigned short* base = &Ls[buf][1][rt*64]; \
      int f_ = ((rt>>2)&3)<<1; \
      bf[j][0] = *(const bf16x8*)(base + ((    quad) ^ f_)*8); \
      bf[j][1] = *(const bf16x8*)(base + ((4 + quad) ^ f_)*8); } }
  #define MFMAQ(mq, nq) { __builtin_amdgcn_s_setprio(1); \
      _Pragma("unroll") for (int j = 0; j < 4; j++) \
        _Pragma("unroll") for (int j2 = 0; j2 < 2; j2++){ \
          acc[(mq)*4+j][(nq)*2+j2] = __builtin_amdgcn_mfma_f32_16x16x32_bf16(af[j][0], bf[j2][0], acc[(mq)*4+j][(nq)*2+j2], 0, 0, 0); \
          acc[(mq)*4+j][(nq)*2+j2] = __builtin_amdgcn_mfma_f32_16x16x32_bf16(af[j][1], bf[j2][1], acc[(mq)*4+j][(nq)*2+j2], 0, 0, 0); } \
      __builtin_amdgcn_s_setprio(0); }
  #define BAR()   { SB(); __builtin_amdgcn_s_barrier(); SB(); }
  #define LGKM0() { asm volatile("s_waitcnt lgkmcnt(0)" ::: "memory"); SB(); }
  #define VM6()   { asm volatile("s_waitcnt vmcnt(6)"   ::: "memory"); SB(); }
  #define VM2()   { asm volatile("s_waitcnt vmcnt(2)"   ::: "memory"); SB(); }

  // prologue: t0 all 4 halves + t1.A0 ("prev-ph6" seed); drain t0, leave t1.A0
  STA(0, 0, 0); STB(0, 0, 0); STB(0, 1, 0); STA(0, 1, 0);
  STA(1, 0, 1);
  asm volatile("s_waitcnt vmcnt(2)" ::: "memory"); SB();
  BAR();

  const int NI = NT >> 1;
  for (int i = 0; i < NI; i++) {
    const int tb  = 2*i + 1;
    int ta2 = 2*i + 2; if (ta2 > NT-1) ta2 = NT-1;
    int tb2 = 2*i + 3; if (tb2 > NT-1) tb2 = NT-1;

    // ph1 (buf0: mq0,nq0)
    LDA8(0, 0); LDB8(0, 0); STB(1, 0, tb); STB(1, 1, tb); STA(1, 1, tb);
    BAR(); LGKM0(); MFMAQ(0, 0); BAR();
    // ph2 (buf0: mq0,nq1)
    LDB8(0, 1); STA(0, 0, ta2);
    BAR(); LGKM0(); MFMAQ(0, 1); BAR();
    // ph3 (buf0: mq1,nq1)
    LDA8(0, 1); STB(0, 1, ta2);
    BAR(); LGKM0(); MFMAQ(1, 1); BAR();
    // ph4 (buf0: mq1,nq0)
    LDB8(0, 0); STA(0, 1, ta2);
    BAR(); LGKM0(); MFMAQ(1, 0); VM6(); BAR();
    // ph5 (buf1: mq0,nq0)
    LDA8(1, 0); LDB8(1, 0); STB(0, 0, ta2);
    BAR(); LGKM0(); MFMAQ(0, 0); BAR();
    // ph6 (buf1: mq0,nq1)
    LDB8(1, 1); STA(1, 0, tb2);
    BAR(); LGKM0(); MFMAQ(0, 1); BAR();
    // ph7 (buf1: mq1,nq1)
    LDA8(1, 1);
    BAR(); LGKM0(); MFMAQ(1, 1); BAR();
    // ph8 (buf1: mq1,nq0)
    LDB8(1, 0);
    BAR(); LGKM0(); MFMAQ(1, 0); VM2(); BAR();
  }
  asm volatile("s_waitcnt vmcnt(0)" ::: "memory");

  #pragma unroll
  for (int f = 0; f < 4; f++) {
    int col = n0 + wn + f*16 + l16;
    float bv = bias ? bias[col] : 0.f;
    #pragma unroll
    for (int i2 = 0; i2 < 8; i2++) {
      #pragma unroll
      for (int r = 0; r < 4; r++) {
        int row = m0 + wm + i2*16 + quad*4 + r;
        if (row < M) {
          float v = acc[i2][f][r] + bv;
          if (mode == 2) v = fgelu(v);
          Cout[(size_t)row * ldc + col] = f2bf(v);
        }
      }
    }
  }
  #undef STA
  #undef STB
  #undef LDA8
  #undef LDB8
  #undef MFMAQ
  #undef BAR
  #undef LGKM0
  #undef VM6
  #undef VM2
}

// ---------------------------------------------------------------- block reduction helper
__device__ __forceinline__ void lma_red2(float& s, float& sq){
  __shared__ float red[16];
  #pragma unroll
  for (int msk = 1; msk < 64; msk <<= 1){ s += __shfl_xor(s, msk); sq += __shfl_xor(sq, msk); }
  int w = threadIdx.x >> 6;
  if ((threadIdx.x & 63) == 0){ red[w] = s; red[8 + w] = sq; }
  __syncthreads();
  s  = red[0] + red[1] + red[2] + red[3];
  sq = red[8] + red[9] + red[10] + red[11];
}

// ---------------------------------------------------------------- generic LN (f32 in, bf16 or f32 out)
__global__ __launch_bounds__(256) void lma_ln(const float* __restrict__ in,
                                              const float* __restrict__ g, const float* __restrict__ bb,
                                              int D, unsigned short* __restrict__ obf, float* __restrict__ of32){
  int row = blockIdx.x, t = threadIdx.x;
  const float* x = in + (size_t)row * D;
  float s = 0.f, sq = 0.f;
  for (int d = t; d < D; d += 256){ float v = x[d]; s += v; sq += v * v; }
  lma_red2(s, sq);
  float mean = s / D;
  float var = sq / D - mean * mean;
  float rstd = rsqrtf(fmaxf(var, 0.f) + 1e-12f);
  if (obf) {
    for (int d = t; d < D; d += 256) obf[(size_t)row * D + d] = f2bf((x[d] - mean) * rstd * g[d] + bb[d]);
  } else {
    for (int d = t; d < D; d += 256) of32[(size_t)row * D + d] = (x[d] - mean) * rstd * g[d] + bb[d];
  }
}

// ---------------------------------------------------------------- branch-combined LN over T12b (bf16, D=512) -> LQ2 bf16
__global__ __launch_bounds__(256) void lma_ln2(const unsigned short* __restrict__ T12b,
                                               const float* __restrict__ fg, const float* __restrict__ fbb,
                                               const float* __restrict__ bg, const float* __restrict__ bbb,
                                               unsigned short* __restrict__ LQ2){
  int m = blockIdx.x, t = threadIdx.x;           // 0..2*M_-1
  int fb = (m >= M_);
  int idx = m - fb * M_;
  const float* g = fb ? bg : fg;
  const float* bb = fb ? bbb : fbb;
  const unsigned short* x = T12b + ((size_t)fb * PAD_ + idx) * 512;
  unsigned short* o = LQ2 + ((size_t)fb * PAD_ + idx) * 512;
  float v0 = bf2f(x[t]), v1 = bf2f(x[t + 256]);
  float s = v0 + v1, sq = v0*v0 + v1*v1;
  lma_red2(s, sq);
  float mean = s / 512.f;
  float var = sq / 512.f - mean * mean;
  float rstd = rsqrtf(fmaxf(var, 0.f) + 1e-12f);
  o[t]       = f2bf((v0 - mean) * rstd * g[t]       + bb[t]);
  o[t + 256] = f2bf((v1 - mean) * rstd * g[t + 256] + bb[t + 256]);
}

// ---------------------------------------------------------------- attn LN: LN(residual(hidden)+[pf,pb](bf16)) -> bf16 (M_ x 1024)
__global__ __launch_bounds__(256) void lma_attn_ln(const unsigned short* __restrict__ pf,
                                                   const unsigned short* __restrict__ pb,
                                                   const float* __restrict__ hidden,
                                                   const float* __restrict__ g, const float* __restrict__ bb,
                                                   unsigned short* __restrict__ out){
  int m = blockIdx.x, t = threadIdx.x;
  int b = m / S2_, s = m - b * S2_;
  const float* hf = hidden + ((size_t)s       * B_ + b) * 1024;
  const float* hb = hidden + ((size_t)(s + 2) * B_ + b) * 1024;
  float v[4]; float sum = 0.f, sq = 0.f;
  #pragma unroll
  for (int j = 0; j < 4; j++){
    int d = t + j * 256;
    float x = (d < 512) ? (bf2f(pf[(size_t)m * 512 + d]) + hf[d])
                        : (bf2f(pb[(size_t)m * 512 + (d - 512)]) + hb[d]);
    v[j] = x; sum += x; sq += x * x;
  }
  lma_red2(sum, sq);
  float mean = sum / 1024.f;
  float var = sq / 1024.f - mean * mean;
  float rstd = rsqrtf(fmaxf(var, 0.f) + 1e-12f);
  #pragma unroll
  for (int j = 0; j < 4; j++){
    int d = t + j * 256;
    out[(size_t)m * 1024 + d] = f2bf((v[j] - mean) * rstd * g[d] + bb[d]);
  }
}

// ---------------------------------------------------------------- combined flash attention v9b
// v9 + qt load-balance permutation: with dispatch round-robin (CU ~ id mod 256)
// a CU's 4 resident blocks had fwd tile-counts {q+1,q+5,q+9,q+13} -> 28..40
// tiles/CU (1.43x imbalance). perm = [0,2,4,6,15,13,11,9,1,3,5,7,14,12,10,8]
// (nibble LUT) makes every residue class sum to exactly 34, fwd AND bwd.
__global__ __launch_bounds__(256, 4) void lma_attn9(const unsigned short* __restrict__ Q2,
                                                    const unsigned short* __restrict__ KV2,
                                                    const unsigned short* __restrict__ VT2,
                                                    unsigned short* __restrict__ CT2,
                                                    const int* __restrict__ lens,
                                                    int fb){
  __shared__ unsigned short Kl[64*64];
  __shared__ unsigned short Vl[64*64];
  __shared__ __align__(16) unsigned short Pl[4][16*64];

  const int tid = threadIdx.x;
  const int w = tid >> 6, lane = tid & 63, quad = lane >> 4, l16 = lane & 15;
  const int id = blockIdx.x;                 // 1024 blocks: [qt:4][h:3][b:3]
  const int qi = id >> 6;
  const int qt = (int)((0x8ACE75319BDF6420ull >> (qi*4)) & 15ull);
  const int h = (id >> 3) & 7, b = id & 7;
  const int backward = fb;
  const int L2 = lens[b] - 2;
  const int q0wg = qt * 64;
  const int q0 = q0wg + w * 16;
  const int qg = q0 + l16;
  const int qload = (qg > S2_-1) ? (S2_-1) : qg;

  const size_t qbase  = ((size_t)b * S2_) * 512  + h * 64;
  const size_t kbase  = ((size_t)b * S2_) * 1024 + h * 64;
  const size_t vtbase = ((size_t)(b * 8 + h) * 64) * 1024;
  char* Pb = (char*)&Pl[w][0];

  const int lrow = lane >> 3;
  const int g0s  = (lane & 7) ^ lrow;
  const int x7   = l16 & 7;
  const int x7s  = x7 << 4;

  const unsigned short* Q  = Q2  + (size_t)fb * PAD_ * 512;
  const unsigned short* Kx = KV2 + (size_t)fb * PAD_ * 1024;
  const unsigned short* VT = VT2 + (size_t)fb * VTS_;
  unsigned short* CTX      = CT2 + (size_t)fb * PAD_ * 512;

  bf16x8 qf[2];
  {
    const unsigned short* qp = Q + qbase + (size_t)qload * 512 + quad * 8;
    qf[0] = *(const bf16x8*)(qp);
    qf[1] = *(const bf16x8*)(qp + 32);
  }

  float mi = -3e38f, li = 0.f;
  f32x4 ot[4];
  #pragma unroll
  for (int f = 0; f < 4; f++) ot[f] = f32x4{0.f,0.f,0.f,0.f};

  int klo = 0, khi = S2_ - 1;
  if (q0wg + 63 < L2) {
    if (!backward) khi = q0wg + 63;
    else { klo = q0wg; khi = L2 - 1; }
  }

  for (int kt0 = klo; kt0 <= khi; kt0 += 64) {
    #pragma unroll
    for (int c = 0; c < 2; c++) {
      int r = w*16 + c*8 + lrow;
      int kr = kt0 + r; if (kr > S2_-1) kr = S2_-1;
      glds16(Kx + kbase + (size_t)kr * 1024 + g0s * 8, &Kl[(w*16 + c*8) * 64]);
      glds16(VT + vtbase + (size_t)r * 1024 + kt0 + g0s * 8, &Vl[(w*16 + c*8) * 64]);
    }
    __syncthreads();

    bf16x8 kf[4][2], vf[4][2];
    #pragma unroll
    for (int sub = 0; sub < 4; sub++) {
      const unsigned short* kp = &Kl[(sub*16 + l16) * 64];
      kf[sub][0] = *(const bf16x8*)(kp + (( quad      ^ x7) * 8));
      kf[sub][1] = *(const bf16x8*)(kp + (((quad + 4) ^ x7) * 8));
    }
    #pragma unroll
    for (int f = 0; f < 4; f++) {
      const unsigned short* vp = &Vl[(f*16 + l16) * 64];
      vf[f][0] = *(const bf16x8*)(vp + (( quad      ^ x7) * 8));
      vf[f][1] = *(const bf16x8*)(vp + (((quad + 4) ^ x7) * 8));
    }

    f32x4 st[4];
    __builtin_amdgcn_s_setprio(1);
    #pragma unroll
    for (int sub = 0; sub < 4; sub++) {
      f32x4 s = f32x4{0.f,0.f,0.f,0.f};
      s = __builtin_amdgcn_mfma_f32_16x16x32_bf16(kf[sub][0], qf[0], s, 0, 0, 0);
      s = __builtin_amdgcn_mfma_f32_16x16x32_bf16(kf[sub][1], qf[1], s, 0, 0, 0);
      st[sub] = s;
    }
    __builtin_amdgcn_s_setprio(0);

    // interior-tile skip: wave-uniform "every (lane,r) passes the mask"
    {
      bool tail = (kt0 + 63 > S2_ - 1);
      bool full;
      if (!backward) full = !tail && ((kt0 + 63 <= q0) || (q0 >= L2));
      else           full = !tail && ((q0 >= L2) || ((kt0 >= q0 + 15) && (kt0 + 63 < L2)));
      if (!full) {
        #pragma unroll
        for (int sub = 0; sub < 4; sub++) {
          #pragma unroll
          for (int r = 0; r < 4; r++) {
            int kg = kt0 + sub*16 + quad*4 + r;
            bool ok;
            if (!backward) ok = (kg < S2_) && ((qg >= L2) || (kg <= qg));
            else           ok = (kg < S2_) && ((qg >= L2) || ((kg >= qg) && (kg < L2)));
            if (!ok) st[sub][r] = -3e38f;
          }
        }
      }
    }

    float mx = -3e38f;
    #pragma unroll
    for (int sub = 0; sub < 4; sub++)
      #pragma unroll
      for (int r = 0; r < 4; r++) mx = fmaxf(mx, st[sub][r]);
    mx = fmaxf(mx, __shfl_xor(mx, 16));
    mx = fmaxf(mx, __shfl_xor(mx, 32));

    // defer-max (T13): only rescale when some row's max grew past THR (log2 units)
    if (__any(mx > mi + 11.f)) {
      float mn = fmaxf(mi, mx);
      float al = fexp2(mi - mn);
      li *= al;
      #pragma unroll
      for (int f = 0; f < 4; f++)
        #pragma unroll
        for (int r = 0; r < 4; r++) ot[f][r] *= al;
      mi = mn;
    }

    float rs = 0.f;
    #pragma unroll
    for (int sub = 0; sub < 4; sub++)
      #pragma unroll
      for (int r = 0; r < 4; r++) {
        float p = fexp2(st[sub][r] - mi);
        st[sub][r] = p; rs += p;
      }
    rs += __shfl_xor(rs, 16);
    rs += __shfl_xor(rs, 32);
    li += rs;

    // P round-trip through XOR-swizzled per-wave LDS (bank-balanced, 2KB/wave)
    #pragma unroll
    for (int sub = 0; sub < 4; sub++) {
      u32x2 pk2;
      pk2[0] = cvtpk(st[sub][0], st[sub][1]);
      pk2[1] = cvtpk(st[sub][2], st[sub][3]);
      *(u32x2*)(Pb + (l16*128 + ((sub*32 + quad*8) ^ x7s))) = pk2;
    }
    bf16x8 pfr0 = *(const bf16x8*)(Pb + (l16*128 + (( 0 + quad*16) ^ x7s)));
    bf16x8 pfr1 = *(const bf16x8*)(Pb + (l16*128 + ((64 + quad*16) ^ x7s)));

    __builtin_amdgcn_s_setprio(1);
    #pragma unroll
    for (int f = 0; f < 4; f++) {
      ot[f] = __builtin_amdgcn_mfma_f32_16x16x32_bf16(vf[f][0], pfr0, ot[f], 0, 0, 0);
      ot[f] = __builtin_amdgcn_mfma_f32_16x16x32_bf16(vf[f][1], pfr1, ot[f], 0, 0, 0);
    }
    __builtin_amdgcn_s_setprio(0);
    __syncthreads();
  }

  if (qg < S2_) {
    float rcp = 1.f / li;
    #pragma unroll
    for (int f = 0; f < 4; f++) {
      ushort4 pk;
      pk.x = f2bf(ot[f][0] * rcp); pk.y = f2bf(ot[f][1] * rcp);
      pk.z = f2bf(ot[f][2] * rcp); pk.w = f2bf(ot[f][3] * rcp);
      *(ushort4*)&CTX[qbase + (size_t)qg * 512 + f*16 + quad*4] = pk;
    }
  }
}

// ----------------------------------------------------------------
extern "C" void kernel_launch(void* const* d_in, const int* in_sizes, int n_in,
                              void* d_out, int out_size, void* d_ws, size_t ws_size,
                              hipStream_t stream)
{
  const float* hidden = (const float*)d_in[0];
  const int*   lens   = (const int*)d_in[1];
  const float* fw[14]; for (int i = 0; i < 14; i++) fw[i] = (const float*)d_in[2 + i];
  const float* bw[14]; for (int i = 0; i < 14; i++) bw[i] = (const float*)d_in[16 + i];
  const float* attn_g = (const float*)d_in[30];
  const float* attn_b = (const float*)d_in[31];
  const float* o_w1 = (const float*)d_in[32];
  const float* o_b1 = (const float*)d_in[33];
  const float* o_w2 = (const float*)d_in[34];
  const float* o_b2 = (const float*)d_in[35];
  const float* o_lng = (const float*)d_in[36];
  const float* o_lnb = (const float*)d_in[37];

  char* ws = (char*)d_ws;
  size_t off = 0;
  auto alloc = [&](size_t bytes)->char* {
    off = (off + 255) & ~(size_t)255;
    char* p = ws + off; off += bytes; return p;
  };

  unsigned short* fw1t = (unsigned short*)alloc((size_t)1024*1024*2);
  unsigned short* fw2t = (unsigned short*)alloc((size_t)512*1024*2);
  unsigned short* fqt  = (unsigned short*)alloc((size_t)512*512*2);
  unsigned short* fkvt = (unsigned short*)alloc((size_t)1024*512*2);  // [K(512 rows); V(512 rows)]
  unsigned short* fot  = (unsigned short*)alloc((size_t)512*512*2);
  unsigned short* bw1t = (unsigned short*)alloc((size_t)1024*1024*2);
  unsigned short* bw2t = (unsigned short*)alloc((size_t)512*1024*2);
  unsigned short* bqt  = (unsigned short*)alloc((size_t)512*512*2);
  unsigned short* bkvt = (unsigned short*)alloc((size_t)1024*512*2);
  unsigned short* bot  = (unsigned short*)alloc((size_t)512*512*2);
  unsigned short* ow1t = (unsigned short*)alloc((size_t)1024*1024*2);
  unsigned short* ow2t = (unsigned short*)alloc((size_t)1024*1024*2);
  float*          biasKV = (float*)alloc(2048*4);

  unsigned short* Xb   = (unsigned short*)alloc((size_t)M_*1024*2);
  unsigned short* big1 = (unsigned short*)alloc((size_t)2*PAD_*1024*2);
  float*          big2 = (float*)alloc((size_t)2*PAD_*512*4);
  unsigned short* LQCT = (unsigned short*)alloc((size_t)2*PAD_*512*2);
  unsigned short* Q2   = (unsigned short*)alloc((size_t)2*PAD_*512*2);

  unsigned short* H12 = big1, *KV2 = big1, *H1o = big1;
  // big2 partitions: [0 .. 2*VTS_) = T12b (bf16) then VT2 (bf16);
  //                  [2*VTS_ .. 4*VTS_) = P2b (bf16 out-proj). Exactly fills big2.
  unsigned short* T12b = (unsigned short*)big2;
  unsigned short* VT2  = (unsigned short*)big2;
  unsigned short* P2b  = (unsigned short*)big2 + 2*VTS_;
  unsigned short* LQ2 = LQCT, *CT2 = LQCT;

  lma_prep_x<<<M_, 256, 0, stream>>>(hidden, Xb);

  {
    TPack tp;
    const float* srcs[14] = { fw[0], fw[2], fw[6], fw[8], fw[10], fw[12],
                              bw[0], bw[2], bw[6], bw[8], bw[10], bw[12],
                              o_w1, o_w2 };
    unsigned short* dsts[14] = { fw1t, fw2t, fqt, fkvt, fkvt + (size_t)512*512, fot,
                                 bw1t, bw2t, bqt, bkvt, bkvt + (size_t)512*512, bot,
                                 ow1t, ow2t };
    int Ks[14] = {1024,1024,512,512,512,512, 1024,1024,512,512,512,512, 1024,1024};
    int Ns[14] = {1024, 512,512,512,512,512, 1024, 512,512,512,512,512, 1024,1024};
    for (int i = 0; i < 14; i++){ tp.src[i]=srcs[i]; tp.dst[i]=dsts[i]; tp.K[i]=Ks[i]; tp.N[i]=Ns[i]; }
    lma_transpose_all<<<dim3(32, 32, 14), 256, 0, stream>>>(tp);
  }
  lma_biascat<<<8, 256, 0, stream>>>(fw[9], fw[11], bw[9], bw[11], biasKV);

  auto G = [&](const unsigned short* A, int lda,
               const unsigned short* B0, const unsigned short* B1,
               const float* b0, const float* b1,
               void* C, int ldc, int M, int N, int K, int mode, int amap){
    int nmt = (M + 127) / 128;
    lma_gemm2<<<dim3(nmt * (N/128)), 256, 0, stream>>>(A, lda, B0, B1, b0, b1, C, ldc, M, N, K, mode, amap, nmt);
  };
  auto G8 = [&](const unsigned short* A, int lda,
                const unsigned short* B0, const unsigned short* B1,
                const float* b0, const float* b1,
                unsigned short* C, int ldc, int M, int N, int K, int mode, int amap){
    int nmt = M / 256;
    lma_gemm8<<<dim3(nmt * (N/256)), 512, 0, stream>>>(A, lda, B0, B1, b0, b1, C, ldc, M, N, K, mode, amap, nmt);
  };

  // both-branch FFN + LN + projections (rows<8192 = forward, >=8192 = backward)
  G8(Xb, 1024, fw1t, bw1t, fw[1], bw[1], H12, 1024, 2*PAD_, 1024, 1024, 2, 1); // FFN1+gelu (8-phase 256^2)
  G(H12, 1024, fw2t, bw2t, fw[3], bw[3], T12b, 512, 2*PAD_, 512, 1024, 0, 0);  // FFN2 -> bf16
  lma_ln2<<<2*M_, 256, 0, stream>>>(T12b, fw[4], fw[5], bw[4], bw[5], LQ2);
  G(LQ2, 512, fqt, bqt, fw[7], bw[7], Q2, 512, 2*PAD_, 512, 512, 1, 0);        // Q (x0.125*log2e)
  G8(Xb, 1024, fkvt, bkvt, biasKV, biasKV + 1024, KV2, 1024, 2*PAD_, 1024, 512, 0, 2); // K|V (8-phase 256^2)
  lma_vt2<<<dim3(32, 16, 16), 256, 0, stream>>>(KV2, VT2);

  lma_attn9<<<dim3(1024), 256, 0, stream>>>(Q2, KV2, VT2, CT2, lens, 0);
  lma_attn9<<<dim3(1024), 256, 0, stream>>>(Q2, KV2, VT2, CT2, lens, 1);

  G(CT2, 512, fot, bot, fw[13], bw[13], P2b, 512, 2*PAD_, 512, 512, 0, 0);     // out proj -> bf16

  lma_attn_ln<<<M_, 256, 0, stream>>>(P2b, P2b + (size_t)PAD_*512, hidden, attn_g, attn_b, Xb);

  G(Xb, 1024, ow1t, ow1t, o_b1, o_b1, H1o, 1024, M_, 1024, 1024, 2, 0);        // out FFN1+gelu
  G(H1o, 1024, ow2t, ow2t, o_b2, o_b2, (float*)d_out, 1024, M_, 1024, 1024, 4, 0); // out FFN2 -> d_out (remapped)
  lma_ln<<<M_, 256, 0, stream>>>((float*)d_out, o_lng, o_lnb, 1024, nullptr, (float*)d_out);
}

// Round 9
// 568.925 us; speedup vs baseline: 1.1215x; 1.1215x over previous
//
#include <hip/hip_runtime.h>
#include <cmath>

#define S_ 1024
#define B_ 8
#define H_ 512
#define S2_ 1022
#define M_ (B_*S2_)     // 8176
#define PAD_ 8192
#define VTS_ ((size_t)8*8*64*1024)   // VT per-branch stride (4194304 shorts)

typedef __attribute__((ext_vector_type(8))) short bf16x8;
typedef __attribute__((ext_vector_type(4))) float f32x4;
typedef __attribute__((ext_vector_type(4))) unsigned int u32x4;
typedef __attribute__((ext_vector_type(2))) unsigned int u32x2;

__device__ __forceinline__ unsigned short f2bf(float f){
  unsigned int u = __float_as_uint(f);
  return (unsigned short)((u + 0x7fffu + ((u>>16)&1u)) >> 16);
}
__device__ __forceinline__ float bf2f(unsigned short u){
  return __uint_as_float((unsigned int)u << 16);
}
// tanh-approx gelu: x*sigmoid(2*(c1 x + c2 x^3)); |err vs erf-gelu| < ~3e-4
__device__ __forceinline__ float fgelu(float x){
  float u = x * (0.7978845608f + 0.0356774081f * x * x);
  return x / (1.f + __expf(-2.f * u));
}
// raw 2^x (v_exp_f32 is natively base-2)
__device__ __forceinline__ float fexp2(float x){
  float r; asm("v_exp_f32 %0, %1" : "=v"(r) : "v"(x)); return r;
}
// hardware packed f32->bf16 (RNE), lo -> bits[15:0], hi -> bits[31:16]
__device__ __forceinline__ unsigned int cvtpk(float lo, float hi){
  unsigned int r; asm("v_cvt_pk_bf16_f32 %0, %1, %2" : "=v"(r) : "v"(lo), "v"(hi)); return r;
}

__device__ __forceinline__ void glds16(const void* g, void* l){
  __builtin_amdgcn_global_load_lds((const __attribute__((address_space(1))) unsigned int*)g,
                                   (__attribute__((address_space(3))) unsigned int*)l, 16, 0, 0);
}
#define SB() __builtin_amdgcn_sched_barrier(0)

// ---------------------------------------------------------------- prep: X = [f[:-2], bk[2:]] bf16 (M_ x 1024)
__global__ __launch_bounds__(256) void lma_prep_x(const float* __restrict__ hidden,
                                                  unsigned short* __restrict__ Xb){
  int m = blockIdx.x; int dq = threadIdx.x * 4;
  int b = m / S2_, s = m - b * S2_;
  int srow = (dq < 512) ? s : (s + 2);
  const float* src = hidden + ((size_t)srow * B_ + b) * 1024 + dq;
  f32x4 v = *(const f32x4*)src;
  union { u32x2 u; unsigned short s4[4]; } pk;
  #pragma unroll
  for (int j = 0; j < 4; j++) pk.s4[j] = f2bf(v[j]);
  *(u32x2*)&Xb[(size_t)m * 1024 + dq] = pk.u;
}

// ---------------------------------------------------------------- batched weight transpose+cast
struct TPack {
  const float* src[14];
  unsigned short* dst[14];
  int K[14];
  int N[14];
};
__global__ __launch_bounds__(256) void lma_transpose_all(TPack p){
  int idx = blockIdx.z;
  int K = p.K[idx], N = p.N[idx];
  int kb = blockIdx.x * 32, nb = blockIdx.y * 32;
  if (kb >= K || nb >= N) return;
  const float* W = p.src[idx];
  unsigned short* WT = p.dst[idx];
  __shared__ float t[32][33];
  int tx = threadIdx.x & 31, ty = threadIdx.x >> 5;
  #pragma unroll
  for (int i = ty; i < 32; i += 8) t[i][tx] = W[(size_t)(kb + i) * N + nb + tx];
  __syncthreads();
  #pragma unroll
  for (int i = ty; i < 32; i += 8) WT[(size_t)(nb + i) * K + kb + tx] = f2bf(t[tx][i]);
}

// ---------------------------------------------------------------- concat K/V biases
__global__ __launch_bounds__(256) void lma_biascat(const float* __restrict__ fk, const float* __restrict__ fv,
                                                   const float* __restrict__ bk, const float* __restrict__ bv,
                                                   float* __restrict__ out){
  int i = blockIdx.x * 256 + threadIdx.x;     // 0..2047
  int fb = i >> 10, col = i & 1023;
  const float* s = (col < 512) ? (fb ? bk : fk) : (fb ? bv : fv);
  out[i] = s[col & 511];
}

// ---------------------------------------------------------------- V (in KV2, cols 512..1023) -> VT2[fb][b][h][d][s pad 1024]
// Pad cols s in [S2_,1024) ZEROED (aliased buffer may hold bf16-NaN bit patterns).
__global__ __launch_bounds__(256) void lma_vt2(const unsigned short* __restrict__ KV2,
                                               unsigned short* __restrict__ VT2){
  __shared__ unsigned short t[32][34];
  int s0 = blockIdx.x * 32, c0 = blockIdx.y * 32;
  int z = blockIdx.z, fb = z >> 3, b = z & 7;
  const unsigned short* V = KV2 + (size_t)fb * PAD_ * 1024 + 512;
  unsigned short* VT = VT2 + (size_t)fb * VTS_;
  int tx = threadIdx.x & 31, ty = threadIdx.x >> 5;
  #pragma unroll
  for (int i = ty; i < 32; i += 8){
    int s = s0 + i; if (s > S2_-1) s = S2_-1;
    t[i][tx] = V[((size_t)b * S2_ + s) * 1024 + c0 + tx];
  }
  __syncthreads();
  int s = s0 + tx;
  #pragma unroll
  for (int i = ty; i < 32; i += 8){
    int c = c0 + i, h = c >> 6, d = c & 63;
    VT[(((size_t)b * 8 + h) * 64 + d) * 1024 + s] = (s < S2_) ? t[tx][i] : (unsigned short)0;
  }
}

// ---------------------------------------------------------------- 128^2 2-phase GEMM (small-grid shapes)
// Swizzle FIX (round 8): stage block ^(lane>>3)&3, read ^(l16>>1)&3 -> 16B
// positions (4*(row&1) + slot) cover all 8 per 128B -> 2 lanes/pos = FREE
// (old lane&3/l16&3 form ignored row parity: 4-way conflict).
// Epilogue: f-INNER store order (wave completes each 128B C-line temporally ->
// no partial-line write amplification; was 56MB written for 33.5MB C) + bias hoist.
__global__ __launch_bounds__(256) void lma_gemm2(
    const unsigned short* __restrict__ A, int lda,
    const unsigned short* __restrict__ Bt0, const unsigned short* __restrict__ Bt1,
    const float* __restrict__ bias0, const float* __restrict__ bias1,
    void* __restrict__ Cout, int ldc,
    int M, int N, int K, int mode, int amap, int nmt)
{
  __shared__ unsigned short Al[128*32];
  __shared__ unsigned short Bl[128*32];
  const int tid = threadIdx.x;
  const int w = tid >> 6, lane = tid & 63, quad = lane >> 4, l16 = lane & 15;
  const int mt = blockIdx.x % nmt, nt = blockIdx.x / nmt;
  const int m0 = mt * 128, n0 = nt * 128;
  const int brch = m0 >> 13;
  const unsigned short* Bt = brch ? Bt1 : Bt0;
  const float* bias = brch ? bias1 : bias0;
  const int coloff = (amap == 2 && brch) ? 512 : 0;
  const int wm = (w >> 1) * 64, wn = (w & 1) * 64;

  f32x4 acc[4][4];
  #pragma unroll
  for (int i = 0; i < 4; i++)
    #pragma unroll
    for (int f = 0; f < 4; f++) acc[i][f] = f32x4{0.f,0.f,0.f,0.f};

  const int srow = lane >> 2;
  const int spc  = (((lane & 3) ^ ((lane >> 3) & 3))) * 8;   // pre-swizzled source block
  const int rswz = (l16 >> 1) & 3;                            // read-side XOR

  for (int k0 = 0; k0 < K; k0 += 32) {
    #pragma unroll
    for (int c = 0; c < 2; c++) {
      int ra = w*32 + c*16 + srow;
      int ga = m0 + ra;
      int ar;
      if (amap == 0) { ar = (ga > M-1) ? (M-1) : ga; }
      else { ar = ga & (PAD_-1); if (ar > M_-1) ar = M_-1; }
      glds16(A + (size_t)ar * lda + coloff + k0 + spc, &Al[(w*32 + c*16) * 32]);
      int gb = n0 + ra; if (gb > N-1) gb = N-1;
      glds16(Bt + (size_t)gb * K + k0 + spc, &Bl[(w*32 + c*16) * 32]);
    }
    __syncthreads();
    bf16x8 af[4], bfr[4];
    #pragma unroll
    for (int i = 0; i < 4; i++) af[i]  = *(const bf16x8*)&Al[(wm + i*16 + l16)*32 + ((quad ^ rswz) * 8)];
    #pragma unroll
    for (int f = 0; f < 4; f++) bfr[f] = *(const bf16x8*)&Bl[(wn + f*16 + l16)*32 + ((quad ^ rswz) * 8)];
    #pragma unroll
    for (int i = 0; i < 4; i++)
      #pragma unroll
      for (int f = 0; f < 4; f++)
        acc[i][f] = __builtin_amdgcn_mfma_f32_16x16x32_bf16(af[i], bfr[f], acc[i][f], 0, 0, 0);
    __syncthreads();
  }

  float bv[4];
  #pragma unroll
  for (int f = 0; f < 4; f++) bv[f] = bias ? bias[n0 + wn + f*16 + l16] : 0.f;
  const int col0 = n0 + wn + l16;
  #pragma unroll
  for (int i = 0; i < 4; i++) {
    #pragma unroll
    for (int r = 0; r < 4; r++) {
      int row = m0 + wm + i*16 + quad*4 + r;
      if (row < M) {
        #pragma unroll
        for (int f = 0; f < 4; f++) {
          float v = acc[i][f][r] + bv[f];
          if (mode == 2) v = fgelu(v);
          else if (mode == 1) v *= 0.18033688011112042f;   // 0.125 * log2(e)
          if (mode <= 2) ((unsigned short*)Cout)[(size_t)row * ldc + col0 + f*16] = f2bf(v);
          else if (mode == 3) ((float*)Cout)[(size_t)row * ldc + col0 + f*16] = v;
          else {
            int sr = row % S2_, bb2 = row / S2_;
            ((float*)Cout)[((size_t)sr * B_ + bb2) * ldc + col0 + f*16] = v;
          }
        }
      }
    }
  }
}

// ---------------------------------------------------------------- 256^2 8-phase GEMM v3 (T2+T3+T4+T5)
// Round-8 fixes vs v2:
// (1) SWIZZLE: phys 16B-slot = logical ^ (row & 7) (FULL 3 bits; v2 used
//     ((row>>2)&3)<<1 -> only 4 slots -> 4-way conflict, 3.67M cycles).
//     Now a quad's 16 lanes (rows r..r+15) cover all 8 slots x2 = 2-way = free.
//     Stage side pre-applies inverse on global source (rule 21).
// (2) one stage per phase: s1..s8 = {b.B0, b.B1, b.A1, a+2.A0, a+2.B1,
//     a+2.A1, a+2.B0, b+2.A0}. Liveness (read order ph1 A0B0, ph2 B1, ph3 A1,
//     ph4 B0 | same for buf1 ph5-8): every stage is >=2 barriers after its
//     region's last read (s1: prev-ph8 read; s4: ph1; s7: ph4; s8: ph5; ...).
// (3) waits: vmcnt(6) after ph4 (drains s8_prev,s1 -> covers ph5 reads),
//     after ph5 (drains s2 -> ph6), after ph6 (drains s3 -> ph7);
//     vmcnt(2) after ph8 (drains s4..s7 -> next ph1-4; leaves s8). Never 0.
// (4) epilogue: f-inner store order + hoisted bias (kills ~32MB partial-line
//     write amplification; WRITE_SIZE was 65.5MB for 33.5MB of C).
__global__ __launch_bounds__(512, 2) void lma_gemm8(
    const unsigned short* __restrict__ A, int lda,
    const unsigned short* __restrict__ Bt0, const unsigned short* __restrict__ Bt1,
    const float* __restrict__ bias0, const float* __restrict__ bias1,
    unsigned short* __restrict__ Cout, int ldc,
    int M, int N, int K, int mode, int amap, int nmt)
{
  __shared__ unsigned short Ls[2][2][256*64];   // [buf][0=A,1=B][row*64+k]
  const int tid = threadIdx.x;
  const int w = tid >> 6, lane = tid & 63, quad = lane >> 4, l16 = lane & 15;
  const int mt = blockIdx.x % nmt, nt = blockIdx.x / nmt;
  const int m0 = mt * 256, n0 = nt * 256;
  const int brch = m0 >> 13;
  const unsigned short* Bt = brch ? Bt1 : Bt0;
  const float* bias = brch ? bias1 : bias0;
  const int coloff = (amap == 2 && brch) ? 512 : 0;
  const int wm = (w >> 2) * 128, wn = (w & 3) * 64;

  f32x4 acc[8][4];
  #pragma unroll
  for (int i = 0; i < 8; i++)
    #pragma unroll
    for (int f = 0; f < 4; f++) acc[i][f] = f32x4{0.f,0.f,0.f,0.f};

  const int lrow8 = lane >> 3;     // 0..7
  const int lkb   = lane & 7;      // phys slot this lane stages
  const int NT = K >> 6;           // K-tiles (even for K in {512,1024})

  // K-invariant per-thread stage pointers + uniform LDS dest offsets
  const unsigned short* aP[2][2]; const unsigned short* bP[2][2];
  int aD[2][2], bD[2][2];
  #pragma unroll
  for (int hf = 0; hf < 2; hf++)
    #pragma unroll
    for (int c = 0; c < 2; c++) {
      int rtA = (w>>2)*128 + hf*64 + ((w&3)*2 + c)*8 + lrow8;
      int kbA = lkb ^ (rtA & 7);
      int ga = m0 + rtA;
      int ar;
      if (amap == 0) { ar = (ga > M-1) ? (M-1) : ga; }
      else { ar = ga & (PAD_-1); if (ar > M_-1) ar = M_-1; }
      aP[hf][c] = A + (size_t)ar * lda + coloff + kbA*8;
      aD[hf][c] = ((w>>2)*128 + hf*64 + ((w&3)*2 + c)*8) * 64;
      int rtB = (w>>1)*64 + hf*32 + ((w&1)*2 + c)*8 + lrow8;
      int kbB = lkb ^ (rtB & 7);
      int gb = n0 + rtB; if (gb > N-1) gb = N-1;
      bP[hf][c] = Bt + (size_t)gb * K + kbB*8;
      bD[hf][c] = ((w>>1)*64 + hf*32 + ((w&1)*2 + c)*8) * 64;
    }

  bf16x8 af[4][2], bf[2][2];

  #define STA(buf, hf, kt) { _Pragma("unroll") for (int c = 0; c < 2; c++) \
      glds16(aP[hf][c] + (size_t)(kt)*64, &Ls[buf][0][aD[hf][c]]); }
  #define STB(buf, hf, kt) { _Pragma("unroll") for (int c = 0; c < 2; c++) \
      glds16(bP[hf][c] + (size_t)(kt)*64, &Ls[buf][1][bD[hf][c]]); }
  #define LDA8(buf, mq) { _Pragma("unroll") for (int j = 0; j < 4; j++){ \
      int rt = wm + (mq)*64 + j*16 + l16; \
      const unsigned short* base = &Ls[buf][0][rt*64]; \
      int f_ = rt & 7; \
      af[j][0] = *(const bf16x8*)(base + ((    quad) ^ f_)*8); \
      af[j][1] = *(const bf16x8*)(base + ((4 + quad) ^ f_)*8); } }
  #define LDB8(buf, nq) { _Pragma("unroll") for (int j = 0; j < 2; j++){ \
      int rt = wn + (nq)*32 + j*16 + l16; \
      const unsigned short* base = &Ls[buf][1][rt*64]; \
      int f_ = rt & 7; \
      bf[j][0] = *(const bf16x8*)(base + ((    quad) ^ f_)*8); \
      bf[j][1] = *(const bf16x8*)(base + ((4 + quad) ^ f_)*8); } }
  #define MFMAQ(mq, nq) { __builtin_amdgcn_s_setprio(1); \
      _Pragma("unroll") for (int j = 0; j < 4; j++) \
        _Pragma("unroll") for (int j2 = 0; j2 < 2; j2++){ \
          acc[(mq)*4+j][(nq)*2+j2] = __builtin_amdgcn_mfma_f32_16x16x32_bf16(af[j][0], bf[j2][0], acc[(mq)*4+j][(nq)*2+j2], 0, 0, 0); \
          acc[(mq)*4+j][(nq)*2+j2] = __builtin_amdgcn_mfma_f32_16x16x32_bf16(af[j][1], bf[j2][1], acc[(mq)*4+j][(nq)*2+j2], 0, 0, 0); } \
      __builtin_amdgcn_s_setprio(0); }
  #define BAR()   { SB(); __builtin_amdgcn_s_barrier(); SB(); }
  #define LGKM0() { asm volatile("s_waitcnt lgkmcnt(0)" ::: "memory"); SB(); }
  #define VM6()   { asm volatile("s_waitcnt vmcnt(6)"   ::: "memory"); SB(); }
  #define VM2()   { asm volatile("s_waitcnt vmcnt(2)"   ::: "memory"); SB(); }

  // prologue: t0 all 4 halves + t1.A0 (s8 seed); drain t0, leave t1.A0
  STA(0, 0, 0); STB(0, 0, 0); STB(0, 1, 0); STA(0, 1, 0);
  STA(1, 0, 1);
  asm volatile("s_waitcnt vmcnt(2)" ::: "memory"); SB();
  BAR();

  const int NI = NT >> 1;
  for (int i = 0; i < NI; i++) {
    const int tb  = 2*i + 1;
    int ta2 = 2*i + 2; if (ta2 > NT-1) ta2 = NT-1;
    int tb2 = 2*i + 3; if (tb2 > NT-1) tb2 = NT-1;

    // ph1 (buf0: mq0,nq0)  s1 = b.B0
    LDA8(0, 0); LDB8(0, 0); STB(1, 0, tb);
    BAR(); LGKM0(); MFMAQ(0, 0); BAR();
    // ph2 (buf0: mq0,nq1)  s2 = b.B1
    LDB8(0, 1); STB(1, 1, tb);
    BAR(); LGKM0(); MFMAQ(0, 1); BAR();
    // ph3 (buf0: mq1,nq1)  s3 = b.A1
    LDA8(0, 1); STA(1, 1, tb);
    BAR(); LGKM0(); MFMAQ(1, 1); BAR();
    // ph4 (buf0: mq1,nq0)  s4 = a+2.A0
    LDB8(0, 0); STA(0, 0, ta2);
    BAR(); LGKM0(); MFMAQ(1, 0); VM6(); BAR();
    // ph5 (buf1: mq0,nq0)  s5 = a+2.B1
    LDA8(1, 0); LDB8(1, 0); STB(0, 1, ta2);
    BAR(); LGKM0(); MFMAQ(0, 0); VM6(); BAR();
    // ph6 (buf1: mq0,nq1)  s6 = a+2.A1
    LDB8(1, 1); STA(0, 1, ta2);
    BAR(); LGKM0(); MFMAQ(0, 1); VM6(); BAR();
    // ph7 (buf1: mq1,nq1)  s7 = a+2.B0
    LDA8(1, 1); STB(0, 0, ta2);
    BAR(); LGKM0(); MFMAQ(1, 1); BAR();
    // ph8 (buf1: mq1,nq0)  s8 = b+2.A0
    LDB8(1, 0); STA(1, 0, tb2);
    BAR(); LGKM0(); MFMAQ(1, 0); VM2(); BAR();
  }
  asm volatile("s_waitcnt vmcnt(0)" ::: "memory");

  float bv[4];
  #pragma unroll
  for (int f = 0; f < 4; f++) bv[f] = bias ? bias[n0 + wn + f*16 + l16] : 0.f;
  const int col0 = n0 + wn + l16;
  #pragma unroll
  for (int i2 = 0; i2 < 8; i2++) {
    #pragma unroll
    for (int r = 0; r < 4; r++) {
      int row = m0 + wm + i2*16 + quad*4 + r;
      if (row < M) {
        #pragma unroll
        for (int f = 0; f < 4; f++) {
          float v = acc[i2][f][r] + bv[f];
          if (mode == 2) v = fgelu(v);
          Cout[(size_t)row * ldc + col0 + f*16] = f2bf(v);
        }
      }
    }
  }
  #undef STA
  #undef STB
  #undef LDA8
  #undef LDB8
  #undef MFMAQ
  #undef BAR
  #undef LGKM0
  #undef VM6
  #undef VM2
}

// ---------------------------------------------------------------- block reduction helper
__device__ __forceinline__ void lma_red2(float& s, float& sq){
  __shared__ float red[16];
  #pragma unroll
  for (int msk = 1; msk < 64; msk <<= 1){ s += __shfl_xor(s, msk); sq += __shfl_xor(sq, msk); }
  int w = threadIdx.x >> 6;
  if ((threadIdx.x & 63) == 0){ red[w] = s; red[8 + w] = sq; }
  __syncthreads();
  s  = red[0] + red[1] + red[2] + red[3];
  sq = red[8] + red[9] + red[10] + red[11];
}

// ---------------------------------------------------------------- generic LN (f32 in, bf16 or f32 out)
__global__ __launch_bounds__(256) void lma_ln(const float* __restrict__ in,
                                              const float* __restrict__ g, const float* __restrict__ bb,
                                              int D, unsigned short* __restrict__ obf, float* __restrict__ of32){
  int row = blockIdx.x, t = threadIdx.x;
  const float* x = in + (size_t)row * D;
  float s = 0.f, sq = 0.f;
  for (int d = t; d < D; d += 256){ float v = x[d]; s += v; sq += v * v; }
  lma_red2(s, sq);
  float mean = s / D;
  float var = sq / D - mean * mean;
  float rstd = rsqrtf(fmaxf(var, 0.f) + 1e-12f);
  if (obf) {
    for (int d = t; d < D; d += 256) obf[(size_t)row * D + d] = f2bf((x[d] - mean) * rstd * g[d] + bb[d]);
  } else {
    for (int d = t; d < D; d += 256) of32[(size_t)row * D + d] = (x[d] - mean) * rstd * g[d] + bb[d];
  }
}

// ---------------------------------------------------------------- branch-combined LN over T12b (bf16, D=512) -> LQ2 bf16
__global__ __launch_bounds__(256) void lma_ln2(const unsigned short* __restrict__ T12b,
                                               const float* __restrict__ fg, const float* __restrict__ fbb,
                                               const float* __restrict__ bg, const float* __restrict__ bbb,
                                               unsigned short* __restrict__ LQ2){
  int m = blockIdx.x, t = threadIdx.x;           // 0..2*M_-1
  int fb = (m >= M_);
  int idx = m - fb * M_;
  const float* g = fb ? bg : fg;
  const float* bb = fb ? bbb : fbb;
  const unsigned short* x = T12b + ((size_t)fb * PAD_ + idx) * 512;
  unsigned short* o = LQ2 + ((size_t)fb * PAD_ + idx) * 512;
  float v0 = bf2f(x[t]), v1 = bf2f(x[t + 256]);
  float s = v0 + v1, sq = v0*v0 + v1*v1;
  lma_red2(s, sq);
  float mean = s / 512.f;
  float var = sq / 512.f - mean * mean;
  float rstd = rsqrtf(fmaxf(var, 0.f) + 1e-12f);
  o[t]       = f2bf((v0 - mean) * rstd * g[t]       + bb[t]);
  o[t + 256] = f2bf((v1 - mean) * rstd * g[t + 256] + bb[t + 256]);
}

// ---------------------------------------------------------------- attn LN: LN(residual(hidden)+[pf,pb](bf16)) -> bf16 (M_ x 1024)
__global__ __launch_bounds__(256) void lma_attn_ln(const unsigned short* __restrict__ pf,
                                                   const unsigned short* __restrict__ pb,
                                                   const float* __restrict__ hidden,
                                                   const float* __restrict__ g, const float* __restrict__ bb,
                                                   unsigned short* __restrict__ out){
  int m = blockIdx.x, t = threadIdx.x;
  int b = m / S2_, s = m - b * S2_;
  const float* hf = hidden + ((size_t)s       * B_ + b) * 1024;
  const float* hb = hidden + ((size_t)(s + 2) * B_ + b) * 1024;
  float v[4]; float sum = 0.f, sq = 0.f;
  #pragma unroll
  for (int j = 0; j < 4; j++){
    int d = t + j * 256;
    float x = (d < 512) ? (bf2f(pf[(size_t)m * 512 + d]) + hf[d])
                        : (bf2f(pb[(size_t)m * 512 + (d - 512)]) + hb[d]);
    v[j] = x; sum += x; sq += x * x;
  }
  lma_red2(sum, sq);
  float mean = sum / 1024.f;
  float var = sq / 1024.f - mean * mean;
  float rstd = rsqrtf(fmaxf(var, 0.f) + 1e-12f);
  #pragma unroll
  for (int j = 0; j < 4; j++){
    int d = t + j * 256;
    out[(size_t)m * 1024 + d] = f2bf((v[j] - mean) * rstd * g[d] + bb[d]);
  }
}

// ---------------------------------------------------------------- combined flash attention v9 (proven structure, fb split;
// round-8: qt permutation REVERTED — R7 total regressed 10us with it)
__global__ __launch_bounds__(256, 4) void lma_attn9(const unsigned short* __restrict__ Q2,
                                                    const unsigned short* __restrict__ KV2,
                                                    const unsigned short* __restrict__ VT2,
                                                    unsigned short* __restrict__ CT2,
                                                    const int* __restrict__ lens,
                                                    int fb){
  __shared__ unsigned short Kl[64*64];
  __shared__ unsigned short Vl[64*64];
  __shared__ __align__(16) unsigned short Pl[4][16*64];

  const int tid = threadIdx.x;
  const int w = tid >> 6, lane = tid & 63, quad = lane >> 4, l16 = lane & 15;
  const int id = blockIdx.x;                 // 1024 blocks: [qt:4][h:3][b:3]
  const int qt = id >> 6, h = (id >> 3) & 7, b = id & 7;
  const int backward = fb;
  const int L2 = lens[b] - 2;
  const int q0wg = qt * 64;
  const int q0 = q0wg + w * 16;
  const int qg = q0 + l16;
  const int qload = (qg > S2_-1) ? (S2_-1) : qg;

  const size_t qbase  = ((size_t)b * S2_) * 512  + h * 64;
  const size_t kbase  = ((size_t)b * S2_) * 1024 + h * 64;
  const size_t vtbase = ((size_t)(b * 8 + h) * 64) * 1024;
  char* Pb = (char*)&Pl[w][0];

  const int lrow = lane >> 3;
  const int g0s  = (lane & 7) ^ lrow;
  const int x7   = l16 & 7;
  const int x7s  = x7 << 4;

  const unsigned short* Q  = Q2  + (size_t)fb * PAD_ * 512;
  const unsigned short* Kx = KV2 + (size_t)fb * PAD_ * 1024;
  const unsigned short* VT = VT2 + (size_t)fb * VTS_;
  unsigned short* CTX      = CT2 + (size_t)fb * PAD_ * 512;

  bf16x8 qf[2];
  {
    const unsigned short* qp = Q + qbase + (size_t)qload * 512 + quad * 8;
    qf[0] = *(const bf16x8*)(qp);
    qf[1] = *(const bf16x8*)(qp + 32);
  }

  float mi = -3e38f, li = 0.f;
  f32x4 ot[4];
  #pragma unroll
  for (int f = 0; f < 4; f++) ot[f] = f32x4{0.f,0.f,0.f,0.f};

  int klo = 0, khi = S2_ - 1;
  if (q0wg + 63 < L2) {
    if (!backward) khi = q0wg + 63;
    else { klo = q0wg; khi = L2 - 1; }
  }

  for (int kt0 = klo; kt0 <= khi; kt0 += 64) {
    #pragma unroll
    for (int c = 0; c < 2; c++) {
      int r = w*16 + c*8 + lrow;
      int kr = kt0 + r; if (kr > S2_-1) kr = S2_-1;
      glds16(Kx + kbase + (size_t)kr * 1024 + g0s * 8, &Kl[(w*16 + c*8) * 64]);
      glds16(VT + vtbase + (size_t)r * 1024 + kt0 + g0s * 8, &Vl[(w*16 + c*8) * 64]);
    }
    __syncthreads();

    bf16x8 kf[4][2], vf[4][2];
    #pragma unroll
    for (int sub = 0; sub < 4; sub++) {
      const unsigned short* kp = &Kl[(sub*16 + l16) * 64];
      kf[sub][0] = *(const bf16x8*)(kp + (( quad      ^ x7) * 8));
      kf[sub][1] = *(const bf16x8*)(kp + (((quad + 4) ^ x7) * 8));
    }
    #pragma unroll
    for (int f = 0; f < 4; f++) {
      const unsigned short* vp = &Vl[(f*16 + l16) * 64];
      vf[f][0] = *(const bf16x8*)(vp + (( quad      ^ x7) * 8));
      vf[f][1] = *(const bf16x8*)(vp + (((quad + 4) ^ x7) * 8));
    }

    f32x4 st[4];
    __builtin_amdgcn_s_setprio(1);
    #pragma unroll
    for (int sub = 0; sub < 4; sub++) {
      f32x4 s = f32x4{0.f,0.f,0.f,0.f};
      s = __builtin_amdgcn_mfma_f32_16x16x32_bf16(kf[sub][0], qf[0], s, 0, 0, 0);
      s = __builtin_amdgcn_mfma_f32_16x16x32_bf16(kf[sub][1], qf[1], s, 0, 0, 0);
      st[sub] = s;
    }
    __builtin_amdgcn_s_setprio(0);

    // interior-tile skip: wave-uniform "every (lane,r) passes the mask"
    {
      bool tail = (kt0 + 63 > S2_ - 1);
      bool full;
      if (!backward) full = !tail && ((kt0 + 63 <= q0) || (q0 >= L2));
      else           full = !tail && ((q0 >= L2) || ((kt0 >= q0 + 15) && (kt0 + 63 < L2)));
      if (!full) {
        #pragma unroll
        for (int sub = 0; sub < 4; sub++) {
          #pragma unroll
          for (int r = 0; r < 4; r++) {
            int kg = kt0 + sub*16 + quad*4 + r;
            bool ok;
            if (!backward) ok = (kg < S2_) && ((qg >= L2) || (kg <= qg));
            else           ok = (kg < S2_) && ((qg >= L2) || ((kg >= qg) && (kg < L2)));
            if (!ok) st[sub][r] = -3e38f;
          }
        }
      }
    }

    float mx = -3e38f;
    #pragma unroll
    for (int sub = 0; sub < 4; sub++)
      #pragma unroll
      for (int r = 0; r < 4; r++) mx = fmaxf(mx, st[sub][r]);
    mx = fmaxf(mx, __shfl_xor(mx, 16));
    mx = fmaxf(mx, __shfl_xor(mx, 32));

    // defer-max (T13): only rescale when some row's max grew past THR (log2 units)
    if (__any(mx > mi + 11.f)) {
      float mn = fmaxf(mi, mx);
      float al = fexp2(mi - mn);
      li *= al;
      #pragma unroll
      for (int f = 0; f < 4; f++)
        #pragma unroll
        for (int r = 0; r < 4; r++) ot[f][r] *= al;
      mi = mn;
    }

    float rs = 0.f;
    #pragma unroll
    for (int sub = 0; sub < 4; sub++)
      #pragma unroll
      for (int r = 0; r < 4; r++) {
        float p = fexp2(st[sub][r] - mi);
        st[sub][r] = p; rs += p;
      }
    rs += __shfl_xor(rs, 16);
    rs += __shfl_xor(rs, 32);
    li += rs;

    // P round-trip through XOR-swizzled per-wave LDS (bank-balanced, 2KB/wave)
    #pragma unroll
    for (int sub = 0; sub < 4; sub++) {
      u32x2 pk2;
      pk2[0] = cvtpk(st[sub][0], st[sub][1]);
      pk2[1] = cvtpk(st[sub][2], st[sub][3]);
      *(u32x2*)(Pb + (l16*128 + ((sub*32 + quad*8) ^ x7s))) = pk2;
    }
    bf16x8 pfr0 = *(const bf16x8*)(Pb + (l16*128 + (( 0 + quad*16) ^ x7s)));
    bf16x8 pfr1 = *(const bf16x8*)(Pb + (l16*128 + ((64 + quad*16) ^ x7s)));

    __builtin_amdgcn_s_setprio(1);
    #pragma unroll
    for (int f = 0; f < 4; f++) {
      ot[f] = __builtin_amdgcn_mfma_f32_16x16x32_bf16(vf[f][0], pfr0, ot[f], 0, 0, 0);
      ot[f] = __builtin_amdgcn_mfma_f32_16x16x32_bf16(vf[f][1], pfr1, ot[f], 0, 0, 0);
    }
    __builtin_amdgcn_s_setprio(0);
    __syncthreads();
  }

  if (qg < S2_) {
    float rcp = 1.f / li;
    #pragma unroll
    for (int f = 0; f < 4; f++) {
      ushort4 pk;
      pk.x = f2bf(ot[f][0] * rcp); pk.y = f2bf(ot[f][1] * rcp);
      pk.z = f2bf(ot[f][2] * rcp); pk.w = f2bf(ot[f][3] * rcp);
      *(ushort4*)&CTX[qbase + (size_t)qg * 512 + f*16 + quad*4] = pk;
    }
  }
}

// ----------------------------------------------------------------
extern "C" void kernel_launch(void* const* d_in, const int* in_sizes, int n_in,
                              void* d_out, int out_size, void* d_ws, size_t ws_size,
                              hipStream_t stream)
{
  const float* hidden = (const float*)d_in[0];
  const int*   lens   = (const int*)d_in[1];
  const float* fw[14]; for (int i = 0; i < 14; i++) fw[i] = (const float*)d_in[2 + i];
  const float* bw[14]; for (int i = 0; i < 14; i++) bw[i] = (const float*)d_in[16 + i];
  const float* attn_g = (const float*)d_in[30];
  const float* attn_b = (const float*)d_in[31];
  const float* o_w1 = (const float*)d_in[32];
  const float* o_b1 = (const float*)d_in[33];
  const float* o_w2 = (const float*)d_in[34];
  const float* o_b2 = (const float*)d_in[35];
  const float* o_lng = (const float*)d_in[36];
  const float* o_lnb = (const float*)d_in[37];

  char* ws = (char*)d_ws;
  size_t off = 0;
  auto alloc = [&](size_t bytes)->char* {
    off = (off + 255) & ~(size_t)255;
    char* p = ws + off; off += bytes; return p;
  };

  unsigned short* fw1t = (unsigned short*)alloc((size_t)1024*1024*2);
  unsigned short* fw2t = (unsigned short*)alloc((size_t)512*1024*2);
  unsigned short* fqt  = (unsigned short*)alloc((size_t)512*512*2);
  unsigned short* fkvt = (unsigned short*)alloc((size_t)1024*512*2);  // [K(512 rows); V(512 rows)]
  unsigned short* fot  = (unsigned short*)alloc((size_t)512*512*2);
  unsigned short* bw1t = (unsigned short*)alloc((size_t)1024*1024*2);
  unsigned short* bw2t = (unsigned short*)alloc((size_t)512*1024*2);
  unsigned short* bqt  = (unsigned short*)alloc((size_t)512*512*2);
  unsigned short* bkvt = (unsigned short*)alloc((size_t)1024*512*2);
  unsigned short* bot  = (unsigned short*)alloc((size_t)512*512*2);
  unsigned short* ow1t = (unsigned short*)alloc((size_t)1024*1024*2);
  unsigned short* ow2t = (unsigned short*)alloc((size_t)1024*1024*2);
  float*          biasKV = (float*)alloc(2048*4);

  unsigned short* Xb   = (unsigned short*)alloc((size_t)M_*1024*2);
  unsigned short* big1 = (unsigned short*)alloc((size_t)2*PAD_*1024*2);
  float*          big2 = (float*)alloc((size_t)2*PAD_*512*4);
  unsigned short* LQCT = (unsigned short*)alloc((size_t)2*PAD_*512*2);
  unsigned short* Q2   = (unsigned short*)alloc((size_t)2*PAD_*512*2);

  unsigned short* H12 = big1, *KV2 = big1, *H1o = big1;
  // big2 partitions: [0 .. 2*VTS_) = T12b (bf16) then VT2 (bf16);
  //                  [2*VTS_ .. 4*VTS_) = P2b (bf16 out-proj). Exactly fills big2.
  unsigned short* T12b = (unsigned short*)big2;
  unsigned short* VT2  = (unsigned short*)big2;
  unsigned short* P2b  = (unsigned short*)big2 + 2*VTS_;
  unsigned short* LQ2 = LQCT, *CT2 = LQCT;

  lma_prep_x<<<M_, 256, 0, stream>>>(hidden, Xb);

  {
    TPack tp;
    const float* srcs[14] = { fw[0], fw[2], fw[6], fw[8], fw[10], fw[12],
                              bw[0], bw[2], bw[6], bw[8], bw[10], bw[12],
                              o_w1, o_w2 };
    unsigned short* dsts[14] = { fw1t, fw2t, fqt, fkvt, fkvt + (size_t)512*512, fot,
                                 bw1t, bw2t, bqt, bkvt, bkvt + (size_t)512*512, bot,
                                 ow1t, ow2t };
    int Ks[14] = {1024,1024,512,512,512,512, 1024,1024,512,512,512,512, 1024,1024};
    int Ns[14] = {1024, 512,512,512,512,512, 1024, 512,512,512,512,512, 1024,1024};
    for (int i = 0; i < 14; i++){ tp.src[i]=srcs[i]; tp.dst[i]=dsts[i]; tp.K[i]=Ks[i]; tp.N[i]=Ns[i]; }
    lma_transpose_all<<<dim3(32, 32, 14), 256, 0, stream>>>(tp);
  }
  lma_biascat<<<8, 256, 0, stream>>>(fw[9], fw[11], bw[9], bw[11], biasKV);

  auto G = [&](const unsigned short* A, int lda,
               const unsigned short* B0, const unsigned short* B1,
               const float* b0, const float* b1,
               void* C, int ldc, int M, int N, int K, int mode, int amap){
    int nmt = (M + 127) / 128;
    lma_gemm2<<<dim3(nmt * (N/128)), 256, 0, stream>>>(A, lda, B0, B1, b0, b1, C, ldc, M, N, K, mode, amap, nmt);
  };
  auto G8 = [&](const unsigned short* A, int lda,
                const unsigned short* B0, const unsigned short* B1,
                const float* b0, const float* b1,
                unsigned short* C, int ldc, int M, int N, int K, int mode, int amap){
    int nmt = M / 256;
    lma_gemm8<<<dim3(nmt * (N/256)), 512, 0, stream>>>(A, lda, B0, B1, b0, b1, C, ldc, M, N, K, mode, amap, nmt);
  };

  // both-branch FFN + LN + projections (rows<8192 = forward, >=8192 = backward)
  G8(Xb, 1024, fw1t, bw1t, fw[1], bw[1], H12, 1024, 2*PAD_, 1024, 1024, 2, 1); // FFN1+gelu (8-phase 256^2)
  G(H12, 1024, fw2t, bw2t, fw[3], bw[3], T12b, 512, 2*PAD_, 512, 1024, 0, 0);  // FFN2 -> bf16
  lma_ln2<<<2*M_, 256, 0, stream>>>(T12b, fw[4], fw[5], bw[4], bw[5], LQ2);
  G(LQ2, 512, fqt, bqt, fw[7], bw[7], Q2, 512, 2*PAD_, 512, 512, 1, 0);        // Q (x0.125*log2e)
  G8(Xb, 1024, fkvt, bkvt, biasKV, biasKV + 1024, KV2, 1024, 2*PAD_, 1024, 512, 0, 2); // K|V (8-phase 256^2)
  lma_vt2<<<dim3(32, 16, 16), 256, 0, stream>>>(KV2, VT2);

  lma_attn9<<<dim3(1024), 256, 0, stream>>>(Q2, KV2, VT2, CT2, lens, 0);
  lma_attn9<<<dim3(1024), 256, 0, stream>>>(Q2, KV2, VT2, CT2, lens, 1);

  G(CT2, 512, fot, bot, fw[13], bw[13], P2b, 512, 2*PAD_, 512, 512, 0, 0);     // out proj -> bf16

  lma_attn_ln<<<M_, 256, 0, stream>>>(P2b, P2b + (size_t)PAD_*512, hidden, attn_g, attn_b, Xb);

  G(Xb, 1024, ow1t, ow1t, o_b1, o_b1, H1o, 1024, M_, 1024, 1024, 2, 0);        // out FFN1+gelu
  G(H1o, 1024, ow2t, ow2t, o_b2, o_b2, (float*)d_out, 1024, M_, 1024, 1024, 4, 0); // out FFN2 -> d_out (remapped)
  lma_ln<<<M_, 256, 0, stream>>>((float*)d_out, o_lng, o_lnb, 1024, nullptr, (float*)d_out);
}

// Round 10
// 550.787 us; speedup vs baseline: 1.1584x; 1.0329x over previous
//
#include <hip/hip_runtime.h>
#include <cmath>

#define S_ 1024
#define B_ 8
#define H_ 512
#define S2_ 1022
#define M_ (B_*S2_)     // 8176
#define PAD_ 8192
#define VTS_ ((size_t)8*8*64*1024)   // VT per-branch stride (4194304 shorts)

typedef __attribute__((ext_vector_type(8))) short bf16x8;
typedef __attribute__((ext_vector_type(4))) float f32x4;
typedef __attribute__((ext_vector_type(4))) unsigned int u32x4;
typedef __attribute__((ext_vector_type(2))) unsigned int u32x2;

__device__ __forceinline__ unsigned short f2bf(float f){
  unsigned int u = __float_as_uint(f);
  return (unsigned short)((u + 0x7fffu + ((u>>16)&1u)) >> 16);
}
__device__ __forceinline__ float bf2f(unsigned short u){
  return __uint_as_float((unsigned int)u << 16);
}
// tanh-approx gelu: x*sigmoid(2*(c1 x + c2 x^3)); |err vs erf-gelu| < ~3e-4
__device__ __forceinline__ float fgelu(float x){
  float u = x * (0.7978845608f + 0.0356774081f * x * x);
  return x / (1.f + __expf(-2.f * u));
}
// raw 2^x (v_exp_f32 is natively base-2)
__device__ __forceinline__ float fexp2(float x){
  float r; asm("v_exp_f32 %0, %1" : "=v"(r) : "v"(x)); return r;
}
// hardware packed f32->bf16 (RNE), lo -> bits[15:0], hi -> bits[31:16]
__device__ __forceinline__ unsigned int cvtpk(float lo, float hi){
  unsigned int r; asm("v_cvt_pk_bf16_f32 %0, %1, %2" : "=v"(r) : "v"(lo), "v"(hi)); return r;
}

__device__ __forceinline__ void glds16(const void* g, void* l){
  __builtin_amdgcn_global_load_lds((const __attribute__((address_space(1))) unsigned int*)g,
                                   (__attribute__((address_space(3))) unsigned int*)l, 16, 0, 0);
}
#define SB() __builtin_amdgcn_sched_barrier(0)

// ---------------------------------------------------------------- prep: X = [f[:-2], bk[2:]] bf16 (M_ x 1024)
__global__ __launch_bounds__(256) void lma_prep_x(const float* __restrict__ hidden,
                                                  unsigned short* __restrict__ Xb){
  int m = blockIdx.x; int dq = threadIdx.x * 4;
  int b = m / S2_, s = m - b * S2_;
  int srow = (dq < 512) ? s : (s + 2);
  const float* src = hidden + ((size_t)srow * B_ + b) * 1024 + dq;
  f32x4 v = *(const f32x4*)src;
  union { u32x2 u; unsigned short s4[4]; } pk;
  #pragma unroll
  for (int j = 0; j < 4; j++) pk.s4[j] = f2bf(v[j]);
  *(u32x2*)&Xb[(size_t)m * 1024 + dq] = pk.u;
}

// ---------------------------------------------------------------- batched weight transpose+cast
struct TPack {
  const float* src[14];
  unsigned short* dst[14];
  int K[14];
  int N[14];
};
__global__ __launch_bounds__(256) void lma_transpose_all(TPack p){
  int idx = blockIdx.z;
  int K = p.K[idx], N = p.N[idx];
  int kb = blockIdx.x * 32, nb = blockIdx.y * 32;
  if (kb >= K || nb >= N) return;
  const float* W = p.src[idx];
  unsigned short* WT = p.dst[idx];
  __shared__ float t[32][33];
  int tx = threadIdx.x & 31, ty = threadIdx.x >> 5;
  #pragma unroll
  for (int i = ty; i < 32; i += 8) t[i][tx] = W[(size_t)(kb + i) * N + nb + tx];
  __syncthreads();
  #pragma unroll
  for (int i = ty; i < 32; i += 8) WT[(size_t)(nb + i) * K + kb + tx] = f2bf(t[tx][i]);
}

// ---------------------------------------------------------------- concat K/V biases
__global__ __launch_bounds__(256) void lma_biascat(const float* __restrict__ fk, const float* __restrict__ fv,
                                                   const float* __restrict__ bk, const float* __restrict__ bv,
                                                   float* __restrict__ out){
  int i = blockIdx.x * 256 + threadIdx.x;     // 0..2047
  int fb = i >> 10, col = i & 1023;
  const float* s = (col < 512) ? (fb ? bk : fk) : (fb ? bv : fv);
  out[i] = s[col & 511];
}

// ---------------------------------------------------------------- V (in KV2, cols 512..1023) -> VT2[fb][b][h][d][s pad 1024]
// Pad cols s in [S2_,1024) ZEROED (aliased buffer may hold bf16-NaN bit patterns).
__global__ __launch_bounds__(256) void lma_vt2(const unsigned short* __restrict__ KV2,
                                               unsigned short* __restrict__ VT2){
  __shared__ unsigned short t[32][34];
  int s0 = blockIdx.x * 32, c0 = blockIdx.y * 32;
  int z = blockIdx.z, fb = z >> 3, b = z & 7;
  const unsigned short* V = KV2 + (size_t)fb * PAD_ * 1024 + 512;
  unsigned short* VT = VT2 + (size_t)fb * VTS_;
  int tx = threadIdx.x & 31, ty = threadIdx.x >> 5;
  #pragma unroll
  for (int i = ty; i < 32; i += 8){
    int s = s0 + i; if (s > S2_-1) s = S2_-1;
    t[i][tx] = V[((size_t)b * S2_ + s) * 1024 + c0 + tx];
  }
  __syncthreads();
  int s = s0 + tx;
  #pragma unroll
  for (int i = ty; i < 32; i += 8){
    int c = c0 + i, h = c >> 6, d = c & 63;
    VT[(((size_t)b * 8 + h) * 64 + d) * 1024 + s] = (s < S2_) ? t[tx][i] : (unsigned short)0;
  }
}

// ---------------------------------------------------------------- 128^2 2-phase GEMM (kept as fallback; no call sites)
__global__ __launch_bounds__(256) void lma_gemm2(
    const unsigned short* __restrict__ A, int lda,
    const unsigned short* __restrict__ Bt0, const unsigned short* __restrict__ Bt1,
    const float* __restrict__ bias0, const float* __restrict__ bias1,
    void* __restrict__ Cout, int ldc,
    int M, int N, int K, int mode, int amap, int nmt)
{
  __shared__ unsigned short Al[128*32];
  __shared__ unsigned short Bl[128*32];
  const int tid = threadIdx.x;
  const int w = tid >> 6, lane = tid & 63, quad = lane >> 4, l16 = lane & 15;
  const int mt = blockIdx.x % nmt, nt = blockIdx.x / nmt;
  const int m0 = mt * 128, n0 = nt * 128;
  const int brch = m0 >> 13;
  const unsigned short* Bt = brch ? Bt1 : Bt0;
  const float* bias = brch ? bias1 : bias0;
  const int coloff = (amap == 2 && brch) ? 512 : 0;
  const int wm = (w >> 1) * 64, wn = (w & 1) * 64;

  f32x4 acc[4][4];
  #pragma unroll
  for (int i = 0; i < 4; i++)
    #pragma unroll
    for (int f = 0; f < 4; f++) acc[i][f] = f32x4{0.f,0.f,0.f,0.f};

  const int srow = lane >> 2;
  const int spc  = (((lane & 3) ^ ((lane >> 3) & 3))) * 8;
  const int rswz = (l16 >> 1) & 3;

  for (int k0 = 0; k0 < K; k0 += 32) {
    #pragma unroll
    for (int c = 0; c < 2; c++) {
      int ra = w*32 + c*16 + srow;
      int ga = m0 + ra;
      int ar;
      if (amap == 0) { ar = (ga > M-1) ? (M-1) : ga; }
      else { ar = ga & (PAD_-1); if (ar > M_-1) ar = M_-1; }
      glds16(A + (size_t)ar * lda + coloff + k0 + spc, &Al[(w*32 + c*16) * 32]);
      int gb = n0 + ra; if (gb > N-1) gb = N-1;
      glds16(Bt + (size_t)gb * K + k0 + spc, &Bl[(w*32 + c*16) * 32]);
    }
    __syncthreads();
    bf16x8 af[4], bfr[4];
    #pragma unroll
    for (int i = 0; i < 4; i++) af[i]  = *(const bf16x8*)&Al[(wm + i*16 + l16)*32 + ((quad ^ rswz) * 8)];
    #pragma unroll
    for (int f = 0; f < 4; f++) bfr[f] = *(const bf16x8*)&Bl[(wn + f*16 + l16)*32 + ((quad ^ rswz) * 8)];
    #pragma unroll
    for (int i = 0; i < 4; i++)
      #pragma unroll
      for (int f = 0; f < 4; f++)
        acc[i][f] = __builtin_amdgcn_mfma_f32_16x16x32_bf16(af[i], bfr[f], acc[i][f], 0, 0, 0);
    __syncthreads();
  }

  float bv[4];
  #pragma unroll
  for (int f = 0; f < 4; f++) bv[f] = bias ? bias[n0 + wn + f*16 + l16] : 0.f;
  const int col0 = n0 + wn + l16;
  #pragma unroll
  for (int i = 0; i < 4; i++) {
    #pragma unroll
    for (int r = 0; r < 4; r++) {
      int row = m0 + wm + i*16 + quad*4 + r;
      if (row < M) {
        #pragma unroll
        for (int f = 0; f < 4; f++) {
          float v = acc[i][f][r] + bv[f];
          if (mode == 2) v = fgelu(v);
          else if (mode == 1) v *= 0.18033688011112042f;
          if (mode <= 2) ((unsigned short*)Cout)[(size_t)row * ldc + col0 + f*16] = f2bf(v);
          else if (mode == 3) ((float*)Cout)[(size_t)row * ldc + col0 + f*16] = v;
          else {
            int sr = row % S2_, bb2 = row / S2_;
            ((float*)Cout)[((size_t)sr * B_ + bb2) * ldc + col0 + f*16] = v;
          }
        }
      }
    }
  }
}

// ---------------------------------------------------------------- 256^2 8-phase GEMM v3 (T2+T3+T4+T5) — full-grid 256-col shapes
__global__ __launch_bounds__(512, 2) void lma_gemm8(
    const unsigned short* __restrict__ A, int lda,
    const unsigned short* __restrict__ Bt0, const unsigned short* __restrict__ Bt1,
    const float* __restrict__ bias0, const float* __restrict__ bias1,
    unsigned short* __restrict__ Cout, int ldc,
    int M, int N, int K, int mode, int amap, int nmt)
{
  __shared__ unsigned short Ls[2][2][256*64];   // [buf][0=A,1=B][row*64+k]
  const int tid = threadIdx.x;
  const int w = tid >> 6, lane = tid & 63, quad = lane >> 4, l16 = lane & 15;
  const int mt = blockIdx.x % nmt, nt = blockIdx.x / nmt;
  const int m0 = mt * 256, n0 = nt * 256;
  const int brch = m0 >> 13;
  const unsigned short* Bt = brch ? Bt1 : Bt0;
  const float* bias = brch ? bias1 : bias0;
  const int coloff = (amap == 2 && brch) ? 512 : 0;
  const int wm = (w >> 2) * 128, wn = (w & 3) * 64;

  f32x4 acc[8][4];
  #pragma unroll
  for (int i = 0; i < 8; i++)
    #pragma unroll
    for (int f = 0; f < 4; f++) acc[i][f] = f32x4{0.f,0.f,0.f,0.f};

  const int lrow8 = lane >> 3;
  const int lkb   = lane & 7;
  const int NT = K >> 6;

  const unsigned short* aP[2][2]; const unsigned short* bP[2][2];
  int aD[2][2], bD[2][2];
  #pragma unroll
  for (int hf = 0; hf < 2; hf++)
    #pragma unroll
    for (int c = 0; c < 2; c++) {
      int rtA = (w>>2)*128 + hf*64 + ((w&3)*2 + c)*8 + lrow8;
      int kbA = lkb ^ (rtA & 7);
      int ga = m0 + rtA;
      int ar;
      if (amap == 0) { ar = (ga > M-1) ? (M-1) : ga; }
      else { ar = ga & (PAD_-1); if (ar > M_-1) ar = M_-1; }
      aP[hf][c] = A + (size_t)ar * lda + coloff + kbA*8;
      aD[hf][c] = ((w>>2)*128 + hf*64 + ((w&3)*2 + c)*8) * 64;
      int rtB = (w>>1)*64 + hf*32 + ((w&1)*2 + c)*8 + lrow8;
      int kbB = lkb ^ (rtB & 7);
      int gb = n0 + rtB; if (gb > N-1) gb = N-1;
      bP[hf][c] = Bt + (size_t)gb * K + kbB*8;
      bD[hf][c] = ((w>>1)*64 + hf*32 + ((w&1)*2 + c)*8) * 64;
    }

  bf16x8 af[4][2], bf[2][2];

  #define STA(buf, hf, kt) { _Pragma("unroll") for (int c = 0; c < 2; c++) \
      glds16(aP[hf][c] + (size_t)(kt)*64, &Ls[buf][0][aD[hf][c]]); }
  #define STB(buf, hf, kt) { _Pragma("unroll") for (int c = 0; c < 2; c++) \
      glds16(bP[hf][c] + (size_t)(kt)*64, &Ls[buf][1][bD[hf][c]]); }
  #define LDA8(buf, mq) { _Pragma("unroll") for (int j = 0; j < 4; j++){ \
      int rt = wm + (mq)*64 + j*16 + l16; \
      const unsigned short* base = &Ls[buf][0][rt*64]; \
      int f_ = rt & 7; \
      af[j][0] = *(const bf16x8*)(base + ((    quad) ^ f_)*8); \
      af[j][1] = *(const bf16x8*)(base + ((4 + quad) ^ f_)*8); } }
  #define LDB8(buf, nq) { _Pragma("unroll") for (int j = 0; j < 2; j++){ \
      int rt = wn + (nq)*32 + j*16 + l16; \
      const unsigned short* base = &Ls[buf][1][rt*64]; \
      int f_ = rt & 7; \
      bf[j][0] = *(const bf16x8*)(base + ((    quad) ^ f_)*8); \
      bf[j][1] = *(const bf16x8*)(base + ((4 + quad) ^ f_)*8); } }
  #define MFMAQ(mq, nq) { __builtin_amdgcn_s_setprio(1); \
      _Pragma("unroll") for (int j = 0; j < 4; j++) \
        _Pragma("unroll") for (int j2 = 0; j2 < 2; j2++){ \
          acc[(mq)*4+j][(nq)*2+j2] = __builtin_amdgcn_mfma_f32_16x16x32_bf16(af[j][0], bf[j2][0], acc[(mq)*4+j][(nq)*2+j2], 0, 0, 0); \
          acc[(mq)*4+j][(nq)*2+j2] = __builtin_amdgcn_mfma_f32_16x16x32_bf16(af[j][1], bf[j2][1], acc[(mq)*4+j][(nq)*2+j2], 0, 0, 0); } \
      __builtin_amdgcn_s_setprio(0); }
  #define BAR()   { SB(); __builtin_amdgcn_s_barrier(); SB(); }
  #define LGKM0() { asm volatile("s_waitcnt lgkmcnt(0)" ::: "memory"); SB(); }
  #define VM6()   { asm volatile("s_waitcnt vmcnt(6)"   ::: "memory"); SB(); }
  #define VM2()   { asm volatile("s_waitcnt vmcnt(2)"   ::: "memory"); SB(); }

  STA(0, 0, 0); STB(0, 0, 0); STB(0, 1, 0); STA(0, 1, 0);
  STA(1, 0, 1);
  asm volatile("s_waitcnt vmcnt(2)" ::: "memory"); SB();
  BAR();

  const int NI = NT >> 1;
  for (int i = 0; i < NI; i++) {
    const int tb  = 2*i + 1;
    int ta2 = 2*i + 2; if (ta2 > NT-1) ta2 = NT-1;
    int tb2 = 2*i + 3; if (tb2 > NT-1) tb2 = NT-1;

    LDA8(0, 0); LDB8(0, 0); STB(1, 0, tb);
    BAR(); LGKM0(); MFMAQ(0, 0); BAR();
    LDB8(0, 1); STB(1, 1, tb);
    BAR(); LGKM0(); MFMAQ(0, 1); BAR();
    LDA8(0, 1); STA(1, 1, tb);
    BAR(); LGKM0(); MFMAQ(1, 1); BAR();
    LDB8(0, 0); STA(0, 0, ta2);
    BAR(); LGKM0(); MFMAQ(1, 0); VM6(); BAR();
    LDA8(1, 0); LDB8(1, 0); STB(0, 1, ta2);
    BAR(); LGKM0(); MFMAQ(0, 0); VM6(); BAR();
    LDB8(1, 1); STA(0, 1, ta2);
    BAR(); LGKM0(); MFMAQ(0, 1); VM6(); BAR();
    LDA8(1, 1); STB(0, 0, ta2);
    BAR(); LGKM0(); MFMAQ(1, 1); BAR();
    LDB8(1, 0); STA(1, 0, tb2);
    BAR(); LGKM0(); MFMAQ(1, 0); VM2(); BAR();
  }
  asm volatile("s_waitcnt vmcnt(0)" ::: "memory");

  float bv[4];
  #pragma unroll
  for (int f = 0; f < 4; f++) bv[f] = bias ? bias[n0 + wn + f*16 + l16] : 0.f;
  const int col0 = n0 + wn + l16;
  #pragma unroll
  for (int i2 = 0; i2 < 8; i2++) {
    #pragma unroll
    for (int r = 0; r < 4; r++) {
      int row = m0 + wm + i2*16 + quad*4 + r;
      if (row < M) {
        #pragma unroll
        for (int f = 0; f < 4; f++) {
          float v = acc[i2][f][r] + bv[f];
          if (mode == 2) v = fgelu(v);
          Cout[(size_t)row * ldc + col0 + f*16] = f2bf(v);
        }
      }
    }
  }
  #undef STA
  #undef STB
  #undef LDA8
  #undef LDB8
  #undef MFMAQ
  #undef BAR
  #undef LGKM0
  #undef VM6
  #undef VM2
}

// ---------------------------------------------------------------- 128x256 8-phase GEMM (gemm8w) — full-grid for N=512/M=8176 shapes
// Same phase/stage ORDER as gemm8 v3, re-derived op counts. Geometry: 8 waves
// 2M x 4N, per-wave 64x64 (acc[4][4] = 64 VGPR), BK=64, LDS A 2x16KB + B 2x32KB
// = 96KB (1 blk/CU). Stage ops/K-tile: A halves 1 glds ea, B halves 2 -> 6.
// Stage map s1..s8 = {b.B0(2), b.B1(2), b.A1(1), a+2.A0(1), a+2.B1(2),
// a+2.A1(1), a+2.B0(2), b+2.A0(1)} = 12 ops/iter. FIFO audit (in-flight from
// [s8p]): ph4 end 7 ops, VM4 drains s8p+s1 (ph5 reads) leaving 4; ph5 VM4
// drains s2 (ph6); ph6 VM4 drains s3 (ph7); ph8 VM1 drains s4..s7 (next
// ph1-4) leaving s8. Prologue: t0(6)+seed(1), VM1. Every stage >=2 barriers
// after its region's last read (reads retire at each phase's LGKM0, before
// the trailing barrier). Grid = ceil(M/128) x N/256 = 256 blocks for ALL of
// FFN2/Q/outproj (16384x512) and oFFN1/oFFN2 (8176x1024). amap 0 only.
__global__ __launch_bounds__(512, 2) void lma_gemm8w(
    const unsigned short* __restrict__ A, int lda,
    const unsigned short* __restrict__ Bt0, const unsigned short* __restrict__ Bt1,
    const float* __restrict__ bias0, const float* __restrict__ bias1,
    void* __restrict__ Cout, int ldc,
    int M, int N, int K, int mode, int nmt)
{
  __shared__ unsigned short LsA[2][128*64];   // 2 x 16KB
  __shared__ unsigned short LsB[2][256*64];   // 2 x 32KB
  const int tid = threadIdx.x;
  const int w = tid >> 6, lane = tid & 63, quad = lane >> 4, l16 = lane & 15;
  const int mt = blockIdx.x % nmt, nt = blockIdx.x / nmt;
  const int m0 = mt * 128, n0 = nt * 256;
  const int brch = m0 >> 13;
  const unsigned short* Bt = brch ? Bt1 : Bt0;
  const float* bias = brch ? bias1 : bias0;
  const int wm = (w >> 2) * 64, wn = (w & 3) * 64;

  f32x4 acc[4][4];
  #pragma unroll
  for (int i = 0; i < 4; i++)
    #pragma unroll
    for (int f = 0; f < 4; f++) acc[i][f] = f32x4{0.f,0.f,0.f,0.f};

  const int lrow8 = lane >> 3;
  const int lkb   = lane & 7;
  const int NT = K >> 6;

  // K-invariant stage pointers. A-half hf: 64 rows, 1 glds/thread.
  // B-half hf: 128 rows, 2 glds/thread.
  const unsigned short* aP[2]; int aD[2];
  const unsigned short* bP[2][2]; int bD[2][2];
  #pragma unroll
  for (int hf = 0; hf < 2; hf++) {
    int rtA = hf*64 + w*8 + lrow8;
    int kbA = lkb ^ (rtA & 7);
    int ga = m0 + rtA; if (ga > M-1) ga = M-1;
    aP[hf] = A + (size_t)ga * lda + kbA*8;
    aD[hf] = (hf*64 + w*8) * 64;
    #pragma unroll
    for (int c = 0; c < 2; c++) {
      int rtB = hf*128 + (w*2 + c)*8 + lrow8;
      int kbB = lkb ^ (rtB & 7);
      int gb = n0 + rtB; if (gb > N-1) gb = N-1;
      bP[hf][c] = Bt + (size_t)gb * K + kbB*8;
      bD[hf][c] = (hf*128 + (w*2 + c)*8) * 64;
    }
  }

  bf16x8 af[2][2], bf[2][2];

  #define WSTA(buf, hf, kt) { glds16(aP[hf] + (size_t)(kt)*64, &LsA[buf][aD[hf]]); }
  #define WSTB(buf, hf, kt) { _Pragma("unroll") for (int c = 0; c < 2; c++) \
      glds16(bP[hf][c] + (size_t)(kt)*64, &LsB[buf][bD[hf][c]]); }
  #define WLDA(buf, mq) { _Pragma("unroll") for (int j = 0; j < 2; j++){ \
      int rt = wm + (mq)*32 + j*16 + l16; \
      const unsigned short* base = &LsA[buf][rt*64]; \
      int f_ = rt & 7; \
      af[j][0] = *(const bf16x8*)(base + ((    quad) ^ f_)*8); \
      af[j][1] = *(const bf16x8*)(base + ((4 + quad) ^ f_)*8); } }
  #define WLDB(buf, nq) { _Pragma("unroll") for (int j = 0; j < 2; j++){ \
      int rt = wn + (nq)*32 + j*16 + l16; \
      const unsigned short* base = &LsB[buf][rt*64]; \
      int f_ = rt & 7; \
      bf[j][0] = *(const bf16x8*)(base + ((    quad) ^ f_)*8); \
      bf[j][1] = *(const bf16x8*)(base + ((4 + quad) ^ f_)*8); } }
  #define WMFMAQ(mq, nq) { __builtin_amdgcn_s_setprio(1); \
      _Pragma("unroll") for (int j = 0; j < 2; j++) \
        _Pragma("unroll") for (int j2 = 0; j2 < 2; j2++){ \
          acc[(mq)*2+j][(nq)*2+j2] = __builtin_amdgcn_mfma_f32_16x16x32_bf16(af[j][0], bf[j2][0], acc[(mq)*2+j][(nq)*2+j2], 0, 0, 0); \
          acc[(mq)*2+j][(nq)*2+j2] = __builtin_amdgcn_mfma_f32_16x16x32_bf16(af[j][1], bf[j2][1], acc[(mq)*2+j][(nq)*2+j2], 0, 0, 0); } \
      __builtin_amdgcn_s_setprio(0); }
  #define WBAR()   { SB(); __builtin_amdgcn_s_barrier(); SB(); }
  #define WLGKM0() { asm volatile("s_waitcnt lgkmcnt(0)" ::: "memory"); SB(); }
  #define WVM4()   { asm volatile("s_waitcnt vmcnt(4)"   ::: "memory"); SB(); }
  #define WVM1()   { asm volatile("s_waitcnt vmcnt(1)"   ::: "memory"); SB(); }

  // prologue: t0 all halves (6 ops) + s8-seed t1.A0 (1); drain t0, leave seed
  WSTA(0, 0, 0); WSTB(0, 0, 0); WSTB(0, 1, 0); WSTA(0, 1, 0);
  WSTA(1, 0, 1);
  WVM1(); WBAR();

  const int NI = NT >> 1;
  for (int i = 0; i < NI; i++) {
    const int tb  = 2*i + 1;
    int ta2 = 2*i + 2; if (ta2 > NT-1) ta2 = NT-1;
    int tb2 = 2*i + 3; if (tb2 > NT-1) tb2 = NT-1;

    // ph1 (buf0: mq0,nq0)  s1 = b.B0 (2)
    WLDA(0, 0); WLDB(0, 0); WSTB(1, 0, tb);
    WBAR(); WLGKM0(); WMFMAQ(0, 0); WBAR();
    // ph2 (buf0: mq0,nq1)  s2 = b.B1 (2)
    WLDB(0, 1); WSTB(1, 1, tb);
    WBAR(); WLGKM0(); WMFMAQ(0, 1); WBAR();
    // ph3 (buf0: mq1,nq1)  s3 = b.A1 (1)
    WLDA(0, 1); WSTA(1, 1, tb);
    WBAR(); WLGKM0(); WMFMAQ(1, 1); WBAR();
    // ph4 (buf0: mq1,nq0)  s4 = a+2.A0 (1)
    WLDB(0, 0); WSTA(0, 0, ta2);
    WBAR(); WLGKM0(); WMFMAQ(1, 0); WVM4(); WBAR();
    // ph5 (buf1: mq0,nq0)  s5 = a+2.B1 (2)
    WLDA(1, 0); WLDB(1, 0); WSTB(0, 1, ta2);
    WBAR(); WLGKM0(); WMFMAQ(0, 0); WVM4(); WBAR();
    // ph6 (buf1: mq0,nq1)  s6 = a+2.A1 (1)
    WLDB(1, 1); WSTA(0, 1, ta2);
    WBAR(); WLGKM0(); WMFMAQ(0, 1); WVM4(); WBAR();
    // ph7 (buf1: mq1,nq1)  s7 = a+2.B0 (2)
    WLDA(1, 1); WSTB(0, 0, ta2);
    WBAR(); WLGKM0(); WMFMAQ(1, 1); WBAR();
    // ph8 (buf1: mq1,nq0)  s8 = b+2.A0 (1)
    WLDB(1, 0); WSTA(1, 0, tb2);
    WBAR(); WLGKM0(); WMFMAQ(1, 0); WVM1(); WBAR();
  }
  asm volatile("s_waitcnt vmcnt(0)" ::: "memory");

  float bv[4];
  #pragma unroll
  for (int f = 0; f < 4; f++) bv[f] = bias ? bias[n0 + wn + f*16 + l16] : 0.f;
  const int col0 = n0 + wn + l16;
  #pragma unroll
  for (int i2 = 0; i2 < 4; i2++) {
    #pragma unroll
    for (int r = 0; r < 4; r++) {
      int row = m0 + wm + i2*16 + quad*4 + r;
      if (row < M) {
        #pragma unroll
        for (int f = 0; f < 4; f++) {
          float v = acc[i2][f][r] + bv[f];
          if (mode == 2) v = fgelu(v);
          else if (mode == 1) v *= 0.18033688011112042f;   // 0.125 * log2(e)
          if (mode <= 2) ((unsigned short*)Cout)[(size_t)row * ldc + col0 + f*16] = f2bf(v);
          else if (mode == 3) ((float*)Cout)[(size_t)row * ldc + col0 + f*16] = v;
          else {
            int sr = row % S2_, bb2 = row / S2_;
            ((float*)Cout)[((size_t)sr * B_ + bb2) * ldc + col0 + f*16] = v;
          }
        }
      }
    }
  }
  #undef WSTA
  #undef WSTB
  #undef WLDA
  #undef WLDB
  #undef WMFMAQ
  #undef WBAR
  #undef WLGKM0
  #undef WVM4
  #undef WVM1
}

// ---------------------------------------------------------------- block reduction helper
__device__ __forceinline__ void lma_red2(float& s, float& sq){
  __shared__ float red[16];
  #pragma unroll
  for (int msk = 1; msk < 64; msk <<= 1){ s += __shfl_xor(s, msk); sq += __shfl_xor(sq, msk); }
  int w = threadIdx.x >> 6;
  if ((threadIdx.x & 63) == 0){ red[w] = s; red[8 + w] = sq; }
  __syncthreads();
  s  = red[0] + red[1] + red[2] + red[3];
  sq = red[8] + red[9] + red[10] + red[11];
}

// ---------------------------------------------------------------- generic LN (f32 in, bf16 or f32 out)
__global__ __launch_bounds__(256) void lma_ln(const float* __restrict__ in,
                                              const float* __restrict__ g, const float* __restrict__ bb,
                                              int D, unsigned short* __restrict__ obf, float* __restrict__ of32){
  int row = blockIdx.x, t = threadIdx.x;
  const float* x = in + (size_t)row * D;
  float s = 0.f, sq = 0.f;
  for (int d = t; d < D; d += 256){ float v = x[d]; s += v; sq += v * v; }
  lma_red2(s, sq);
  float mean = s / D;
  float var = sq / D - mean * mean;
  float rstd = rsqrtf(fmaxf(var, 0.f) + 1e-12f);
  if (obf) {
    for (int d = t; d < D; d += 256) obf[(size_t)row * D + d] = f2bf((x[d] - mean) * rstd * g[d] + bb[d]);
  } else {
    for (int d = t; d < D; d += 256) of32[(size_t)row * D + d] = (x[d] - mean) * rstd * g[d] + bb[d];
  }
}

// ---------------------------------------------------------------- branch-combined LN over T12b (bf16, D=512) -> LQ2 bf16
__global__ __launch_bounds__(256) void lma_ln2(const unsigned short* __restrict__ T12b,
                                               const float* __restrict__ fg, const float* __restrict__ fbb,
                                               const float* __restrict__ bg, const float* __restrict__ bbb,
                                               unsigned short* __restrict__ LQ2){
  int m = blockIdx.x, t = threadIdx.x;           // 0..2*M_-1
  int fb = (m >= M_);
  int idx = m - fb * M_;
  const float* g = fb ? bg : fg;
  const float* bb = fb ? bbb : fbb;
  const unsigned short* x = T12b + ((size_t)fb * PAD_ + idx) * 512;
  unsigned short* o = LQ2 + ((size_t)fb * PAD_ + idx) * 512;
  float v0 = bf2f(x[t]), v1 = bf2f(x[t + 256]);
  float s = v0 + v1, sq = v0*v0 + v1*v1;
  lma_red2(s, sq);
  float mean = s / 512.f;
  float var = sq / 512.f - mean * mean;
  float rstd = rsqrtf(fmaxf(var, 0.f) + 1e-12f);
  o[t]       = f2bf((v0 - mean) * rstd * g[t]       + bb[t]);
  o[t + 256] = f2bf((v1 - mean) * rstd * g[t + 256] + bb[t + 256]);
}

// ---------------------------------------------------------------- attn LN: LN(residual(hidden)+[pf,pb](bf16)) -> bf16 (M_ x 1024)
__global__ __launch_bounds__(256) void lma_attn_ln(const unsigned short* __restrict__ pf,
                                                   const unsigned short* __restrict__ pb,
                                                   const float* __restrict__ hidden,
                                                   const float* __restrict__ g, const float* __restrict__ bb,
                                                   unsigned short* __restrict__ out){
  int m = blockIdx.x, t = threadIdx.x;
  int b = m / S2_, s = m - b * S2_;
  const float* hf = hidden + ((size_t)s       * B_ + b) * 1024;
  const float* hb = hidden + ((size_t)(s + 2) * B_ + b) * 1024;
  float v[4]; float sum = 0.f, sq = 0.f;
  #pragma unroll
  for (int j = 0; j < 4; j++){
    int d = t + j * 256;
    float x = (d < 512) ? (bf2f(pf[(size_t)m * 512 + d]) + hf[d])
                        : (bf2f(pb[(size_t)m * 512 + (d - 512)]) + hb[d]);
    v[j] = x; sum += x; sq += x * x;
  }
  lma_red2(sum, sq);
  float mean = sum / 1024.f;
  float var = sq / 1024.f - mean * mean;
  float rstd = rsqrtf(fmaxf(var, 0.f) + 1e-12f);
  #pragma unroll
  for (int j = 0; j < 4; j++){
    int d = t + j * 256;
    out[(size_t)m * 1024 + d] = f2bf((v[j] - mean) * rstd * g[d] + bb[d]);
  }
}

// ---------------------------------------------------------------- combined flash attention v10: fused fwd+bwd (fb loop).
// Re-fuses the fb split (round 5) back into one 1024-block dispatch: per-block
// work = fwd(qt+1) + bwd(~16-qt) tiles ~= constant -> balanced; split version
// measured 2x66us vs fused ~118-121 historically. v9 innards (cvtpk, exp2
// softmax, defer-max, interior-skip, setprio, swizzled P) kept unchanged.
__global__ __launch_bounds__(256, 4) void lma_attn10(const unsigned short* __restrict__ Q2,
                                                     const unsigned short* __restrict__ KV2,
                                                     const unsigned short* __restrict__ VT2,
                                                     unsigned short* __restrict__ CT2,
                                                     const int* __restrict__ lens){
  __shared__ unsigned short Kl[64*64];
  __shared__ unsigned short Vl[64*64];
  __shared__ __align__(16) unsigned short Pl[4][16*64];

  const int tid = threadIdx.x;
  const int w = tid >> 6, lane = tid & 63, quad = lane >> 4, l16 = lane & 15;
  const int id = blockIdx.x;                 // 1024 blocks: [qt:4][h:3][b:3]
  const int qt = id >> 6, h = (id >> 3) & 7, b = id & 7;
  const int L2 = lens[b] - 2;
  const int q0wg = qt * 64;
  const int q0 = q0wg + w * 16;
  const int qg = q0 + l16;
  const int qload = (qg > S2_-1) ? (S2_-1) : qg;

  const size_t qbase  = ((size_t)b * S2_) * 512  + h * 64;
  const size_t kbase  = ((size_t)b * S2_) * 1024 + h * 64;
  const size_t vtbase = ((size_t)(b * 8 + h) * 64) * 1024;
  char* Pb = (char*)&Pl[w][0];

  const int lrow = lane >> 3;
  const int g0s  = (lane & 7) ^ lrow;
  const int x7   = l16 & 7;
  const int x7s  = x7 << 4;

  for (int fb = 0; fb < 2; fb++) {
    const int backward = fb;
    const unsigned short* Q  = Q2  + (size_t)fb * PAD_ * 512;
    const unsigned short* Kx = KV2 + (size_t)fb * PAD_ * 1024;
    const unsigned short* VT = VT2 + (size_t)fb * VTS_;
    unsigned short* CTX      = CT2 + (size_t)fb * PAD_ * 512;

    bf16x8 qf[2];
    {
      const unsigned short* qp = Q + qbase + (size_t)qload * 512 + quad * 8;
      qf[0] = *(const bf16x8*)(qp);
      qf[1] = *(const bf16x8*)(qp + 32);
    }

    float mi = -3e38f, li = 0.f;
    f32x4 ot[4];
    #pragma unroll
    for (int f = 0; f < 4; f++) ot[f] = f32x4{0.f,0.f,0.f,0.f};

    int klo = 0, khi = S2_ - 1;
    if (q0wg + 63 < L2) {
      if (!backward) khi = q0wg + 63;
      else { klo = q0wg; khi = L2 - 1; }
    }

    for (int kt0 = klo; kt0 <= khi; kt0 += 64) {
      #pragma unroll
      for (int c = 0; c < 2; c++) {
        int r = w*16 + c*8 + lrow;
        int kr = kt0 + r; if (kr > S2_-1) kr = S2_-1;
        glds16(Kx + kbase + (size_t)kr * 1024 + g0s * 8, &Kl[(w*16 + c*8) * 64]);
        glds16(VT + vtbase + (size_t)r * 1024 + kt0 + g0s * 8, &Vl[(w*16 + c*8) * 64]);
      }
      __syncthreads();

      bf16x8 kf[4][2], vf[4][2];
      #pragma unroll
      for (int sub = 0; sub < 4; sub++) {
        const unsigned short* kp = &Kl[(sub*16 + l16) * 64];
        kf[sub][0] = *(const bf16x8*)(kp + (( quad      ^ x7) * 8));
        kf[sub][1] = *(const bf16x8*)(kp + (((quad + 4) ^ x7) * 8));
      }
      #pragma unroll
      for (int f = 0; f < 4; f++) {
        const unsigned short* vp = &Vl[(f*16 + l16) * 64];
        vf[f][0] = *(const bf16x8*)(vp + (( quad      ^ x7) * 8));
        vf[f][1] = *(const bf16x8*)(vp + (((quad + 4) ^ x7) * 8));
      }

      f32x4 st[4];
      __builtin_amdgcn_s_setprio(1);
      #pragma unroll
      for (int sub = 0; sub < 4; sub++) {
        f32x4 s = f32x4{0.f,0.f,0.f,0.f};
        s = __builtin_amdgcn_mfma_f32_16x16x32_bf16(kf[sub][0], qf[0], s, 0, 0, 0);
        s = __builtin_amdgcn_mfma_f32_16x16x32_bf16(kf[sub][1], qf[1], s, 0, 0, 0);
        st[sub] = s;
      }
      __builtin_amdgcn_s_setprio(0);

      // interior-tile skip: wave-uniform "every (lane,r) passes the mask"
      {
        bool tail = (kt0 + 63 > S2_ - 1);
        bool full;
        if (!backward) full = !tail && ((kt0 + 63 <= q0) || (q0 >= L2));
        else           full = !tail && ((q0 >= L2) || ((kt0 >= q0 + 15) && (kt0 + 63 < L2)));
        if (!full) {
          #pragma unroll
          for (int sub = 0; sub < 4; sub++) {
            #pragma unroll
            for (int r = 0; r < 4; r++) {
              int kg = kt0 + sub*16 + quad*4 + r;
              bool ok;
              if (!backward) ok = (kg < S2_) && ((qg >= L2) || (kg <= qg));
              else           ok = (kg < S2_) && ((qg >= L2) || ((kg >= qg) && (kg < L2)));
              if (!ok) st[sub][r] = -3e38f;
            }
          }
        }
      }

      float mx = -3e38f;
      #pragma unroll
      for (int sub = 0; sub < 4; sub++)
        #pragma unroll
        for (int r = 0; r < 4; r++) mx = fmaxf(mx, st[sub][r]);
      mx = fmaxf(mx, __shfl_xor(mx, 16));
      mx = fmaxf(mx, __shfl_xor(mx, 32));

      // defer-max (T13)
      if (__any(mx > mi + 11.f)) {
        float mn = fmaxf(mi, mx);
        float al = fexp2(mi - mn);
        li *= al;
        #pragma unroll
        for (int f = 0; f < 4; f++)
          #pragma unroll
          for (int r = 0; r < 4; r++) ot[f][r] *= al;
        mi = mn;
      }

      float rs = 0.f;
      #pragma unroll
      for (int sub = 0; sub < 4; sub++)
        #pragma unroll
        for (int r = 0; r < 4; r++) {
          float p = fexp2(st[sub][r] - mi);
          st[sub][r] = p; rs += p;
        }
      rs += __shfl_xor(rs, 16);
      rs += __shfl_xor(rs, 32);
      li += rs;

      // P round-trip through XOR-swizzled per-wave LDS
      #pragma unroll
      for (int sub = 0; sub < 4; sub++) {
        u32x2 pk2;
        pk2[0] = cvtpk(st[sub][0], st[sub][1]);
        pk2[1] = cvtpk(st[sub][2], st[sub][3]);
        *(u32x2*)(Pb + (l16*128 + ((sub*32 + quad*8) ^ x7s))) = pk2;
      }
      bf16x8 pfr0 = *(const bf16x8*)(Pb + (l16*128 + (( 0 + quad*16) ^ x7s)));
      bf16x8 pfr1 = *(const bf16x8*)(Pb + (l16*128 + ((64 + quad*16) ^ x7s)));

      __builtin_amdgcn_s_setprio(1);
      #pragma unroll
      for (int f = 0; f < 4; f++) {
        ot[f] = __builtin_amdgcn_mfma_f32_16x16x32_bf16(vf[f][0], pfr0, ot[f], 0, 0, 0);
        ot[f] = __builtin_amdgcn_mfma_f32_16x16x32_bf16(vf[f][1], pfr1, ot[f], 0, 0, 0);
      }
      __builtin_amdgcn_s_setprio(0);
      __syncthreads();
    }

    if (qg < S2_) {
      float rcp = 1.f / li;
      #pragma unroll
      for (int f = 0; f < 4; f++) {
        ushort4 pk;
        pk.x = f2bf(ot[f][0] * rcp); pk.y = f2bf(ot[f][1] * rcp);
        pk.z = f2bf(ot[f][2] * rcp); pk.w = f2bf(ot[f][3] * rcp);
        *(ushort4*)&CTX[qbase + (size_t)qg * 512 + f*16 + quad*4] = pk;
      }
    }
  }
}

// ----------------------------------------------------------------
extern "C" void kernel_launch(void* const* d_in, const int* in_sizes, int n_in,
                              void* d_out, int out_size, void* d_ws, size_t ws_size,
                              hipStream_t stream)
{
  const float* hidden = (const float*)d_in[0];
  const int*   lens   = (const int*)d_in[1];
  const float* fw[14]; for (int i = 0; i < 14; i++) fw[i] = (const float*)d_in[2 + i];
  const float* bw[14]; for (int i = 0; i < 14; i++) bw[i] = (const float*)d_in[16 + i];
  const float* attn_g = (const float*)d_in[30];
  const float* attn_b = (const float*)d_in[31];
  const float* o_w1 = (const float*)d_in[32];
  const float* o_b1 = (const float*)d_in[33];
  const float* o_w2 = (const float*)d_in[34];
  const float* o_b2 = (const float*)d_in[35];
  const float* o_lng = (const float*)d_in[36];
  const float* o_lnb = (const float*)d_in[37];

  char* ws = (char*)d_ws;
  size_t off = 0;
  auto alloc = [&](size_t bytes)->char* {
    off = (off + 255) & ~(size_t)255;
    char* p = ws + off; off += bytes; return p;
  };

  unsigned short* fw1t = (unsigned short*)alloc((size_t)1024*1024*2);
  unsigned short* fw2t = (unsigned short*)alloc((size_t)512*1024*2);
  unsigned short* fqt  = (unsigned short*)alloc((size_t)512*512*2);
  unsigned short* fkvt = (unsigned short*)alloc((size_t)1024*512*2);  // [K(512 rows); V(512 rows)]
  unsigned short* fot  = (unsigned short*)alloc((size_t)512*512*2);
  unsigned short* bw1t = (unsigned short*)alloc((size_t)1024*1024*2);
  unsigned short* bw2t = (unsigned short*)alloc((size_t)512*1024*2);
  unsigned short* bqt  = (unsigned short*)alloc((size_t)512*512*2);
  unsigned short* bkvt = (unsigned short*)alloc((size_t)1024*512*2);
  unsigned short* bot  = (unsigned short*)alloc((size_t)512*512*2);
  unsigned short* ow1t = (unsigned short*)alloc((size_t)1024*1024*2);
  unsigned short* ow2t = (unsigned short*)alloc((size_t)1024*1024*2);
  float*          biasKV = (float*)alloc(2048*4);

  unsigned short* Xb   = (unsigned short*)alloc((size_t)M_*1024*2);
  unsigned short* big1 = (unsigned short*)alloc((size_t)2*PAD_*1024*2);
  float*          big2 = (float*)alloc((size_t)2*PAD_*512*4);
  unsigned short* LQCT = (unsigned short*)alloc((size_t)2*PAD_*512*2);
  unsigned short* Q2   = (unsigned short*)alloc((size_t)2*PAD_*512*2);

  unsigned short* H12 = big1, *KV2 = big1, *H1o = big1;
  // big2 partitions: [0 .. 2*VTS_) = T12b (bf16) then VT2 (bf16);
  //                  [2*VTS_ .. 4*VTS_) = P2b (bf16 out-proj). Exactly fills big2.
  unsigned short* T12b = (unsigned short*)big2;
  unsigned short* VT2  = (unsigned short*)big2;
  unsigned short* P2b  = (unsigned short*)big2 + 2*VTS_;
  unsigned short* LQ2 = LQCT, *CT2 = LQCT;

  lma_prep_x<<<M_, 256, 0, stream>>>(hidden, Xb);

  {
    TPack tp;
    const float* srcs[14] = { fw[0], fw[2], fw[6], fw[8], fw[10], fw[12],
                              bw[0], bw[2], bw[6], bw[8], bw[10], bw[12],
                              o_w1, o_w2 };
    unsigned short* dsts[14] = { fw1t, fw2t, fqt, fkvt, fkvt + (size_t)512*512, fot,
                                 bw1t, bw2t, bqt, bkvt, bkvt + (size_t)512*512, bot,
                                 ow1t, ow2t };
    int Ks[14] = {1024,1024,512,512,512,512, 1024,1024,512,512,512,512, 1024,1024};
    int Ns[14] = {1024, 512,512,512,512,512, 1024, 512,512,512,512,512, 1024,1024};
    for (int i = 0; i < 14; i++){ tp.src[i]=srcs[i]; tp.dst[i]=dsts[i]; tp.K[i]=Ks[i]; tp.N[i]=Ns[i]; }
    lma_transpose_all<<<dim3(32, 32, 14), 256, 0, stream>>>(tp);
  }
  lma_biascat<<<8, 256, 0, stream>>>(fw[9], fw[11], bw[9], bw[11], biasKV);

  auto G8 = [&](const unsigned short* A, int lda,
                const unsigned short* B0, const unsigned short* B1,
                const float* b0, const float* b1,
                unsigned short* C, int ldc, int M, int N, int K, int mode, int amap){
    int nmt = M / 256;
    lma_gemm8<<<dim3(nmt * (N/256)), 512, 0, stream>>>(A, lda, B0, B1, b0, b1, C, ldc, M, N, K, mode, amap, nmt);
  };
  auto G8W = [&](const unsigned short* A, int lda,
                 const unsigned short* B0, const unsigned short* B1,
                 const float* b0, const float* b1,
                 void* C, int ldc, int M, int N, int K, int mode){
    int nmt = (M + 127) / 128;
    lma_gemm8w<<<dim3(nmt * (N/256)), 512, 0, stream>>>(A, lda, B0, B1, b0, b1, C, ldc, M, N, K, mode, nmt);
  };

  // both-branch FFN + LN + projections (rows<8192 = forward, >=8192 = backward)
  G8(Xb, 1024, fw1t, bw1t, fw[1], bw[1], H12, 1024, 2*PAD_, 1024, 1024, 2, 1);   // FFN1+gelu (256^2 8-phase)
  G8W(H12, 1024, fw2t, bw2t, fw[3], bw[3], T12b, 512, 2*PAD_, 512, 1024, 0);     // FFN2 -> bf16 (128x256 8-phase)
  lma_ln2<<<2*M_, 256, 0, stream>>>(T12b, fw[4], fw[5], bw[4], bw[5], LQ2);
  G8W(LQ2, 512, fqt, bqt, fw[7], bw[7], Q2, 512, 2*PAD_, 512, 512, 1);           // Q (x0.125*log2e)
  G8(Xb, 1024, fkvt, bkvt, biasKV, biasKV + 1024, KV2, 1024, 2*PAD_, 1024, 512, 0, 2); // K|V (256^2 8-phase)
  lma_vt2<<<dim3(32, 16, 16), 256, 0, stream>>>(KV2, VT2);

  lma_attn10<<<dim3(1024), 256, 0, stream>>>(Q2, KV2, VT2, CT2, lens);

  G8W(CT2, 512, fot, bot, fw[13], bw[13], P2b, 512, 2*PAD_, 512, 512, 0);        // out proj -> bf16

  lma_attn_ln<<<M_, 256, 0, stream>>>(P2b, P2b + (size_t)PAD_*512, hidden, attn_g, attn_b, Xb);

  G8W(Xb, 1024, ow1t, ow1t, o_b1, o_b1, H1o, 1024, M_, 1024, 1024, 2);           // out FFN1+gelu
  G8W(H1o, 1024, ow2t, ow2t, o_b2, o_b2, (float*)d_out, 1024, M_, 1024, 1024, 4); // out FFN2 -> d_out (remapped)
  lma_ln<<<M_, 256, 0, stream>>>((float*)d_out, o_lng, o_lnb, 1024, nullptr, (float*)d_out);
}

// Round 11
// 545.438 us; speedup vs baseline: 1.1698x; 1.0098x over previous
//
#include <hip/hip_runtime.h>
#include <cmath>

#define S_ 1024
#define B_ 8
#define H_ 512
#define S2_ 1022
#define M_ (B_*S2_)     // 8176
#define PAD_ 8192
#define VTS_ ((size_t)8*8*64*1024)   // VT per-branch stride (4194304 shorts)

typedef __attribute__((ext_vector_type(8))) short bf16x8;
typedef __attribute__((ext_vector_type(4))) float f32x4;
typedef __attribute__((ext_vector_type(4))) unsigned int u32x4;
typedef __attribute__((ext_vector_type(2))) unsigned int u32x2;

__device__ __forceinline__ unsigned short f2bf(float f){
  unsigned int u = __float_as_uint(f);
  return (unsigned short)((u + 0x7fffu + ((u>>16)&1u)) >> 16);
}
__device__ __forceinline__ float bf2f(unsigned short u){
  return __uint_as_float((unsigned int)u << 16);
}
// tanh-approx gelu: x*sigmoid(2*(c1 x + c2 x^3)); |err vs erf-gelu| < ~3e-4
__device__ __forceinline__ float fgelu(float x){
  float u = x * (0.7978845608f + 0.0356774081f * x * x);
  return x / (1.f + __expf(-2.f * u));
}
// raw 2^x (v_exp_f32 is natively base-2)
__device__ __forceinline__ float fexp2(float x){
  float r; asm("v_exp_f32 %0, %1" : "=v"(r) : "v"(x)); return r;
}
// hardware packed f32->bf16 (RNE), lo -> bits[15:0], hi -> bits[31:16]
__device__ __forceinline__ unsigned int cvtpk(float lo, float hi){
  unsigned int r; asm("v_cvt_pk_bf16_f32 %0, %1, %2" : "=v"(r) : "v"(lo), "v"(hi)); return r;
}

__device__ __forceinline__ void glds16(const void* g, void* l){
  __builtin_amdgcn_global_load_lds((const __attribute__((address_space(1))) unsigned int*)g,
                                   (__attribute__((address_space(3))) unsigned int*)l, 16, 0, 0);
}
#define SB() __builtin_amdgcn_sched_barrier(0)

// ---------------------------------------------------------------- prep: X = [f[:-2], bk[2:]] bf16 (M_ x 1024)
__global__ __launch_bounds__(256) void lma_prep_x(const float* __restrict__ hidden,
                                                  unsigned short* __restrict__ Xb){
  int m = blockIdx.x; int dq = threadIdx.x * 4;
  int b = m / S2_, s = m - b * S2_;
  int srow = (dq < 512) ? s : (s + 2);
  const float* src = hidden + ((size_t)srow * B_ + b) * 1024 + dq;
  f32x4 v = *(const f32x4*)src;
  union { u32x2 u; unsigned short s4[4]; } pk;
  #pragma unroll
  for (int j = 0; j < 4; j++) pk.s4[j] = f2bf(v[j]);
  *(u32x2*)&Xb[(size_t)m * 1024 + dq] = pk.u;
}

// ---------------------------------------------------------------- batched weight transpose+cast
struct TPack {
  const float* src[14];
  unsigned short* dst[14];
  int K[14];
  int N[14];
};
__global__ __launch_bounds__(256) void lma_transpose_all(TPack p){
  int idx = blockIdx.z;
  int K = p.K[idx], N = p.N[idx];
  int kb = blockIdx.x * 32, nb = blockIdx.y * 32;
  if (kb >= K || nb >= N) return;
  const float* W = p.src[idx];
  unsigned short* WT = p.dst[idx];
  __shared__ float t[32][33];
  int tx = threadIdx.x & 31, ty = threadIdx.x >> 5;
  #pragma unroll
  for (int i = ty; i < 32; i += 8) t[i][tx] = W[(size_t)(kb + i) * N + nb + tx];
  __syncthreads();
  #pragma unroll
  for (int i = ty; i < 32; i += 8) WT[(size_t)(nb + i) * K + kb + tx] = f2bf(t[tx][i]);
}

// ---------------------------------------------------------------- concat K/V biases
__global__ __launch_bounds__(256) void lma_biascat(const float* __restrict__ fk, const float* __restrict__ fv,
                                                   const float* __restrict__ bk, const float* __restrict__ bv,
                                                   float* __restrict__ out){
  int i = blockIdx.x * 256 + threadIdx.x;     // 0..2047
  int fb = i >> 10, col = i & 1023;
  const float* s = (col < 512) ? (fb ? bk : fk) : (fb ? bv : fv);
  out[i] = s[col & 511];
}

// ---------------------------------------------------------------- V (in KV2, cols 512..1023) -> VT2[fb][b][h][d][s pad 1024]
// Pad cols s in [S2_,1024) ZEROED (aliased buffer may hold bf16-NaN bit patterns).
__global__ __launch_bounds__(256) void lma_vt2(const unsigned short* __restrict__ KV2,
                                               unsigned short* __restrict__ VT2){
  __shared__ unsigned short t[32][34];
  int s0 = blockIdx.x * 32, c0 = blockIdx.y * 32;
  int z = blockIdx.z, fb = z >> 3, b = z & 7;
  const unsigned short* V = KV2 + (size_t)fb * PAD_ * 1024 + 512;
  unsigned short* VT = VT2 + (size_t)fb * VTS_;
  int tx = threadIdx.x & 31, ty = threadIdx.x >> 5;
  #pragma unroll
  for (int i = ty; i < 32; i += 8){
    int s = s0 + i; if (s > S2_-1) s = S2_-1;
    t[i][tx] = V[((size_t)b * S2_ + s) * 1024 + c0 + tx];
  }
  __syncthreads();
  int s = s0 + tx;
  #pragma unroll
  for (int i = ty; i < 32; i += 8){
    int c = c0 + i, h = c >> 6, d = c & 63;
    VT[(((size_t)b * 8 + h) * 64 + d) * 1024 + s] = (s < S2_) ? t[tx][i] : (unsigned short)0;
  }
}

// ---------------------------------------------------------------- 128^2 2-phase GEMM (kept as fallback; no call sites)
__global__ __launch_bounds__(256) void lma_gemm2(
    const unsigned short* __restrict__ A, int lda,
    const unsigned short* __restrict__ Bt0, const unsigned short* __restrict__ Bt1,
    const float* __restrict__ bias0, const float* __restrict__ bias1,
    void* __restrict__ Cout, int ldc,
    int M, int N, int K, int mode, int amap, int nmt)
{
  __shared__ unsigned short Al[128*32];
  __shared__ unsigned short Bl[128*32];
  const int tid = threadIdx.x;
  const int w = tid >> 6, lane = tid & 63, quad = lane >> 4, l16 = lane & 15;
  const int mt = blockIdx.x % nmt, nt = blockIdx.x / nmt;
  const int m0 = mt * 128, n0 = nt * 128;
  const int brch = m0 >> 13;
  const unsigned short* Bt = brch ? Bt1 : Bt0;
  const float* bias = brch ? bias1 : bias0;
  const int coloff = (amap == 2 && brch) ? 512 : 0;
  const int wm = (w >> 1) * 64, wn = (w & 1) * 64;

  f32x4 acc[4][4];
  #pragma unroll
  for (int i = 0; i < 4; i++)
    #pragma unroll
    for (int f = 0; f < 4; f++) acc[i][f] = f32x4{0.f,0.f,0.f,0.f};

  const int srow = lane >> 2;
  const int spc  = (((lane & 3) ^ ((lane >> 3) & 3))) * 8;
  const int rswz = (l16 >> 1) & 3;

  for (int k0 = 0; k0 < K; k0 += 32) {
    #pragma unroll
    for (int c = 0; c < 2; c++) {
      int ra = w*32 + c*16 + srow;
      int ga = m0 + ra;
      int ar;
      if (amap == 0) { ar = (ga > M-1) ? (M-1) : ga; }
      else { ar = ga & (PAD_-1); if (ar > M_-1) ar = M_-1; }
      glds16(A + (size_t)ar * lda + coloff + k0 + spc, &Al[(w*32 + c*16) * 32]);
      int gb = n0 + ra; if (gb > N-1) gb = N-1;
      glds16(Bt + (size_t)gb * K + k0 + spc, &Bl[(w*32 + c*16) * 32]);
    }
    __syncthreads();
    bf16x8 af[4], bfr[4];
    #pragma unroll
    for (int i = 0; i < 4; i++) af[i]  = *(const bf16x8*)&Al[(wm + i*16 + l16)*32 + ((quad ^ rswz) * 8)];
    #pragma unroll
    for (int f = 0; f < 4; f++) bfr[f] = *(const bf16x8*)&Bl[(wn + f*16 + l16)*32 + ((quad ^ rswz) * 8)];
    #pragma unroll
    for (int i = 0; i < 4; i++)
      #pragma unroll
      for (int f = 0; f < 4; f++)
        acc[i][f] = __builtin_amdgcn_mfma_f32_16x16x32_bf16(af[i], bfr[f], acc[i][f], 0, 0, 0);
    __syncthreads();
  }

  float bv[4];
  #pragma unroll
  for (int f = 0; f < 4; f++) bv[f] = bias ? bias[n0 + wn + f*16 + l16] : 0.f;
  const int col0 = n0 + wn + l16;
  #pragma unroll
  for (int i = 0; i < 4; i++) {
    #pragma unroll
    for (int r = 0; r < 4; r++) {
      int row = m0 + wm + i*16 + quad*4 + r;
      if (row < M) {
        #pragma unroll
        for (int f = 0; f < 4; f++) {
          float v = acc[i][f][r] + bv[f];
          if (mode == 2) v = fgelu(v);
          else if (mode == 1) v *= 0.18033688011112042f;
          if (mode <= 2) ((unsigned short*)Cout)[(size_t)row * ldc + col0 + f*16] = f2bf(v);
          else if (mode == 3) ((float*)Cout)[(size_t)row * ldc + col0 + f*16] = v;
          else {
            int sr = row % S2_, bb2 = row / S2_;
            ((float*)Cout)[((size_t)sr * B_ + bb2) * ldc + col0 + f*16] = v;
          }
        }
      }
    }
  }
}

// ---------------------------------------------------------------- 256^2 8-phase GEMM v3 (T2+T3+T4+T5) — full-grid 256-col shapes
__global__ __launch_bounds__(512, 2) void lma_gemm8(
    const unsigned short* __restrict__ A, int lda,
    const unsigned short* __restrict__ Bt0, const unsigned short* __restrict__ Bt1,
    const float* __restrict__ bias0, const float* __restrict__ bias1,
    unsigned short* __restrict__ Cout, int ldc,
    int M, int N, int K, int mode, int amap, int nmt)
{
  __shared__ unsigned short Ls[2][2][256*64];   // [buf][0=A,1=B][row*64+k]
  const int tid = threadIdx.x;
  const int w = tid >> 6, lane = tid & 63, quad = lane >> 4, l16 = lane & 15;
  const int mt = blockIdx.x % nmt, nt = blockIdx.x / nmt;
  const int m0 = mt * 256, n0 = nt * 256;
  const int brch = m0 >> 13;
  const unsigned short* Bt = brch ? Bt1 : Bt0;
  const float* bias = brch ? bias1 : bias0;
  const int coloff = (amap == 2 && brch) ? 512 : 0;
  const int wm = (w >> 2) * 128, wn = (w & 3) * 64;

  f32x4 acc[8][4];
  #pragma unroll
  for (int i = 0; i < 8; i++)
    #pragma unroll
    for (int f = 0; f < 4; f++) acc[i][f] = f32x4{0.f,0.f,0.f,0.f};

  const int lrow8 = lane >> 3;
  const int lkb   = lane & 7;
  const int NT = K >> 6;

  const unsigned short* aP[2][2]; const unsigned short* bP[2][2];
  int aD[2][2], bD[2][2];
  #pragma unroll
  for (int hf = 0; hf < 2; hf++)
    #pragma unroll
    for (int c = 0; c < 2; c++) {
      int rtA = (w>>2)*128 + hf*64 + ((w&3)*2 + c)*8 + lrow8;
      int kbA = lkb ^ (rtA & 7);
      int ga = m0 + rtA;
      int ar;
      if (amap == 0) { ar = (ga > M-1) ? (M-1) : ga; }
      else { ar = ga & (PAD_-1); if (ar > M_-1) ar = M_-1; }
      aP[hf][c] = A + (size_t)ar * lda + coloff + kbA*8;
      aD[hf][c] = ((w>>2)*128 + hf*64 + ((w&3)*2 + c)*8) * 64;
      int rtB = (w>>1)*64 + hf*32 + ((w&1)*2 + c)*8 + lrow8;
      int kbB = lkb ^ (rtB & 7);
      int gb = n0 + rtB; if (gb > N-1) gb = N-1;
      bP[hf][c] = Bt + (size_t)gb * K + kbB*8;
      bD[hf][c] = ((w>>1)*64 + hf*32 + ((w&1)*2 + c)*8) * 64;
    }

  bf16x8 af[4][2], bf[2][2];

  #define STA(buf, hf, kt) { _Pragma("unroll") for (int c = 0; c < 2; c++) \
      glds16(aP[hf][c] + (size_t)(kt)*64, &Ls[buf][0][aD[hf][c]]); }
  #define STB(buf, hf, kt) { _Pragma("unroll") for (int c = 0; c < 2; c++) \
      glds16(bP[hf][c] + (size_t)(kt)*64, &Ls[buf][1][bD[hf][c]]); }
  #define LDA8(buf, mq) { _Pragma("unroll") for (int j = 0; j < 4; j++){ \
      int rt = wm + (mq)*64 + j*16 + l16; \
      const unsigned short* base = &Ls[buf][0][rt*64]; \
      int f_ = rt & 7; \
      af[j][0] = *(const bf16x8*)(base + ((    quad) ^ f_)*8); \
      af[j][1] = *(const bf16x8*)(base + ((4 + quad) ^ f_)*8); } }
  #define LDB8(buf, nq) { _Pragma("unroll") for (int j = 0; j < 2; j++){ \
      int rt = wn + (nq)*32 + j*16 + l16; \
      const unsigned short* base = &Ls[buf][1][rt*64]; \
      int f_ = rt & 7; \
      bf[j][0] = *(const bf16x8*)(base + ((    quad) ^ f_)*8); \
      bf[j][1] = *(const bf16x8*)(base + ((4 + quad) ^ f_)*8); } }
  #define MFMAQ(mq, nq) { __builtin_amdgcn_s_setprio(1); \
      _Pragma("unroll") for (int j = 0; j < 4; j++) \
        _Pragma("unroll") for (int j2 = 0; j2 < 2; j2++){ \
          acc[(mq)*4+j][(nq)*2+j2] = __builtin_amdgcn_mfma_f32_16x16x32_bf16(af[j][0], bf[j2][0], acc[(mq)*4+j][(nq)*2+j2], 0, 0, 0); \
          acc[(mq)*4+j][(nq)*2+j2] = __builtin_amdgcn_mfma_f32_16x16x32_bf16(af[j][1], bf[j2][1], acc[(mq)*4+j][(nq)*2+j2], 0, 0, 0); } \
      __builtin_amdgcn_s_setprio(0); }
  #define BAR()   { SB(); __builtin_amdgcn_s_barrier(); SB(); }
  #define LGKM0() { asm volatile("s_waitcnt lgkmcnt(0)" ::: "memory"); SB(); }
  #define VM6()   { asm volatile("s_waitcnt vmcnt(6)"   ::: "memory"); SB(); }
  #define VM2()   { asm volatile("s_waitcnt vmcnt(2)"   ::: "memory"); SB(); }

  STA(0, 0, 0); STB(0, 0, 0); STB(0, 1, 0); STA(0, 1, 0);
  STA(1, 0, 1);
  asm volatile("s_waitcnt vmcnt(2)" ::: "memory"); SB();
  BAR();

  const int NI = NT >> 1;
  for (int i = 0; i < NI; i++) {
    const int tb  = 2*i + 1;
    int ta2 = 2*i + 2; if (ta2 > NT-1) ta2 = NT-1;
    int tb2 = 2*i + 3; if (tb2 > NT-1) tb2 = NT-1;

    LDA8(0, 0); LDB8(0, 0); STB(1, 0, tb);
    BAR(); LGKM0(); MFMAQ(0, 0); BAR();
    LDB8(0, 1); STB(1, 1, tb);
    BAR(); LGKM0(); MFMAQ(0, 1); BAR();
    LDA8(0, 1); STA(1, 1, tb);
    BAR(); LGKM0(); MFMAQ(1, 1); BAR();
    LDB8(0, 0); STA(0, 0, ta2);
    BAR(); LGKM0(); MFMAQ(1, 0); VM6(); BAR();
    LDA8(1, 0); LDB8(1, 0); STB(0, 1, ta2);
    BAR(); LGKM0(); MFMAQ(0, 0); VM6(); BAR();
    LDB8(1, 1); STA(0, 1, ta2);
    BAR(); LGKM0(); MFMAQ(0, 1); VM6(); BAR();
    LDA8(1, 1); STB(0, 0, ta2);
    BAR(); LGKM0(); MFMAQ(1, 1); BAR();
    LDB8(1, 0); STA(1, 0, tb2);
    BAR(); LGKM0(); MFMAQ(1, 0); VM2(); BAR();
  }
  asm volatile("s_waitcnt vmcnt(0)" ::: "memory");

  float bv[4];
  #pragma unroll
  for (int f = 0; f < 4; f++) bv[f] = bias ? bias[n0 + wn + f*16 + l16] : 0.f;
  const int col0 = n0 + wn + l16;
  #pragma unroll
  for (int i2 = 0; i2 < 8; i2++) {
    #pragma unroll
    for (int r = 0; r < 4; r++) {
      int row = m0 + wm + i2*16 + quad*4 + r;
      if (row < M) {
        #pragma unroll
        for (int f = 0; f < 4; f++) {
          float v = acc[i2][f][r] + bv[f];
          if (mode == 2) v = fgelu(v);
          Cout[(size_t)row * ldc + col0 + f*16] = f2bf(v);
        }
      }
    }
  }
  #undef STA
  #undef STB
  #undef LDA8
  #undef LDB8
  #undef MFMAQ
  #undef BAR
  #undef LGKM0
  #undef VM6
  #undef VM2
}

// ---------------------------------------------------------------- 128x256 8-phase GEMM (gemm8w) — full-grid for N=512/M=8176 shapes
__global__ __launch_bounds__(512, 2) void lma_gemm8w(
    const unsigned short* __restrict__ A, int lda,
    const unsigned short* __restrict__ Bt0, const unsigned short* __restrict__ Bt1,
    const float* __restrict__ bias0, const float* __restrict__ bias1,
    void* __restrict__ Cout, int ldc,
    int M, int N, int K, int mode, int nmt)
{
  __shared__ unsigned short LsA[2][128*64];   // 2 x 16KB
  __shared__ unsigned short LsB[2][256*64];   // 2 x 32KB
  const int tid = threadIdx.x;
  const int w = tid >> 6, lane = tid & 63, quad = lane >> 4, l16 = lane & 15;
  const int mt = blockIdx.x % nmt, nt = blockIdx.x / nmt;
  const int m0 = mt * 128, n0 = nt * 256;
  const int brch = m0 >> 13;
  const unsigned short* Bt = brch ? Bt1 : Bt0;
  const float* bias = brch ? bias1 : bias0;
  const int wm = (w >> 2) * 64, wn = (w & 3) * 64;

  f32x4 acc[4][4];
  #pragma unroll
  for (int i = 0; i < 4; i++)
    #pragma unroll
    for (int f = 0; f < 4; f++) acc[i][f] = f32x4{0.f,0.f,0.f,0.f};

  const int lrow8 = lane >> 3;
  const int lkb   = lane & 7;
  const int NT = K >> 6;

  const unsigned short* aP[2]; int aD[2];
  const unsigned short* bP[2][2]; int bD[2][2];
  #pragma unroll
  for (int hf = 0; hf < 2; hf++) {
    int rtA = hf*64 + w*8 + lrow8;
    int kbA = lkb ^ (rtA & 7);
    int ga = m0 + rtA; if (ga > M-1) ga = M-1;
    aP[hf] = A + (size_t)ga * lda + kbA*8;
    aD[hf] = (hf*64 + w*8) * 64;
    #pragma unroll
    for (int c = 0; c < 2; c++) {
      int rtB = hf*128 + (w*2 + c)*8 + lrow8;
      int kbB = lkb ^ (rtB & 7);
      int gb = n0 + rtB; if (gb > N-1) gb = N-1;
      bP[hf][c] = Bt + (size_t)gb * K + kbB*8;
      bD[hf][c] = (hf*128 + (w*2 + c)*8) * 64;
    }
  }

  bf16x8 af[2][2], bf[2][2];

  #define WSTA(buf, hf, kt) { glds16(aP[hf] + (size_t)(kt)*64, &LsA[buf][aD[hf]]); }
  #define WSTB(buf, hf, kt) { _Pragma("unroll") for (int c = 0; c < 2; c++) \
      glds16(bP[hf][c] + (size_t)(kt)*64, &LsB[buf][bD[hf][c]]); }
  #define WLDA(buf, mq) { _Pragma("unroll") for (int j = 0; j < 2; j++){ \
      int rt = wm + (mq)*32 + j*16 + l16; \
      const unsigned short* base = &LsA[buf][rt*64]; \
      int f_ = rt & 7; \
      af[j][0] = *(const bf16x8*)(base + ((    quad) ^ f_)*8); \
      af[j][1] = *(const bf16x8*)(base + ((4 + quad) ^ f_)*8); } }
  #define WLDB(buf, nq) { _Pragma("unroll") for (int j = 0; j < 2; j++){ \
      int rt = wn + (nq)*32 + j*16 + l16; \
      const unsigned short* base = &LsB[buf][rt*64]; \
      int f_ = rt & 7; \
      bf[j][0] = *(const bf16x8*)(base + ((    quad) ^ f_)*8); \
      bf[j][1] = *(const bf16x8*)(base + ((4 + quad) ^ f_)*8); } }
  #define WMFMAQ(mq, nq) { __builtin_amdgcn_s_setprio(1); \
      _Pragma("unroll") for (int j = 0; j < 2; j++) \
        _Pragma("unroll") for (int j2 = 0; j2 < 2; j2++){ \
          acc[(mq)*2+j][(nq)*2+j2] = __builtin_amdgcn_mfma_f32_16x16x32_bf16(af[j][0], bf[j2][0], acc[(mq)*2+j][(nq)*2+j2], 0, 0, 0); \
          acc[(mq)*2+j][(nq)*2+j2] = __builtin_amdgcn_mfma_f32_16x16x32_bf16(af[j][1], bf[j2][1], acc[(mq)*2+j][(nq)*2+j2], 0, 0, 0); } \
      __builtin_amdgcn_s_setprio(0); }
  #define WBAR()   { SB(); __builtin_amdgcn_s_barrier(); SB(); }
  #define WLGKM0() { asm volatile("s_waitcnt lgkmcnt(0)" ::: "memory"); SB(); }
  #define WVM4()   { asm volatile("s_waitcnt vmcnt(4)"   ::: "memory"); SB(); }
  #define WVM1()   { asm volatile("s_waitcnt vmcnt(1)"   ::: "memory"); SB(); }

  WSTA(0, 0, 0); WSTB(0, 0, 0); WSTB(0, 1, 0); WSTA(0, 1, 0);
  WSTA(1, 0, 1);
  WVM1(); WBAR();

  const int NI = NT >> 1;
  for (int i = 0; i < NI; i++) {
    const int tb  = 2*i + 1;
    int ta2 = 2*i + 2; if (ta2 > NT-1) ta2 = NT-1;
    int tb2 = 2*i + 3; if (tb2 > NT-1) tb2 = NT-1;

    WLDA(0, 0); WLDB(0, 0); WSTB(1, 0, tb);
    WBAR(); WLGKM0(); WMFMAQ(0, 0); WBAR();
    WLDB(0, 1); WSTB(1, 1, tb);
    WBAR(); WLGKM0(); WMFMAQ(0, 1); WBAR();
    WLDA(0, 1); WSTA(1, 1, tb);
    WBAR(); WLGKM0(); WMFMAQ(1, 1); WBAR();
    WLDB(0, 0); WSTA(0, 0, ta2);
    WBAR(); WLGKM0(); WMFMAQ(1, 0); WVM4(); WBAR();
    WLDA(1, 0); WLDB(1, 0); WSTB(0, 1, ta2);
    WBAR(); WLGKM0(); WMFMAQ(0, 0); WVM4(); WBAR();
    WLDB(1, 1); WSTA(0, 1, ta2);
    WBAR(); WLGKM0(); WMFMAQ(0, 1); WVM4(); WBAR();
    WLDA(1, 1); WSTB(0, 0, ta2);
    WBAR(); WLGKM0(); WMFMAQ(1, 1); WBAR();
    WLDB(1, 0); WSTA(1, 0, tb2);
    WBAR(); WLGKM0(); WMFMAQ(1, 0); WVM1(); WBAR();
  }
  asm volatile("s_waitcnt vmcnt(0)" ::: "memory");

  float bv[4];
  #pragma unroll
  for (int f = 0; f < 4; f++) bv[f] = bias ? bias[n0 + wn + f*16 + l16] : 0.f;
  const int col0 = n0 + wn + l16;
  #pragma unroll
  for (int i2 = 0; i2 < 4; i2++) {
    #pragma unroll
    for (int r = 0; r < 4; r++) {
      int row = m0 + wm + i2*16 + quad*4 + r;
      if (row < M) {
        #pragma unroll
        for (int f = 0; f < 4; f++) {
          float v = acc[i2][f][r] + bv[f];
          if (mode == 2) v = fgelu(v);
          else if (mode == 1) v *= 0.18033688011112042f;   // 0.125 * log2(e)
          if (mode <= 2) ((unsigned short*)Cout)[(size_t)row * ldc + col0 + f*16] = f2bf(v);
          else if (mode == 3) ((float*)Cout)[(size_t)row * ldc + col0 + f*16] = v;
          else {
            int sr = row % S2_, bb2 = row / S2_;
            ((float*)Cout)[((size_t)sr * B_ + bb2) * ldc + col0 + f*16] = v;
          }
        }
      }
    }
  }
  #undef WSTA
  #undef WSTB
  #undef WLDA
  #undef WLDB
  #undef WMFMAQ
  #undef WBAR
  #undef WLGKM0
  #undef WVM4
  #undef WVM1
}

// ---------------------------------------------------------------- block reduction helper
__device__ __forceinline__ void lma_red2(float& s, float& sq){
  __shared__ float red[16];
  #pragma unroll
  for (int msk = 1; msk < 64; msk <<= 1){ s += __shfl_xor(s, msk); sq += __shfl_xor(sq, msk); }
  int w = threadIdx.x >> 6;
  if ((threadIdx.x & 63) == 0){ red[w] = s; red[8 + w] = sq; }
  __syncthreads();
  s  = red[0] + red[1] + red[2] + red[3];
  sq = red[8] + red[9] + red[10] + red[11];
}

// ---------------------------------------------------------------- generic LN (f32 in, bf16 or f32 out)
__global__ __launch_bounds__(256) void lma_ln(const float* __restrict__ in,
                                              const float* __restrict__ g, const float* __restrict__ bb,
                                              int D, unsigned short* __restrict__ obf, float* __restrict__ of32){
  int row = blockIdx.x, t = threadIdx.x;
  const float* x = in + (size_t)row * D;
  float s = 0.f, sq = 0.f;
  for (int d = t; d < D; d += 256){ float v = x[d]; s += v; sq += v * v; }
  lma_red2(s, sq);
  float mean = s / D;
  float var = sq / D - mean * mean;
  float rstd = rsqrtf(fmaxf(var, 0.f) + 1e-12f);
  if (obf) {
    for (int d = t; d < D; d += 256) obf[(size_t)row * D + d] = f2bf((x[d] - mean) * rstd * g[d] + bb[d]);
  } else {
    for (int d = t; d < D; d += 256) of32[(size_t)row * D + d] = (x[d] - mean) * rstd * g[d] + bb[d];
  }
}

// ---------------------------------------------------------------- branch-combined LN over T12b (bf16, D=512) -> LQ2 bf16
__global__ __launch_bounds__(256) void lma_ln2(const unsigned short* __restrict__ T12b,
                                               const float* __restrict__ fg, const float* __restrict__ fbb,
                                               const float* __restrict__ bg, const float* __restrict__ bbb,
                                               unsigned short* __restrict__ LQ2){
  int m = blockIdx.x, t = threadIdx.x;           // 0..2*M_-1
  int fb = (m >= M_);
  int idx = m - fb * M_;
  const float* g = fb ? bg : fg;
  const float* bb = fb ? bbb : fbb;
  const unsigned short* x = T12b + ((size_t)fb * PAD_ + idx) * 512;
  unsigned short* o = LQ2 + ((size_t)fb * PAD_ + idx) * 512;
  float v0 = bf2f(x[t]), v1 = bf2f(x[t + 256]);
  float s = v0 + v1, sq = v0*v0 + v1*v1;
  lma_red2(s, sq);
  float mean = s / 512.f;
  float var = sq / 512.f - mean * mean;
  float rstd = rsqrtf(fmaxf(var, 0.f) + 1e-12f);
  o[t]       = f2bf((v0 - mean) * rstd * g[t]       + bb[t]);
  o[t + 256] = f2bf((v1 - mean) * rstd * g[t + 256] + bb[t + 256]);
}

// ---------------------------------------------------------------- attn LN: LN(residual(hidden)+[pf,pb](bf16)) -> bf16 (M_ x 1024)
__global__ __launch_bounds__(256) void lma_attn_ln(const unsigned short* __restrict__ pf,
                                                   const unsigned short* __restrict__ pb,
                                                   const float* __restrict__ hidden,
                                                   const float* __restrict__ g, const float* __restrict__ bb,
                                                   unsigned short* __restrict__ out){
  int m = blockIdx.x, t = threadIdx.x;
  int b = m / S2_, s = m - b * S2_;
  const float* hf = hidden + ((size_t)s       * B_ + b) * 1024;
  const float* hb = hidden + ((size_t)(s + 2) * B_ + b) * 1024;
  float v[4]; float sum = 0.f, sq = 0.f;
  #pragma unroll
  for (int j = 0; j < 4; j++){
    int d = t + j * 256;
    float x = (d < 512) ? (bf2f(pf[(size_t)m * 512 + d]) + hf[d])
                        : (bf2f(pb[(size_t)m * 512 + (d - 512)]) + hb[d]);
    v[j] = x; sum += x; sq += x * x;
  }
  lma_red2(sum, sq);
  float mean = sum / 1024.f;
  float var = sq / 1024.f - mean * mean;
  float rstd = rsqrtf(fmaxf(var, 0.f) + 1e-12f);
  #pragma unroll
  for (int j = 0; j < 4; j++){
    int d = t + j * 256;
    out[(size_t)m * 1024 + d] = f2bf((v[j] - mean) * rstd * g[d] + bb[d]);
  }
}

// ---------------------------------------------------------------- combined flash attention v11: KVBLK=128 (2 k-tiles/iter)
// attn10 was 4k cycles/tile vs ~400 of work — per-iteration fixed cost
// (2 barriers + vmcnt drain + 2 shfl-reduce pairs + defer-max pass) dominates.
// v11 amortizes it over TWO 64-row k-tiles: Kl/Vl are 2-buffer arrays of the
// IDENTICAL proven 64x64 swizzled tiles; one barrier pair / softmax-reduce /
// defer-max per 128 rows. QK per half (kf stays 32 VGPR); PV per half reusing
// the same 2KB wave-private P buffer (DS ops are in-order per wave -> WAR safe
// without barrier). Odd trailing 64-tile: block-uniform h2=false path skips
// stage/QK/mask/exp/PV of subs 4-7 (no stale-V NaN can reach MFMA). LDS 40KB
// -> exactly 4 blocks/CU. Interior-skip "full" cannot overshoot khi (fwd:
// kt0+span<=q0<=khi; bwd: <L2); masked paths cover all overshoot rows; V cols
// <=1023 since kt0 is a multiple of 64 with kt0+64<=960 when h2.
__global__ __launch_bounds__(256, 4) void lma_attn11(const unsigned short* __restrict__ Q2,
                                                     const unsigned short* __restrict__ KV2,
                                                     const unsigned short* __restrict__ VT2,
                                                     unsigned short* __restrict__ CT2,
                                                     const int* __restrict__ lens){
  __shared__ unsigned short Kl[2][64*64];
  __shared__ unsigned short Vl[2][64*64];
  __shared__ __align__(16) unsigned short Pl[4][16*64];

  const int tid = threadIdx.x;
  const int w = tid >> 6, lane = tid & 63, quad = lane >> 4, l16 = lane & 15;
  const int id = blockIdx.x;                 // 1024 blocks: [qt:4][h:3][b:3]
  const int qt = id >> 6, h = (id >> 3) & 7, b = id & 7;
  const int L2 = lens[b] - 2;
  const int q0wg = qt * 64;
  const int q0 = q0wg + w * 16;
  const int qg = q0 + l16;
  const int qload = (qg > S2_-1) ? (S2_-1) : qg;

  const size_t qbase  = ((size_t)b * S2_) * 512  + h * 64;
  const size_t kbase  = ((size_t)b * S2_) * 1024 + h * 64;
  const size_t vtbase = ((size_t)(b * 8 + h) * 64) * 1024;
  char* Pb = (char*)&Pl[w][0];

  const int lrow = lane >> 3;
  const int g0s  = (lane & 7) ^ lrow;
  const int x7   = l16 & 7;
  const int x7s  = x7 << 4;

  for (int fb = 0; fb < 2; fb++) {
    const int backward = fb;
    const unsigned short* Q  = Q2  + (size_t)fb * PAD_ * 512;
    const unsigned short* Kx = KV2 + (size_t)fb * PAD_ * 1024;
    const unsigned short* VT = VT2 + (size_t)fb * VTS_;
    unsigned short* CTX      = CT2 + (size_t)fb * PAD_ * 512;

    bf16x8 qf[2];
    {
      const unsigned short* qp = Q + qbase + (size_t)qload * 512 + quad * 8;
      qf[0] = *(const bf16x8*)(qp);
      qf[1] = *(const bf16x8*)(qp + 32);
    }

    float mi = -3e38f, li = 0.f;
    f32x4 ot[4];
    #pragma unroll
    for (int f = 0; f < 4; f++) ot[f] = f32x4{0.f,0.f,0.f,0.f};

    int klo = 0, khi = S2_ - 1;
    if (q0wg + 63 < L2) {
      if (!backward) khi = q0wg + 63;
      else { klo = q0wg; khi = L2 - 1; }
    }

    for (int kt0 = klo; kt0 <= khi; kt0 += 128) {
      const bool h2 = (kt0 + 64 <= khi);       // block-uniform
      const int span = h2 ? 127 : 63;

      // stage tile 0 (and tile 1 if present) — identical 64x64 swizzled tiles
      #pragma unroll
      for (int c = 0; c < 2; c++) {
        int r = w*16 + c*8 + lrow;
        int kr = kt0 + r; if (kr > S2_-1) kr = S2_-1;
        glds16(Kx + kbase + (size_t)kr * 1024 + g0s * 8, &Kl[0][(w*16 + c*8) * 64]);
        glds16(VT + vtbase + (size_t)r * 1024 + kt0 + g0s * 8, &Vl[0][(w*16 + c*8) * 64]);
      }
      if (h2) {
        #pragma unroll
        for (int c = 0; c < 2; c++) {
          int r = w*16 + c*8 + lrow;
          int kr = kt0 + 64 + r; if (kr > S2_-1) kr = S2_-1;
          glds16(Kx + kbase + (size_t)kr * 1024 + g0s * 8, &Kl[1][(w*16 + c*8) * 64]);
          glds16(VT + vtbase + (size_t)r * 1024 + (kt0 + 64) + g0s * 8, &Vl[1][(w*16 + c*8) * 64]);
        }
      }
      __syncthreads();

      f32x4 st[8];
      // QK half 0
      {
        bf16x8 kf[4][2];
        #pragma unroll
        for (int sub = 0; sub < 4; sub++) {
          const unsigned short* kp = &Kl[0][(sub*16 + l16) * 64];
          kf[sub][0] = *(const bf16x8*)(kp + (( quad      ^ x7) * 8));
          kf[sub][1] = *(const bf16x8*)(kp + (((quad + 4) ^ x7) * 8));
        }
        __builtin_amdgcn_s_setprio(1);
        #pragma unroll
        for (int sub = 0; sub < 4; sub++) {
          f32x4 s = f32x4{0.f,0.f,0.f,0.f};
          s = __builtin_amdgcn_mfma_f32_16x16x32_bf16(kf[sub][0], qf[0], s, 0, 0, 0);
          s = __builtin_amdgcn_mfma_f32_16x16x32_bf16(kf[sub][1], qf[1], s, 0, 0, 0);
          st[sub] = s;
        }
        __builtin_amdgcn_s_setprio(0);
      }
      // QK half 1
      if (h2) {
        bf16x8 kf[4][2];
        #pragma unroll
        for (int sub = 0; sub < 4; sub++) {
          const unsigned short* kp = &Kl[1][(sub*16 + l16) * 64];
          kf[sub][0] = *(const bf16x8*)(kp + (( quad      ^ x7) * 8));
          kf[sub][1] = *(const bf16x8*)(kp + (((quad + 4) ^ x7) * 8));
        }
        __builtin_amdgcn_s_setprio(1);
        #pragma unroll
        for (int sub = 0; sub < 4; sub++) {
          f32x4 s = f32x4{0.f,0.f,0.f,0.f};
          s = __builtin_amdgcn_mfma_f32_16x16x32_bf16(kf[sub][0], qf[0], s, 0, 0, 0);
          s = __builtin_amdgcn_mfma_f32_16x16x32_bf16(kf[sub][1], qf[1], s, 0, 0, 0);
          st[4 + sub] = s;
        }
        __builtin_amdgcn_s_setprio(0);
      }

      // interior-tile skip: wave-uniform over the whole span
      {
        bool tail = (kt0 + span > S2_ - 1);
        bool full;
        if (!backward) full = !tail && ((kt0 + span <= q0) || (q0 >= L2));
        else           full = !tail && ((q0 >= L2) || ((kt0 >= q0 + 15) && (kt0 + span < L2)));
        if (!full) {
          #pragma unroll
          for (int sub = 0; sub < 4; sub++) {
            #pragma unroll
            for (int r = 0; r < 4; r++) {
              int kg = kt0 + sub*16 + quad*4 + r;
              bool ok;
              if (!backward) ok = (kg < S2_) && ((qg >= L2) || (kg <= qg));
              else           ok = (kg < S2_) && ((qg >= L2) || ((kg >= qg) && (kg < L2)));
              if (!ok) st[sub][r] = -3e38f;
            }
          }
          if (h2) {
            #pragma unroll
            for (int sub = 0; sub < 4; sub++) {
              #pragma unroll
              for (int r = 0; r < 4; r++) {
                int kg = kt0 + 64 + sub*16 + quad*4 + r;
                bool ok;
                if (!backward) ok = (kg < S2_) && ((qg >= L2) || (kg <= qg));
                else           ok = (kg < S2_) && ((qg >= L2) || ((kg >= qg) && (kg < L2)));
                if (!ok) st[4 + sub][r] = -3e38f;
              }
            }
          }
        }
      }

      float mx = -3e38f;
      #pragma unroll
      for (int sub = 0; sub < 4; sub++)
        #pragma unroll
        for (int r = 0; r < 4; r++) mx = fmaxf(mx, st[sub][r]);
      if (h2) {
        #pragma unroll
        for (int sub = 4; sub < 8; sub++)
          #pragma unroll
          for (int r = 0; r < 4; r++) mx = fmaxf(mx, st[sub][r]);
      }
      mx = fmaxf(mx, __shfl_xor(mx, 16));
      mx = fmaxf(mx, __shfl_xor(mx, 32));

      // defer-max (T13): once per 128 rows
      if (__any(mx > mi + 11.f)) {
        float mn = fmaxf(mi, mx);
        float al = fexp2(mi - mn);
        li *= al;
        #pragma unroll
        for (int f = 0; f < 4; f++)
          #pragma unroll
          for (int r = 0; r < 4; r++) ot[f][r] *= al;
        mi = mn;
      }

      float rs = 0.f;
      #pragma unroll
      for (int sub = 0; sub < 4; sub++)
        #pragma unroll
        for (int r = 0; r < 4; r++) {
          float p = fexp2(st[sub][r] - mi);
          st[sub][r] = p; rs += p;
        }
      if (h2) {
        #pragma unroll
        for (int sub = 4; sub < 8; sub++)
          #pragma unroll
          for (int r = 0; r < 4; r++) {
            float p = fexp2(st[sub][r] - mi);
            st[sub][r] = p; rs += p;
          }
      }
      rs += __shfl_xor(rs, 16);
      rs += __shfl_xor(rs, 32);
      li += rs;

      // PV half 0: P subs 0-3 via wave-private swizzled LDS (proven pattern)
      #pragma unroll
      for (int sub = 0; sub < 4; sub++) {
        u32x2 pk2;
        pk2[0] = cvtpk(st[sub][0], st[sub][1]);
        pk2[1] = cvtpk(st[sub][2], st[sub][3]);
        *(u32x2*)(Pb + (l16*128 + ((sub*32 + quad*8) ^ x7s))) = pk2;
      }
      {
        bf16x8 pfr0 = *(const bf16x8*)(Pb + (l16*128 + (( 0 + quad*16) ^ x7s)));
        bf16x8 pfr1 = *(const bf16x8*)(Pb + (l16*128 + ((64 + quad*16) ^ x7s)));
        bf16x8 vf[4][2];
        #pragma unroll
        for (int f = 0; f < 4; f++) {
          const unsigned short* vp = &Vl[0][(f*16 + l16) * 64];
          vf[f][0] = *(const bf16x8*)(vp + (( quad      ^ x7) * 8));
          vf[f][1] = *(const bf16x8*)(vp + (((quad + 4) ^ x7) * 8));
        }
        __builtin_amdgcn_s_setprio(1);
        #pragma unroll
        for (int f = 0; f < 4; f++) {
          ot[f] = __builtin_amdgcn_mfma_f32_16x16x32_bf16(vf[f][0], pfr0, ot[f], 0, 0, 0);
          ot[f] = __builtin_amdgcn_mfma_f32_16x16x32_bf16(vf[f][1], pfr1, ot[f], 0, 0, 0);
        }
        __builtin_amdgcn_s_setprio(0);
      }
      // PV half 1: reuse the same P buffer (per-wave DS ops are in-order -> WAR safe)
      if (h2) {
        #pragma unroll
        for (int sub = 0; sub < 4; sub++) {
          u32x2 pk2;
          pk2[0] = cvtpk(st[4+sub][0], st[4+sub][1]);
          pk2[1] = cvtpk(st[4+sub][2], st[4+sub][3]);
          *(u32x2*)(Pb + (l16*128 + ((sub*32 + quad*8) ^ x7s))) = pk2;
        }
        bf16x8 pfr0 = *(const bf16x8*)(Pb + (l16*128 + (( 0 + quad*16) ^ x7s)));
        bf16x8 pfr1 = *(const bf16x8*)(Pb + (l16*128 + ((64 + quad*16) ^ x7s)));
        bf16x8 vf[4][2];
        #pragma unroll
        for (int f = 0; f < 4; f++) {
          const unsigned short* vp = &Vl[1][(f*16 + l16) * 64];
          vf[f][0] = *(const bf16x8*)(vp + (( quad      ^ x7) * 8));
          vf[f][1] = *(const bf16x8*)(vp + (((quad + 4) ^ x7) * 8));
        }
        __builtin_amdgcn_s_setprio(1);
        #pragma unroll
        for (int f = 0; f < 4; f++) {
          ot[f] = __builtin_amdgcn_mfma_f32_16x16x32_bf16(vf[f][0], pfr0, ot[f], 0, 0, 0);
          ot[f] = __builtin_amdgcn_mfma_f32_16x16x32_bf16(vf[f][1], pfr1, ot[f], 0, 0, 0);
        }
        __builtin_amdgcn_s_setprio(0);
      }
      __syncthreads();
    }

    if (qg < S2_) {
      float rcp = 1.f / li;
      #pragma unroll
      for (int f = 0; f < 4; f++) {
        ushort4 pk;
        pk.x = f2bf(ot[f][0] * rcp); pk.y = f2bf(ot[f][1] * rcp);
        pk.z = f2bf(ot[f][2] * rcp); pk.w = f2bf(ot[f][3] * rcp);
        *(ushort4*)&CTX[qbase + (size_t)qg * 512 + f*16 + quad*4] = pk;
      }
    }
  }
}

// ----------------------------------------------------------------
extern "C" void kernel_launch(void* const* d_in, const int* in_sizes, int n_in,
                              void* d_out, int out_size, void* d_ws, size_t ws_size,
                              hipStream_t stream)
{
  const float* hidden = (const float*)d_in[0];
  const int*   lens   = (const int*)d_in[1];
  const float* fw[14]; for (int i = 0; i < 14; i++) fw[i] = (const float*)d_in[2 + i];
  const float* bw[14]; for (int i = 0; i < 14; i++) bw[i] = (const float*)d_in[16 + i];
  const float* attn_g = (const float*)d_in[30];
  const float* attn_b = (const float*)d_in[31];
  const float* o_w1 = (const float*)d_in[32];
  const float* o_b1 = (const float*)d_in[33];
  const float* o_w2 = (const float*)d_in[34];
  const float* o_b2 = (const float*)d_in[35];
  const float* o_lng = (const float*)d_in[36];
  const float* o_lnb = (const float*)d_in[37];

  char* ws = (char*)d_ws;
  size_t off = 0;
  auto alloc = [&](size_t bytes)->char* {
    off = (off + 255) & ~(size_t)255;
    char* p = ws + off; off += bytes; return p;
  };

  unsigned short* fw1t = (unsigned short*)alloc((size_t)1024*1024*2);
  unsigned short* fw2t = (unsigned short*)alloc((size_t)512*1024*2);
  unsigned short* fqt  = (unsigned short*)alloc((size_t)512*512*2);
  unsigned short* fkvt = (unsigned short*)alloc((size_t)1024*512*2);  // [K(512 rows); V(512 rows)]
  unsigned short* fot  = (unsigned short*)alloc((size_t)512*512*2);
  unsigned short* bw1t = (unsigned short*)alloc((size_t)1024*1024*2);
  unsigned short* bw2t = (unsigned short*)alloc((size_t)512*1024*2);
  unsigned short* bqt  = (unsigned short*)alloc((size_t)512*512*2);
  unsigned short* bkvt = (unsigned short*)alloc((size_t)1024*512*2);
  unsigned short* bot  = (unsigned short*)alloc((size_t)512*512*2);
  unsigned short* ow1t = (unsigned short*)alloc((size_t)1024*1024*2);
  unsigned short* ow2t = (unsigned short*)alloc((size_t)1024*1024*2);
  float*          biasKV = (float*)alloc(2048*4);

  unsigned short* Xb   = (unsigned short*)alloc((size_t)M_*1024*2);
  unsigned short* big1 = (unsigned short*)alloc((size_t)2*PAD_*1024*2);
  float*          big2 = (float*)alloc((size_t)2*PAD_*512*4);
  unsigned short* LQCT = (unsigned short*)alloc((size_t)2*PAD_*512*2);
  unsigned short* Q2   = (unsigned short*)alloc((size_t)2*PAD_*512*2);

  unsigned short* H12 = big1, *KV2 = big1, *H1o = big1;
  // big2 partitions: [0 .. 2*VTS_) = T12b (bf16) then VT2 (bf16);
  //                  [2*VTS_ .. 4*VTS_) = P2b (bf16 out-proj). Exactly fills big2.
  unsigned short* T12b = (unsigned short*)big2;
  unsigned short* VT2  = (unsigned short*)big2;
  unsigned short* P2b  = (unsigned short*)big2 + 2*VTS_;
  unsigned short* LQ2 = LQCT, *CT2 = LQCT;

  lma_prep_x<<<M_, 256, 0, stream>>>(hidden, Xb);

  {
    TPack tp;
    const float* srcs[14] = { fw[0], fw[2], fw[6], fw[8], fw[10], fw[12],
                              bw[0], bw[2], bw[6], bw[8], bw[10], bw[12],
                              o_w1, o_w2 };
    unsigned short* dsts[14] = { fw1t, fw2t, fqt, fkvt, fkvt + (size_t)512*512, fot,
                                 bw1t, bw2t, bqt, bkvt, bkvt + (size_t)512*512, bot,
                                 ow1t, ow2t };
    int Ks[14] = {1024,1024,512,512,512,512, 1024,1024,512,512,512,512, 1024,1024};
    int Ns[14] = {1024, 512,512,512,512,512, 1024, 512,512,512,512,512, 1024,1024};
    for (int i = 0; i < 14; i++){ tp.src[i]=srcs[i]; tp.dst[i]=dsts[i]; tp.K[i]=Ks[i]; tp.N[i]=Ns[i]; }
    lma_transpose_all<<<dim3(32, 32, 14), 256, 0, stream>>>(tp);
  }
  lma_biascat<<<8, 256, 0, stream>>>(fw[9], fw[11], bw[9], bw[11], biasKV);

  auto G8 = [&](const unsigned short* A, int lda,
                const unsigned short* B0, const unsigned short* B1,
                const float* b0, const float* b1,
                unsigned short* C, int ldc, int M, int N, int K, int mode, int amap){
    int nmt = M / 256;
    lma_gemm8<<<dim3(nmt * (N/256)), 512, 0, stream>>>(A, lda, B0, B1, b0, b1, C, ldc, M, N, K, mode, amap, nmt);
  };
  auto G8W = [&](const unsigned short* A, int lda,
                 const unsigned short* B0, const unsigned short* B1,
                 const float* b0, const float* b1,
                 void* C, int ldc, int M, int N, int K, int mode){
    int nmt = (M + 127) / 128;
    lma_gemm8w<<<dim3(nmt * (N/256)), 512, 0, stream>>>(A, lda, B0, B1, b0, b1, C, ldc, M, N, K, mode, nmt);
  };

  // both-branch FFN + LN + projections (rows<8192 = forward, >=8192 = backward)
  G8(Xb, 1024, fw1t, bw1t, fw[1], bw[1], H12, 1024, 2*PAD_, 1024, 1024, 2, 1);   // FFN1+gelu (256^2 8-phase)
  G8W(H12, 1024, fw2t, bw2t, fw[3], bw[3], T12b, 512, 2*PAD_, 512, 1024, 0);     // FFN2 -> bf16 (128x256 8-phase)
  lma_ln2<<<2*M_, 256, 0, stream>>>(T12b, fw[4], fw[5], bw[4], bw[5], LQ2);
  G8W(LQ2, 512, fqt, bqt, fw[7], bw[7], Q2, 512, 2*PAD_, 512, 512, 1);           // Q (x0.125*log2e)
  G8(Xb, 1024, fkvt, bkvt, biasKV, biasKV + 1024, KV2, 1024, 2*PAD_, 1024, 512, 0, 2); // K|V (256^2 8-phase)
  lma_vt2<<<dim3(32, 16, 16), 256, 0, stream>>>(KV2, VT2);

  lma_attn11<<<dim3(1024), 256, 0, stream>>>(Q2, KV2, VT2, CT2, lens);

  G8W(CT2, 512, fot, bot, fw[13], bw[13], P2b, 512, 2*PAD_, 512, 512, 0);        // out proj -> bf16

  lma_attn_ln<<<M_, 256, 0, stream>>>(P2b, P2b + (size_t)PAD_*512, hidden, attn_g, attn_b, Xb);

  G8W(Xb, 1024, ow1t, ow1t, o_b1, o_b1, H1o, 1024, M_, 1024, 1024, 2);           // out FFN1+gelu
  G8W(H1o, 1024, ow2t, ow2t, o_b2, o_b2, (float*)d_out, 1024, M_, 1024, 1024, 4); // out FFN2 -> d_out (remapped)
  lma_ln<<<M_, 256, 0, stream>>>((float*)d_out, o_lng, o_lnb, 1024, nullptr, (float*)d_out);
}

// Round 12
// 516.723 us; speedup vs baseline: 1.2348x; 1.0556x over previous
//
#include <hip/hip_runtime.h>
#include <cmath>

#define S_ 1024
#define B_ 8
#define H_ 512
#define S2_ 1022
#define M_ (B_*S2_)     // 8176
#define PAD_ 8192
#define VTS_ ((size_t)8*8*64*1024)   // VT per-branch stride (4194304 shorts)

typedef __attribute__((ext_vector_type(8))) short bf16x8;
typedef __attribute__((ext_vector_type(4))) float f32x4;
typedef __attribute__((ext_vector_type(4))) unsigned int u32x4;
typedef __attribute__((ext_vector_type(2))) unsigned int u32x2;

__device__ __forceinline__ unsigned short f2bf(float f){
  unsigned int u = __float_as_uint(f);
  return (unsigned short)((u + 0x7fffu + ((u>>16)&1u)) >> 16);
}
__device__ __forceinline__ float bf2f(unsigned short u){
  return __uint_as_float((unsigned int)u << 16);
}
// tanh-approx gelu: x*sigmoid(2*(c1 x + c2 x^3)); |err vs erf-gelu| < ~3e-4
__device__ __forceinline__ float fgelu(float x){
  float u = x * (0.7978845608f + 0.0356774081f * x * x);
  return x / (1.f + __expf(-2.f * u));
}
// raw 2^x (v_exp_f32 is natively base-2)
__device__ __forceinline__ float fexp2(float x){
  float r; asm("v_exp_f32 %0, %1" : "=v"(r) : "v"(x)); return r;
}
// hardware packed f32->bf16 (RNE), lo -> bits[15:0], hi -> bits[31:16]
__device__ __forceinline__ unsigned int cvtpk(float lo, float hi){
  unsigned int r; asm("v_cvt_pk_bf16_f32 %0, %1, %2" : "=v"(r) : "v"(lo), "v"(hi)); return r;
}

__device__ __forceinline__ void glds16(const void* g, void* l){
  __builtin_amdgcn_global_load_lds((const __attribute__((address_space(1))) unsigned int*)g,
                                   (__attribute__((address_space(3))) unsigned int*)l, 16, 0, 0);
}
#define SB() __builtin_amdgcn_sched_barrier(0)

// ---------------------------------------------------------------- prep: X = [f[:-2], bk[2:]] bf16 (M_ x 1024)
__global__ __launch_bounds__(256) void lma_prep_x(const float* __restrict__ hidden,
                                                  unsigned short* __restrict__ Xb){
  int m = blockIdx.x; int dq = threadIdx.x * 4;
  int b = m / S2_, s = m - b * S2_;
  int srow = (dq < 512) ? s : (s + 2);
  const float* src = hidden + ((size_t)srow * B_ + b) * 1024 + dq;
  f32x4 v = *(const f32x4*)src;
  union { u32x2 u; unsigned short s4[4]; } pk;
  #pragma unroll
  for (int j = 0; j < 4; j++) pk.s4[j] = f2bf(v[j]);
  *(u32x2*)&Xb[(size_t)m * 1024 + dq] = pk.u;
}

// ---------------------------------------------------------------- batched weight transpose+cast
struct TPack {
  const float* src[14];
  unsigned short* dst[14];
  int K[14];
  int N[14];
};
__global__ __launch_bounds__(256) void lma_transpose_all(TPack p){
  int idx = blockIdx.z;
  int K = p.K[idx], N = p.N[idx];
  int kb = blockIdx.x * 32, nb = blockIdx.y * 32;
  if (kb >= K || nb >= N) return;
  const float* W = p.src[idx];
  unsigned short* WT = p.dst[idx];
  __shared__ float t[32][33];
  int tx = threadIdx.x & 31, ty = threadIdx.x >> 5;
  #pragma unroll
  for (int i = ty; i < 32; i += 8) t[i][tx] = W[(size_t)(kb + i) * N + nb + tx];
  __syncthreads();
  #pragma unroll
  for (int i = ty; i < 32; i += 8) WT[(size_t)(nb + i) * K + kb + tx] = f2bf(t[tx][i]);
}

// ---------------------------------------------------------------- concat K/V biases
__global__ __launch_bounds__(256) void lma_biascat(const float* __restrict__ fk, const float* __restrict__ fv,
                                                   const float* __restrict__ bk, const float* __restrict__ bv,
                                                   float* __restrict__ out){
  int i = blockIdx.x * 256 + threadIdx.x;     // 0..2047
  int fb = i >> 10, col = i & 1023;
  const float* s = (col < 512) ? (fb ? bk : fk) : (fb ? bv : fv);
  out[i] = s[col & 511];
}

// ---------------------------------------------------------------- V (in KV2, cols 512..1023) -> VT2[fb][b][h][d][s pad 1024]
// Pad cols s in [S2_,1024) ZEROED (aliased buffer may hold bf16-NaN bit patterns).
__global__ __launch_bounds__(256) void lma_vt2(const unsigned short* __restrict__ KV2,
                                               unsigned short* __restrict__ VT2){
  __shared__ unsigned short t[32][34];
  int s0 = blockIdx.x * 32, c0 = blockIdx.y * 32;
  int z = blockIdx.z, fb = z >> 3, b = z & 7;
  const unsigned short* V = KV2 + (size_t)fb * PAD_ * 1024 + 512;
  unsigned short* VT = VT2 + (size_t)fb * VTS_;
  int tx = threadIdx.x & 31, ty = threadIdx.x >> 5;
  #pragma unroll
  for (int i = ty; i < 32; i += 8){
    int s = s0 + i; if (s > S2_-1) s = S2_-1;
    t[i][tx] = V[((size_t)b * S2_ + s) * 1024 + c0 + tx];
  }
  __syncthreads();
  int s = s0 + tx;
  #pragma unroll
  for (int i = ty; i < 32; i += 8){
    int c = c0 + i, h = c >> 6, d = c & 63;
    VT[(((size_t)b * 8 + h) * 64 + d) * 1024 + s] = (s < S2_) ? t[tx][i] : (unsigned short)0;
  }
}

// ---------------------------------------------------------------- 128^2 2-phase GEMM (kept as fallback; no call sites)
__global__ __launch_bounds__(256) void lma_gemm2(
    const unsigned short* __restrict__ A, int lda,
    const unsigned short* __restrict__ Bt0, const unsigned short* __restrict__ Bt1,
    const float* __restrict__ bias0, const float* __restrict__ bias1,
    void* __restrict__ Cout, int ldc,
    int M, int N, int K, int mode, int amap, int nmt)
{
  __shared__ unsigned short Al[128*32];
  __shared__ unsigned short Bl[128*32];
  const int tid = threadIdx.x;
  const int w = tid >> 6, lane = tid & 63, quad = lane >> 4, l16 = lane & 15;
  const int mt = blockIdx.x % nmt, nt = blockIdx.x / nmt;
  const int m0 = mt * 128, n0 = nt * 128;
  const int brch = m0 >> 13;
  const unsigned short* Bt = brch ? Bt1 : Bt0;
  const float* bias = brch ? bias1 : bias0;
  const int coloff = (amap == 2 && brch) ? 512 : 0;
  const int wm = (w >> 1) * 64, wn = (w & 1) * 64;

  f32x4 acc[4][4];
  #pragma unroll
  for (int i = 0; i < 4; i++)
    #pragma unroll
    for (int f = 0; f < 4; f++) acc[i][f] = f32x4{0.f,0.f,0.f,0.f};

  const int srow = lane >> 2;
  const int spc  = (((lane & 3) ^ ((lane >> 3) & 3))) * 8;
  const int rswz = (l16 >> 1) & 3;

  for (int k0 = 0; k0 < K; k0 += 32) {
    #pragma unroll
    for (int c = 0; c < 2; c++) {
      int ra = w*32 + c*16 + srow;
      int ga = m0 + ra;
      int ar;
      if (amap == 0) { ar = (ga > M-1) ? (M-1) : ga; }
      else { ar = ga & (PAD_-1); if (ar > M_-1) ar = M_-1; }
      glds16(A + (size_t)ar * lda + coloff + k0 + spc, &Al[(w*32 + c*16) * 32]);
      int gb = n0 + ra; if (gb > N-1) gb = N-1;
      glds16(Bt + (size_t)gb * K + k0 + spc, &Bl[(w*32 + c*16) * 32]);
    }
    __syncthreads();
    bf16x8 af[4], bfr[4];
    #pragma unroll
    for (int i = 0; i < 4; i++) af[i]  = *(const bf16x8*)&Al[(wm + i*16 + l16)*32 + ((quad ^ rswz) * 8)];
    #pragma unroll
    for (int f = 0; f < 4; f++) bfr[f] = *(const bf16x8*)&Bl[(wn + f*16 + l16)*32 + ((quad ^ rswz) * 8)];
    #pragma unroll
    for (int i = 0; i < 4; i++)
      #pragma unroll
      for (int f = 0; f < 4; f++)
        acc[i][f] = __builtin_amdgcn_mfma_f32_16x16x32_bf16(af[i], bfr[f], acc[i][f], 0, 0, 0);
    __syncthreads();
  }

  float bv[4];
  #pragma unroll
  for (int f = 0; f < 4; f++) bv[f] = bias ? bias[n0 + wn + f*16 + l16] : 0.f;
  const int col0 = n0 + wn + l16;
  #pragma unroll
  for (int i = 0; i < 4; i++) {
    #pragma unroll
    for (int r = 0; r < 4; r++) {
      int row = m0 + wm + i*16 + quad*4 + r;
      if (row < M) {
        #pragma unroll
        for (int f = 0; f < 4; f++) {
          float v = acc[i][f][r] + bv[f];
          if (mode == 2) v = fgelu(v);
          else if (mode == 1) v *= 0.18033688011112042f;
          if (mode <= 2) ((unsigned short*)Cout)[(size_t)row * ldc + col0 + f*16] = f2bf(v);
          else if (mode == 3) ((float*)Cout)[(size_t)row * ldc + col0 + f*16] = v;
          else {
            int sr = row % S2_, bb2 = row / S2_;
            ((float*)Cout)[((size_t)sr * B_ + bb2) * ldc + col0 + f*16] = v;
          }
        }
      }
    }
  }
}

// ---------------------------------------------------------------- 256^2 8-phase GEMM v4 (T2+T3+T4+T5)
// Round-12 change: SCHED-FENCE DIET (m141 errata). v3 wrapped every s_barrier
// and vmcnt wait in sched_barrier(0) — 24 scheduler fences per iteration,
// the exact order-pinning failure m141 measured (880->510 TF). Rule #18 needs
// a fence in ONE place only: after the inline-asm lgkmcnt(0) that guards
// register-MFMA against hoisting above the ds_read wait. All other fences
// dropped; s_barrier and asm volatile are mutually ordered side-effecting ops,
// so the schedule-freedom is semantics-preserving.
__global__ __launch_bounds__(512, 2) void lma_gemm8(
    const unsigned short* __restrict__ A, int lda,
    const unsigned short* __restrict__ Bt0, const unsigned short* __restrict__ Bt1,
    const float* __restrict__ bias0, const float* __restrict__ bias1,
    unsigned short* __restrict__ Cout, int ldc,
    int M, int N, int K, int mode, int amap, int nmt)
{
  __shared__ unsigned short Ls[2][2][256*64];   // [buf][0=A,1=B][row*64+k]
  const int tid = threadIdx.x;
  const int w = tid >> 6, lane = tid & 63, quad = lane >> 4, l16 = lane & 15;
  const int mt = blockIdx.x % nmt, nt = blockIdx.x / nmt;
  const int m0 = mt * 256, n0 = nt * 256;
  const int brch = m0 >> 13;
  const unsigned short* Bt = brch ? Bt1 : Bt0;
  const float* bias = brch ? bias1 : bias0;
  const int coloff = (amap == 2 && brch) ? 512 : 0;
  const int wm = (w >> 2) * 128, wn = (w & 3) * 64;

  f32x4 acc[8][4];
  #pragma unroll
  for (int i = 0; i < 8; i++)
    #pragma unroll
    for (int f = 0; f < 4; f++) acc[i][f] = f32x4{0.f,0.f,0.f,0.f};

  const int lrow8 = lane >> 3;
  const int lkb   = lane & 7;
  const int NT = K >> 6;

  const unsigned short* aP[2][2]; const unsigned short* bP[2][2];
  int aD[2][2], bD[2][2];
  #pragma unroll
  for (int hf = 0; hf < 2; hf++)
    #pragma unroll
    for (int c = 0; c < 2; c++) {
      int rtA = (w>>2)*128 + hf*64 + ((w&3)*2 + c)*8 + lrow8;
      int kbA = lkb ^ (rtA & 7);
      int ga = m0 + rtA;
      int ar;
      if (amap == 0) { ar = (ga > M-1) ? (M-1) : ga; }
      else { ar = ga & (PAD_-1); if (ar > M_-1) ar = M_-1; }
      aP[hf][c] = A + (size_t)ar * lda + coloff + kbA*8;
      aD[hf][c] = ((w>>2)*128 + hf*64 + ((w&3)*2 + c)*8) * 64;
      int rtB = (w>>1)*64 + hf*32 + ((w&1)*2 + c)*8 + lrow8;
      int kbB = lkb ^ (rtB & 7);
      int gb = n0 + rtB; if (gb > N-1) gb = N-1;
      bP[hf][c] = Bt + (size_t)gb * K + kbB*8;
      bD[hf][c] = ((w>>1)*64 + hf*32 + ((w&1)*2 + c)*8) * 64;
    }

  bf16x8 af[4][2], bf[2][2];

  #define STA(buf, hf, kt) { _Pragma("unroll") for (int c = 0; c < 2; c++) \
      glds16(aP[hf][c] + (size_t)(kt)*64, &Ls[buf][0][aD[hf][c]]); }
  #define STB(buf, hf, kt) { _Pragma("unroll") for (int c = 0; c < 2; c++) \
      glds16(bP[hf][c] + (size_t)(kt)*64, &Ls[buf][1][bD[hf][c]]); }
  #define LDA8(buf, mq) { _Pragma("unroll") for (int j = 0; j < 4; j++){ \
      int rt = wm + (mq)*64 + j*16 + l16; \
      const unsigned short* base = &Ls[buf][0][rt*64]; \
      int f_ = rt & 7; \
      af[j][0] = *(const bf16x8*)(base + ((    quad) ^ f_)*8); \
      af[j][1] = *(const bf16x8*)(base + ((4 + quad) ^ f_)*8); } }
  #define LDB8(buf, nq) { _Pragma("unroll") for (int j = 0; j < 2; j++){ \
      int rt = wn + (nq)*32 + j*16 + l16; \
      const unsigned short* base = &Ls[buf][1][rt*64]; \
      int f_ = rt & 7; \
      bf[j][0] = *(const bf16x8*)(base + ((    quad) ^ f_)*8); \
      bf[j][1] = *(const bf16x8*)(base + ((4 + quad) ^ f_)*8); } }
  #define MFMAQ(mq, nq) { __builtin_amdgcn_s_setprio(1); \
      _Pragma("unroll") for (int j = 0; j < 4; j++) \
        _Pragma("unroll") for (int j2 = 0; j2 < 2; j2++){ \
          acc[(mq)*4+j][(nq)*2+j2] = __builtin_amdgcn_mfma_f32_16x16x32_bf16(af[j][0], bf[j2][0], acc[(mq)*4+j][(nq)*2+j2], 0, 0, 0); \
          acc[(mq)*4+j][(nq)*2+j2] = __builtin_amdgcn_mfma_f32_16x16x32_bf16(af[j][1], bf[j2][1], acc[(mq)*4+j][(nq)*2+j2], 0, 0, 0); } \
      __builtin_amdgcn_s_setprio(0); }
  #define BAR()   { __builtin_amdgcn_s_barrier(); }
  #define LGKM0() { asm volatile("s_waitcnt lgkmcnt(0)" ::: "memory"); SB(); }
  #define VM6()   { asm volatile("s_waitcnt vmcnt(6)"   ::: "memory"); }
  #define VM2()   { asm volatile("s_waitcnt vmcnt(2)"   ::: "memory"); }

  STA(0, 0, 0); STB(0, 0, 0); STB(0, 1, 0); STA(0, 1, 0);
  STA(1, 0, 1);
  asm volatile("s_waitcnt vmcnt(2)" ::: "memory");
  BAR();

  const int NI = NT >> 1;
  for (int i = 0; i < NI; i++) {
    const int tb  = 2*i + 1;
    int ta2 = 2*i + 2; if (ta2 > NT-1) ta2 = NT-1;
    int tb2 = 2*i + 3; if (tb2 > NT-1) tb2 = NT-1;

    LDA8(0, 0); LDB8(0, 0); STB(1, 0, tb);
    BAR(); LGKM0(); MFMAQ(0, 0); BAR();
    LDB8(0, 1); STB(1, 1, tb);
    BAR(); LGKM0(); MFMAQ(0, 1); BAR();
    LDA8(0, 1); STA(1, 1, tb);
    BAR(); LGKM0(); MFMAQ(1, 1); BAR();
    LDB8(0, 0); STA(0, 0, ta2);
    BAR(); LGKM0(); MFMAQ(1, 0); VM6(); BAR();
    LDA8(1, 0); LDB8(1, 0); STB(0, 1, ta2);
    BAR(); LGKM0(); MFMAQ(0, 0); VM6(); BAR();
    LDB8(1, 1); STA(0, 1, ta2);
    BAR(); LGKM0(); MFMAQ(0, 1); VM6(); BAR();
    LDA8(1, 1); STB(0, 0, ta2);
    BAR(); LGKM0(); MFMAQ(1, 1); BAR();
    LDB8(1, 0); STA(1, 0, tb2);
    BAR(); LGKM0(); MFMAQ(1, 0); VM2(); BAR();
  }
  asm volatile("s_waitcnt vmcnt(0)" ::: "memory");

  float bv[4];
  #pragma unroll
  for (int f = 0; f < 4; f++) bv[f] = bias ? bias[n0 + wn + f*16 + l16] : 0.f;
  const int col0 = n0 + wn + l16;
  #pragma unroll
  for (int i2 = 0; i2 < 8; i2++) {
    #pragma unroll
    for (int r = 0; r < 4; r++) {
      int row = m0 + wm + i2*16 + quad*4 + r;
      if (row < M) {
        #pragma unroll
        for (int f = 0; f < 4; f++) {
          float v = acc[i2][f][r] + bv[f];
          if (mode == 2) v = fgelu(v);
          Cout[(size_t)row * ldc + col0 + f*16] = f2bf(v);
        }
      }
    }
  }
  #undef STA
  #undef STB
  #undef LDA8
  #undef LDB8
  #undef MFMAQ
  #undef BAR
  #undef LGKM0
  #undef VM6
  #undef VM2
}

// ---------------------------------------------------------------- 128x256 8-phase GEMM (gemm8w) v2 — sched-fence diet (same as gemm8 v4)
__global__ __launch_bounds__(512, 2) void lma_gemm8w(
    const unsigned short* __restrict__ A, int lda,
    const unsigned short* __restrict__ Bt0, const unsigned short* __restrict__ Bt1,
    const float* __restrict__ bias0, const float* __restrict__ bias1,
    void* __restrict__ Cout, int ldc,
    int M, int N, int K, int mode, int nmt)
{
  __shared__ unsigned short LsA[2][128*64];   // 2 x 16KB
  __shared__ unsigned short LsB[2][256*64];   // 2 x 32KB
  const int tid = threadIdx.x;
  const int w = tid >> 6, lane = tid & 63, quad = lane >> 4, l16 = lane & 15;
  const int mt = blockIdx.x % nmt, nt = blockIdx.x / nmt;
  const int m0 = mt * 128, n0 = nt * 256;
  const int brch = m0 >> 13;
  const unsigned short* Bt = brch ? Bt1 : Bt0;
  const float* bias = brch ? bias1 : bias0;
  const int wm = (w >> 2) * 64, wn = (w & 3) * 64;

  f32x4 acc[4][4];
  #pragma unroll
  for (int i = 0; i < 4; i++)
    #pragma unroll
    for (int f = 0; f < 4; f++) acc[i][f] = f32x4{0.f,0.f,0.f,0.f};

  const int lrow8 = lane >> 3;
  const int lkb   = lane & 7;
  const int NT = K >> 6;

  const unsigned short* aP[2]; int aD[2];
  const unsigned short* bP[2][2]; int bD[2][2];
  #pragma unroll
  for (int hf = 0; hf < 2; hf++) {
    int rtA = hf*64 + w*8 + lrow8;
    int kbA = lkb ^ (rtA & 7);
    int ga = m0 + rtA; if (ga > M-1) ga = M-1;
    aP[hf] = A + (size_t)ga * lda + kbA*8;
    aD[hf] = (hf*64 + w*8) * 64;
    #pragma unroll
    for (int c = 0; c < 2; c++) {
      int rtB = hf*128 + (w*2 + c)*8 + lrow8;
      int kbB = lkb ^ (rtB & 7);
      int gb = n0 + rtB; if (gb > N-1) gb = N-1;
      bP[hf][c] = Bt + (size_t)gb * K + kbB*8;
      bD[hf][c] = (hf*128 + (w*2 + c)*8) * 64;
    }
  }

  bf16x8 af[2][2], bf[2][2];

  #define WSTA(buf, hf, kt) { glds16(aP[hf] + (size_t)(kt)*64, &LsA[buf][aD[hf]]); }
  #define WSTB(buf, hf, kt) { _Pragma("unroll") for (int c = 0; c < 2; c++) \
      glds16(bP[hf][c] + (size_t)(kt)*64, &LsB[buf][bD[hf][c]]); }
  #define WLDA(buf, mq) { _Pragma("unroll") for (int j = 0; j < 2; j++){ \
      int rt = wm + (mq)*32 + j*16 + l16; \
      const unsigned short* base = &LsA[buf][rt*64]; \
      int f_ = rt & 7; \
      af[j][0] = *(const bf16x8*)(base + ((    quad) ^ f_)*8); \
      af[j][1] = *(const bf16x8*)(base + ((4 + quad) ^ f_)*8); } }
  #define WLDB(buf, nq) { _Pragma("unroll") for (int j = 0; j < 2; j++){ \
      int rt = wn + (nq)*32 + j*16 + l16; \
      const unsigned short* base = &LsB[buf][rt*64]; \
      int f_ = rt & 7; \
      bf[j][0] = *(const bf16x8*)(base + ((    quad) ^ f_)*8); \
      bf[j][1] = *(const bf16x8*)(base + ((4 + quad) ^ f_)*8); } }
  #define WMFMAQ(mq, nq) { __builtin_amdgcn_s_setprio(1); \
      _Pragma("unroll") for (int j = 0; j < 2; j++) \
        _Pragma("unroll") for (int j2 = 0; j2 < 2; j2++){ \
          acc[(mq)*2+j][(nq)*2+j2] = __builtin_amdgcn_mfma_f32_16x16x32_bf16(af[j][0], bf[j2][0], acc[(mq)*2+j][(nq)*2+j2], 0, 0, 0); \
          acc[(mq)*2+j][(nq)*2+j2] = __builtin_amdgcn_mfma_f32_16x16x32_bf16(af[j][1], bf[j2][1], acc[(mq)*2+j][(nq)*2+j2], 0, 0, 0); } \
      __builtin_amdgcn_s_setprio(0); }
  #define WBAR()   { __builtin_amdgcn_s_barrier(); }
  #define WLGKM0() { asm volatile("s_waitcnt lgkmcnt(0)" ::: "memory"); SB(); }
  #define WVM4()   { asm volatile("s_waitcnt vmcnt(4)"   ::: "memory"); }
  #define WVM1()   { asm volatile("s_waitcnt vmcnt(1)"   ::: "memory"); }

  WSTA(0, 0, 0); WSTB(0, 0, 0); WSTB(0, 1, 0); WSTA(0, 1, 0);
  WSTA(1, 0, 1);
  WVM1(); WBAR();

  const int NI = NT >> 1;
  for (int i = 0; i < NI; i++) {
    const int tb  = 2*i + 1;
    int ta2 = 2*i + 2; if (ta2 > NT-1) ta2 = NT-1;
    int tb2 = 2*i + 3; if (tb2 > NT-1) tb2 = NT-1;

    WLDA(0, 0); WLDB(0, 0); WSTB(1, 0, tb);
    WBAR(); WLGKM0(); WMFMAQ(0, 0); WBAR();
    WLDB(0, 1); WSTB(1, 1, tb);
    WBAR(); WLGKM0(); WMFMAQ(0, 1); WBAR();
    WLDA(0, 1); WSTA(1, 1, tb);
    WBAR(); WLGKM0(); WMFMAQ(1, 1); WBAR();
    WLDB(0, 0); WSTA(0, 0, ta2);
    WBAR(); WLGKM0(); WMFMAQ(1, 0); WVM4(); WBAR();
    WLDA(1, 0); WLDB(1, 0); WSTB(0, 1, ta2);
    WBAR(); WLGKM0(); WMFMAQ(0, 0); WVM4(); WBAR();
    WLDB(1, 1); WSTA(0, 1, ta2);
    WBAR(); WLGKM0(); WMFMAQ(0, 1); WVM4(); WBAR();
    WLDA(1, 1); WSTB(0, 0, ta2);
    WBAR(); WLGKM0(); WMFMAQ(1, 1); WBAR();
    WLDB(1, 0); WSTA(1, 0, tb2);
    WBAR(); WLGKM0(); WMFMAQ(1, 0); WVM1(); WBAR();
  }
  asm volatile("s_waitcnt vmcnt(0)" ::: "memory");

  float bv[4];
  #pragma unroll
  for (int f = 0; f < 4; f++) bv[f] = bias ? bias[n0 + wn + f*16 + l16] : 0.f;
  const int col0 = n0 + wn + l16;
  #pragma unroll
  for (int i2 = 0; i2 < 4; i2++) {
    #pragma unroll
    for (int r = 0; r < 4; r++) {
      int row = m0 + wm + i2*16 + quad*4 + r;
      if (row < M) {
        #pragma unroll
        for (int f = 0; f < 4; f++) {
          float v = acc[i2][f][r] + bv[f];
          if (mode == 2) v = fgelu(v);
          else if (mode == 1) v *= 0.18033688011112042f;   // 0.125 * log2(e)
          if (mode <= 2) ((unsigned short*)Cout)[(size_t)row * ldc + col0 + f*16] = f2bf(v);
          else if (mode == 3) ((float*)Cout)[(size_t)row * ldc + col0 + f*16] = v;
          else {
            int sr = row % S2_, bb2 = row / S2_;
            ((float*)Cout)[((size_t)sr * B_ + bb2) * ldc + col0 + f*16] = v;
          }
        }
      }
    }
  }
  #undef WSTA
  #undef WSTB
  #undef WLDA
  #undef WLDB
  #undef WMFMAQ
  #undef WBAR
  #undef WLGKM0
  #undef WVM4
  #undef WVM1
}

// ---------------------------------------------------------------- block reduction helper
__device__ __forceinline__ void lma_red2(float& s, float& sq){
  __shared__ float red[16];
  #pragma unroll
  for (int msk = 1; msk < 64; msk <<= 1){ s += __shfl_xor(s, msk); sq += __shfl_xor(sq, msk); }
  int w = threadIdx.x >> 6;
  if ((threadIdx.x & 63) == 0){ red[w] = s; red[8 + w] = sq; }
  __syncthreads();
  s  = red[0] + red[1] + red[2] + red[3];
  sq = red[8] + red[9] + red[10] + red[11];
}

// ---------------------------------------------------------------- generic LN (f32 in, bf16 or f32 out)
__global__ __launch_bounds__(256) void lma_ln(const float* __restrict__ in,
                                              const float* __restrict__ g, const float* __restrict__ bb,
                                              int D, unsigned short* __restrict__ obf, float* __restrict__ of32){
  int row = blockIdx.x, t = threadIdx.x;
  const float* x = in + (size_t)row * D;
  float s = 0.f, sq = 0.f;
  for (int d = t; d < D; d += 256){ float v = x[d]; s += v; sq += v * v; }
  lma_red2(s, sq);
  float mean = s / D;
  float var = sq / D - mean * mean;
  float rstd = rsqrtf(fmaxf(var, 0.f) + 1e-12f);
  if (obf) {
    for (int d = t; d < D; d += 256) obf[(size_t)row * D + d] = f2bf((x[d] - mean) * rstd * g[d] + bb[d]);
  } else {
    for (int d = t; d < D; d += 256) of32[(size_t)row * D + d] = (x[d] - mean) * rstd * g[d] + bb[d];
  }
}

// ---------------------------------------------------------------- branch-combined LN over T12b (bf16, D=512) -> LQ2 bf16
__global__ __launch_bounds__(256) void lma_ln2(const unsigned short* __restrict__ T12b,
                                               const float* __restrict__ fg, const float* __restrict__ fbb,
                                               const float* __restrict__ bg, const float* __restrict__ bbb,
                                               unsigned short* __restrict__ LQ2){
  int m = blockIdx.x, t = threadIdx.x;           // 0..2*M_-1
  int fb = (m >= M_);
  int idx = m - fb * M_;
  const float* g = fb ? bg : fg;
  const float* bb = fb ? bbb : fbb;
  const unsigned short* x = T12b + ((size_t)fb * PAD_ + idx) * 512;
  unsigned short* o = LQ2 + ((size_t)fb * PAD_ + idx) * 512;
  float v0 = bf2f(x[t]), v1 = bf2f(x[t + 256]);
  float s = v0 + v1, sq = v0*v0 + v1*v1;
  lma_red2(s, sq);
  float mean = s / 512.f;
  float var = sq / 512.f - mean * mean;
  float rstd = rsqrtf(fmaxf(var, 0.f) + 1e-12f);
  o[t]       = f2bf((v0 - mean) * rstd * g[t]       + bb[t]);
  o[t + 256] = f2bf((v1 - mean) * rstd * g[t + 256] + bb[t + 256]);
}

// ---------------------------------------------------------------- attn LN: LN(residual(hidden)+[pf,pb](bf16)) -> bf16 (M_ x 1024)
__global__ __launch_bounds__(256) void lma_attn_ln(const unsigned short* __restrict__ pf,
                                                   const unsigned short* __restrict__ pb,
                                                   const float* __restrict__ hidden,
                                                   const float* __restrict__ g, const float* __restrict__ bb,
                                                   unsigned short* __restrict__ out){
  int m = blockIdx.x, t = threadIdx.x;
  int b = m / S2_, s = m - b * S2_;
  const float* hf = hidden + ((size_t)s       * B_ + b) * 1024;
  const float* hb = hidden + ((size_t)(s + 2) * B_ + b) * 1024;
  float v[4]; float sum = 0.f, sq = 0.f;
  #pragma unroll
  for (int j = 0; j < 4; j++){
    int d = t + j * 256;
    float x = (d < 512) ? (bf2f(pf[(size_t)m * 512 + d]) + hf[d])
                        : (bf2f(pb[(size_t)m * 512 + (d - 512)]) + hb[d]);
    v[j] = x; sum += x; sq += x * x;
  }
  lma_red2(sum, sq);
  float mean = sum / 1024.f;
  float var = sq / 1024.f - mean * mean;
  float rstd = rsqrtf(fmaxf(var, 0.f) + 1e-12f);
  #pragma unroll
  for (int j = 0; j < 4; j++){
    int d = t + j * 256;
    out[(size_t)m * 1024 + d] = f2bf((v[j] - mean) * rstd * g[d] + bb[d]);
  }
}

// ---------------------------------------------------------------- combined flash attention v11: KVBLK=128 (2 k-tiles/iter)
// (unchanged from round 11 — 99.1us measured, MfmaUtil 9.8)
__global__ __launch_bounds__(256, 4) void lma_attn11(const unsigned short* __restrict__ Q2,
                                                     const unsigned short* __restrict__ KV2,
                                                     const unsigned short* __restrict__ VT2,
                                                     unsigned short* __restrict__ CT2,
                                                     const int* __restrict__ lens){
  __shared__ unsigned short Kl[2][64*64];
  __shared__ unsigned short Vl[2][64*64];
  __shared__ __align__(16) unsigned short Pl[4][16*64];

  const int tid = threadIdx.x;
  const int w = tid >> 6, lane = tid & 63, quad = lane >> 4, l16 = lane & 15;
  const int id = blockIdx.x;                 // 1024 blocks: [qt:4][h:3][b:3]
  const int qt = id >> 6, h = (id >> 3) & 7, b = id & 7;
  const int L2 = lens[b] - 2;
  const int q0wg = qt * 64;
  const int q0 = q0wg + w * 16;
  const int qg = q0 + l16;
  const int qload = (qg > S2_-1) ? (S2_-1) : qg;

  const size_t qbase  = ((size_t)b * S2_) * 512  + h * 64;
  const size_t kbase  = ((size_t)b * S2_) * 1024 + h * 64;
  const size_t vtbase = ((size_t)(b * 8 + h) * 64) * 1024;
  char* Pb = (char*)&Pl[w][0];

  const int lrow = lane >> 3;
  const int g0s  = (lane & 7) ^ lrow;
  const int x7   = l16 & 7;
  const int x7s  = x7 << 4;

  for (int fb = 0; fb < 2; fb++) {
    const int backward = fb;
    const unsigned short* Q  = Q2  + (size_t)fb * PAD_ * 512;
    const unsigned short* Kx = KV2 + (size_t)fb * PAD_ * 1024;
    const unsigned short* VT = VT2 + (size_t)fb * VTS_;
    unsigned short* CTX      = CT2 + (size_t)fb * PAD_ * 512;

    bf16x8 qf[2];
    {
      const unsigned short* qp = Q + qbase + (size_t)qload * 512 + quad * 8;
      qf[0] = *(const bf16x8*)(qp);
      qf[1] = *(const bf16x8*)(qp + 32);
    }

    float mi = -3e38f, li = 0.f;
    f32x4 ot[4];
    #pragma unroll
    for (int f = 0; f < 4; f++) ot[f] = f32x4{0.f,0.f,0.f,0.f};

    int klo = 0, khi = S2_ - 1;
    if (q0wg + 63 < L2) {
      if (!backward) khi = q0wg + 63;
      else { klo = q0wg; khi = L2 - 1; }
    }

    for (int kt0 = klo; kt0 <= khi; kt0 += 128) {
      const bool h2 = (kt0 + 64 <= khi);       // block-uniform
      const int span = h2 ? 127 : 63;

      #pragma unroll
      for (int c = 0; c < 2; c++) {
        int r = w*16 + c*8 + lrow;
        int kr = kt0 + r; if (kr > S2_-1) kr = S2_-1;
        glds16(Kx + kbase + (size_t)kr * 1024 + g0s * 8, &Kl[0][(w*16 + c*8) * 64]);
        glds16(VT + vtbase + (size_t)r * 1024 + kt0 + g0s * 8, &Vl[0][(w*16 + c*8) * 64]);
      }
      if (h2) {
        #pragma unroll
        for (int c = 0; c < 2; c++) {
          int r = w*16 + c*8 + lrow;
          int kr = kt0 + 64 + r; if (kr > S2_-1) kr = S2_-1;
          glds16(Kx + kbase + (size_t)kr * 1024 + g0s * 8, &Kl[1][(w*16 + c*8) * 64]);
          glds16(VT + vtbase + (size_t)r * 1024 + (kt0 + 64) + g0s * 8, &Vl[1][(w*16 + c*8) * 64]);
        }
      }
      __syncthreads();

      f32x4 st[8];
      {
        bf16x8 kf[4][2];
        #pragma unroll
        for (int sub = 0; sub < 4; sub++) {
          const unsigned short* kp = &Kl[0][(sub*16 + l16) * 64];
          kf[sub][0] = *(const bf16x8*)(kp + (( quad      ^ x7) * 8));
          kf[sub][1] = *(const bf16x8*)(kp + (((quad + 4) ^ x7) * 8));
        }
        __builtin_amdgcn_s_setprio(1);
        #pragma unroll
        for (int sub = 0; sub < 4; sub++) {
          f32x4 s = f32x4{0.f,0.f,0.f,0.f};
          s = __builtin_amdgcn_mfma_f32_16x16x32_bf16(kf[sub][0], qf[0], s, 0, 0, 0);
          s = __builtin_amdgcn_mfma_f32_16x16x32_bf16(kf[sub][1], qf[1], s, 0, 0, 0);
          st[sub] = s;
        }
        __builtin_amdgcn_s_setprio(0);
      }
      if (h2) {
        bf16x8 kf[4][2];
        #pragma unroll
        for (int sub = 0; sub < 4; sub++) {
          const unsigned short* kp = &Kl[1][(sub*16 + l16) * 64];
          kf[sub][0] = *(const bf16x8*)(kp + (( quad      ^ x7) * 8));
          kf[sub][1] = *(const bf16x8*)(kp + (((quad + 4) ^ x7) * 8));
        }
        __builtin_amdgcn_s_setprio(1);
        #pragma unroll
        for (int sub = 0; sub < 4; sub++) {
          f32x4 s = f32x4{0.f,0.f,0.f,0.f};
          s = __builtin_amdgcn_mfma_f32_16x16x32_bf16(kf[sub][0], qf[0], s, 0, 0, 0);
          s = __builtin_amdgcn_mfma_f32_16x16x32_bf16(kf[sub][1], qf[1], s, 0, 0, 0);
          st[4 + sub] = s;
        }
        __builtin_amdgcn_s_setprio(0);
      }

      {
        bool tail = (kt0 + span > S2_ - 1);
        bool full;
        if (!backward) full = !tail && ((kt0 + span <= q0) || (q0 >= L2));
        else           full = !tail && ((q0 >= L2) || ((kt0 >= q0 + 15) && (kt0 + span < L2)));
        if (!full) {
          #pragma unroll
          for (int sub = 0; sub < 4; sub++) {
            #pragma unroll
            for (int r = 0; r < 4; r++) {
              int kg = kt0 + sub*16 + quad*4 + r;
              bool ok;
              if (!backward) ok = (kg < S2_) && ((qg >= L2) || (kg <= qg));
              else           ok = (kg < S2_) && ((qg >= L2) || ((kg >= qg) && (kg < L2)));
              if (!ok) st[sub][r] = -3e38f;
            }
          }
          if (h2) {
            #pragma unroll
            for (int sub = 0; sub < 4; sub++) {
              #pragma unroll
              for (int r = 0; r < 4; r++) {
                int kg = kt0 + 64 + sub*16 + quad*4 + r;
                bool ok;
                if (!backward) ok = (kg < S2_) && ((qg >= L2) || (kg <= qg));
                else           ok = (kg < S2_) && ((qg >= L2) || ((kg >= qg) && (kg < L2)));
                if (!ok) st[4 + sub][r] = -3e38f;
              }
            }
          }
        }
      }

      float mx = -3e38f;
      #pragma unroll
      for (int sub = 0; sub < 4; sub++)
        #pragma unroll
        for (int r = 0; r < 4; r++) mx = fmaxf(mx, st[sub][r]);
      if (h2) {
        #pragma unroll
        for (int sub = 4; sub < 8; sub++)
          #pragma unroll
          for (int r = 0; r < 4; r++) mx = fmaxf(mx, st[sub][r]);
      }
      mx = fmaxf(mx, __shfl_xor(mx, 16));
      mx = fmaxf(mx, __shfl_xor(mx, 32));

      if (__any(mx > mi + 11.f)) {
        float mn = fmaxf(mi, mx);
        float al = fexp2(mi - mn);
        li *= al;
        #pragma unroll
        for (int f = 0; f < 4; f++)
          #pragma unroll
          for (int r = 0; r < 4; r++) ot[f][r] *= al;
        mi = mn;
      }

      float rs = 0.f;
      #pragma unroll
      for (int sub = 0; sub < 4; sub++)
        #pragma unroll
        for (int r = 0; r < 4; r++) {
          float p = fexp2(st[sub][r] - mi);
          st[sub][r] = p; rs += p;
        }
      if (h2) {
        #pragma unroll
        for (int sub = 4; sub < 8; sub++)
          #pragma unroll
          for (int r = 0; r < 4; r++) {
            float p = fexp2(st[sub][r] - mi);
            st[sub][r] = p; rs += p;
          }
      }
      rs += __shfl_xor(rs, 16);
      rs += __shfl_xor(rs, 32);
      li += rs;

      #pragma unroll
      for (int sub = 0; sub < 4; sub++) {
        u32x2 pk2;
        pk2[0] = cvtpk(st[sub][0], st[sub][1]);
        pk2[1] = cvtpk(st[sub][2], st[sub][3]);
        *(u32x2*)(Pb + (l16*128 + ((sub*32 + quad*8) ^ x7s))) = pk2;
      }
      {
        bf16x8 pfr0 = *(const bf16x8*)(Pb + (l16*128 + (( 0 + quad*16) ^ x7s)));
        bf16x8 pfr1 = *(const bf16x8*)(Pb + (l16*128 + ((64 + quad*16) ^ x7s)));
        bf16x8 vf[4][2];
        #pragma unroll
        for (int f = 0; f < 4; f++) {
          const unsigned short* vp = &Vl[0][(f*16 + l16) * 64];
          vf[f][0] = *(const bf16x8*)(vp + (( quad      ^ x7) * 8));
          vf[f][1] = *(const bf16x8*)(vp + (((quad + 4) ^ x7) * 8));
        }
        __builtin_amdgcn_s_setprio(1);
        #pragma unroll
        for (int f = 0; f < 4; f++) {
          ot[f] = __builtin_amdgcn_mfma_f32_16x16x32_bf16(vf[f][0], pfr0, ot[f], 0, 0, 0);
          ot[f] = __builtin_amdgcn_mfma_f32_16x16x32_bf16(vf[f][1], pfr1, ot[f], 0, 0, 0);
        }
        __builtin_amdgcn_s_setprio(0);
      }
      if (h2) {
        #pragma unroll
        for (int sub = 0; sub < 4; sub++) {
          u32x2 pk2;
          pk2[0] = cvtpk(st[4+sub][0], st[4+sub][1]);
          pk2[1] = cvtpk(st[4+sub][2], st[4+sub][3]);
          *(u32x2*)(Pb + (l16*128 + ((sub*32 + quad*8) ^ x7s))) = pk2;
        }
        bf16x8 pfr0 = *(const bf16x8*)(Pb + (l16*128 + (( 0 + quad*16) ^ x7s)));
        bf16x8 pfr1 = *(const bf16x8*)(Pb + (l16*128 + ((64 + quad*16) ^ x7s)));
        bf16x8 vf[4][2];
        #pragma unroll
        for (int f = 0; f < 4; f++) {
          const unsigned short* vp = &Vl[1][(f*16 + l16) * 64];
          vf[f][0] = *(const bf16x8*)(vp + (( quad      ^ x7) * 8));
          vf[f][1] = *(const bf16x8*)(vp + (((quad + 4) ^ x7) * 8));
        }
        __builtin_amdgcn_s_setprio(1);
        #pragma unroll
        for (int f = 0; f < 4; f++) {
          ot[f] = __builtin_amdgcn_mfma_f32_16x16x32_bf16(vf[f][0], pfr0, ot[f], 0, 0, 0);
          ot[f] = __builtin_amdgcn_mfma_f32_16x16x32_bf16(vf[f][1], pfr1, ot[f], 0, 0, 0);
        }
        __builtin_amdgcn_s_setprio(0);
      }
      __syncthreads();
    }

    if (qg < S2_) {
      float rcp = 1.f / li;
      #pragma unroll
      for (int f = 0; f < 4; f++) {
        ushort4 pk;
        pk.x = f2bf(ot[f][0] * rcp); pk.y = f2bf(ot[f][1] * rcp);
        pk.z = f2bf(ot[f][2] * rcp); pk.w = f2bf(ot[f][3] * rcp);
        *(ushort4*)&CTX[qbase + (size_t)qg * 512 + f*16 + quad*4] = pk;
      }
    }
  }
}

// ----------------------------------------------------------------
extern "C" void kernel_launch(void* const* d_in, const int* in_sizes, int n_in,
                              void* d_out, int out_size, void* d_ws, size_t ws_size,
                              hipStream_t stream)
{
  const float* hidden = (const float*)d_in[0];
  const int*   lens   = (const int*)d_in[1];
  const float* fw[14]; for (int i = 0; i < 14; i++) fw[i] = (const float*)d_in[2 + i];
  const float* bw[14]; for (int i = 0; i < 14; i++) bw[i] = (const float*)d_in[16 + i];
  const float* attn_g = (const float*)d_in[30];
  const float* attn_b = (const float*)d_in[31];
  const float* o_w1 = (const float*)d_in[32];
  const float* o_b1 = (const float*)d_in[33];
  const float* o_w2 = (const float*)d_in[34];
  const float* o_b2 = (const float*)d_in[35];
  const float* o_lng = (const float*)d_in[36];
  const float* o_lnb = (const float*)d_in[37];

  char* ws = (char*)d_ws;
  size_t off = 0;
  auto alloc = [&](size_t bytes)->char* {
    off = (off + 255) & ~(size_t)255;
    char* p = ws + off; off += bytes; return p;
  };

  unsigned short* fw1t = (unsigned short*)alloc((size_t)1024*1024*2);
  unsigned short* fw2t = (unsigned short*)alloc((size_t)512*1024*2);
  unsigned short* fqt  = (unsigned short*)alloc((size_t)512*512*2);
  unsigned short* fkvt = (unsigned short*)alloc((size_t)1024*512*2);  // [K(512 rows); V(512 rows)]
  unsigned short* fot  = (unsigned short*)alloc((size_t)512*512*2);
  unsigned short* bw1t = (unsigned short*)alloc((size_t)1024*1024*2);
  unsigned short* bw2t = (unsigned short*)alloc((size_t)512*1024*2);
  unsigned short* bqt  = (unsigned short*)alloc((size_t)512*512*2);
  unsigned short* bkvt = (unsigned short*)alloc((size_t)1024*512*2);
  unsigned short* bot  = (unsigned short*)alloc((size_t)512*512*2);
  unsigned short* ow1t = (unsigned short*)alloc((size_t)1024*1024*2);
  unsigned short* ow2t = (unsigned short*)alloc((size_t)1024*1024*2);
  float*          biasKV = (float*)alloc(2048*4);

  unsigned short* Xb   = (unsigned short*)alloc((size_t)M_*1024*2);
  unsigned short* big1 = (unsigned short*)alloc((size_t)2*PAD_*1024*2);
  float*          big2 = (float*)alloc((size_t)2*PAD_*512*4);
  unsigned short* LQCT = (unsigned short*)alloc((size_t)2*PAD_*512*2);
  unsigned short* Q2   = (unsigned short*)alloc((size_t)2*PAD_*512*2);

  unsigned short* H12 = big1, *KV2 = big1, *H1o = big1;
  // big2 partitions: [0 .. 2*VTS_) = T12b (bf16) then VT2 (bf16);
  //                  [2*VTS_ .. 4*VTS_) = P2b (bf16 out-proj). Exactly fills big2.
  unsigned short* T12b = (unsigned short*)big2;
  unsigned short* VT2  = (unsigned short*)big2;
  unsigned short* P2b  = (unsigned short*)big2 + 2*VTS_;
  unsigned short* LQ2 = LQCT, *CT2 = LQCT;

  lma_prep_x<<<M_, 256, 0, stream>>>(hidden, Xb);

  {
    TPack tp;
    const float* srcs[14] = { fw[0], fw[2], fw[6], fw[8], fw[10], fw[12],
                              bw[0], bw[2], bw[6], bw[8], bw[10], bw[12],
                              o_w1, o_w2 };
    unsigned short* dsts[14] = { fw1t, fw2t, fqt, fkvt, fkvt + (size_t)512*512, fot,
                                 bw1t, bw2t, bqt, bkvt, bkvt + (size_t)512*512, bot,
                                 ow1t, ow2t };
    int Ks[14] = {1024,1024,512,512,512,512, 1024,1024,512,512,512,512, 1024,1024};
    int Ns[14] = {1024, 512,512,512,512,512, 1024, 512,512,512,512,512, 1024,1024};
    for (int i = 0; i < 14; i++){ tp.src[i]=srcs[i]; tp.dst[i]=dsts[i]; tp.K[i]=Ks[i]; tp.N[i]=Ns[i]; }
    lma_transpose_all<<<dim3(32, 32, 14), 256, 0, stream>>>(tp);
  }
  lma_biascat<<<8, 256, 0, stream>>>(fw[9], fw[11], bw[9], bw[11], biasKV);

  auto G8 = [&](const unsigned short* A, int lda,
                const unsigned short* B0, const unsigned short* B1,
                const float* b0, const float* b1,
                unsigned short* C, int ldc, int M, int N, int K, int mode, int amap){
    int nmt = M / 256;
    lma_gemm8<<<dim3(nmt * (N/256)), 512, 0, stream>>>(A, lda, B0, B1, b0, b1, C, ldc, M, N, K, mode, amap, nmt);
  };
  auto G8W = [&](const unsigned short* A, int lda,
                 const unsigned short* B0, const unsigned short* B1,
                 const float* b0, const float* b1,
                 void* C, int ldc, int M, int N, int K, int mode){
    int nmt = (M + 127) / 128;
    lma_gemm8w<<<dim3(nmt * (N/256)), 512, 0, stream>>>(A, lda, B0, B1, b0, b1, C, ldc, M, N, K, mode, nmt);
  };

  // both-branch FFN + LN + projections (rows<8192 = forward, >=8192 = backward)
  G8(Xb, 1024, fw1t, bw1t, fw[1], bw[1], H12, 1024, 2*PAD_, 1024, 1024, 2, 1);   // FFN1+gelu (256^2 8-phase)
  G8W(H12, 1024, fw2t, bw2t, fw[3], bw[3], T12b, 512, 2*PAD_, 512, 1024, 0);     // FFN2 -> bf16 (128x256 8-phase)
  lma_ln2<<<2*M_, 256, 0, stream>>>(T12b, fw[4], fw[5], bw[4], bw[5], LQ2);
  G8W(LQ2, 512, fqt, bqt, fw[7], bw[7], Q2, 512, 2*PAD_, 512, 512, 1);           // Q (x0.125*log2e)
  G8(Xb, 1024, fkvt, bkvt, biasKV, biasKV + 1024, KV2, 1024, 2*PAD_, 1024, 512, 0, 2); // K|V (256^2 8-phase)
  lma_vt2<<<dim3(32, 16, 16), 256, 0, stream>>>(KV2, VT2);

  lma_attn11<<<dim3(1024), 256, 0, stream>>>(Q2, KV2, VT2, CT2, lens);

  G8W(CT2, 512, fot, bot, fw[13], bw[13], P2b, 512, 2*PAD_, 512, 512, 0);        // out proj -> bf16

  lma_attn_ln<<<M_, 256, 0, stream>>>(P2b, P2b + (size_t)PAD_*512, hidden, attn_g, attn_b, Xb);

  G8W(Xb, 1024, ow1t, ow1t, o_b1, o_b1, H1o, 1024, M_, 1024, 1024, 2);           // out FFN1+gelu
  G8W(H1o, 1024, ow2t, ow2t, o_b2, o_b2, (float*)d_out, 1024, M_, 1024, 1024, 4); // out FFN2 -> d_out (remapped)
  lma_ln<<<M_, 256, 0, stream>>>((float*)d_out, o_lng, o_lnb, 1024, nullptr, (float*)d_out);
}